// Round 1
// baseline (2875.024 us; speedup 1.0000x reference)
//
#include <hip/hip_runtime.h>

#define TDIM 2048
#define CDIM 512
#define BDIM 8
#define PDIM 512
#define DMODEL 512
#define NCOUT 30
#define SPPOUT 3584
#define AKDIM 4096   // SPPOUT + DMODEL

__device__ __forceinline__ float waveSum(float v){
#pragma unroll
  for (int o = 32; o > 0; o >>= 1) v += __shfl_xor(v, o);
  return v;
}
__device__ __forceinline__ float waveMax(float v){
#pragma unroll
  for (int o = 32; o > 0; o >>= 1) v = fmaxf(v, __shfl_xor(v, o));
  return v;
}

__global__ void kzero(float* p, int n){
  int i = blockIdx.x * 256 + threadIdx.x;
  if (i < n) p[i] = 0.f;
}

// Chunked inclusive scan along T. W[b][t][c] = sum x[b,c, chunkstart..t], chunk=(t>>8)
__global__ void kscan(const float* __restrict__ x, float* __restrict__ W, float* __restrict__ tot){
  int idx = blockIdx.x;             // b*16 + ch*2 + cg
  int b = idx >> 4, rem = idx & 15, ch = rem >> 1, cg = rem & 1;
  int c = cg * 256 + threadIdx.x;
  const float* xp = x + ((size_t)(b * CDIM + c)) * TDIM + ch * 256;
  float* wp = W + ((size_t)b * TDIM + ch * 256) * CDIM + c;
  float run = 0.f;
  for (int tl = 0; tl < 256; tl += 4){
    float4 v = *(const float4*)(xp + tl);
    run += v.x; wp[(size_t)(tl + 0) * CDIM] = run;
    run += v.y; wp[(size_t)(tl + 1) * CDIM] = run;
    run += v.z; wp[(size_t)(tl + 2) * CDIM] = run;
    run += v.w; wp[(size_t)(tl + 3) * CDIM] = run;
  }
  tot[((size_t)b * 8 + ch) * CDIM + c] = run;
}

__global__ void koff(const float* __restrict__ tot, float* __restrict__ off){
  int b = blockIdx.x >> 1, cg = blockIdx.x & 1;
  int c = cg * 256 + threadIdx.x;
  float run = 0.f;
  for (int ch = 0; ch < 8; ++ch){
    off[((size_t)b * 8 + ch) * CDIM + c] = run;
    run += tot[((size_t)b * 8 + ch) * CDIM + c];
  }
}

// Stable argsort by center: key = ((s+e)<<9) | p  (unique keys -> stable)
__global__ void ksort(const int* __restrict__ boxes, int* __restrict__ sidx){
  __shared__ unsigned key[PDIM];
  int b = blockIdx.x, t = threadIdx.x;
  int s = boxes[(size_t)(b * PDIM + t) * 2];
  int e = boxes[(size_t)(b * PDIM + t) * 2 + 1];
  key[t] = ((unsigned)(s + e) << 9) | (unsigned)t;
  __syncthreads();
  for (int k = 2; k <= PDIM; k <<= 1){
    for (int j = k >> 1; j > 0; j >>= 1){
      int ixj = t ^ j;
      if (ixj > t){
        unsigned a = key[t], c2 = key[ixj];
        bool up = ((t & k) == 0);
        bool doswap = up ? (a > c2) : (a < c2);
        if (doswap){ key[t] = c2; key[ixj] = a; }
      }
      __syncthreads();
    }
  }
  sidx[b * PDIM + t] = (int)(key[t] & 511u);
}

// Build Wcat = [proj_w | pos_w2]  (512 x 4096)
__global__ void kwcat(const float* __restrict__ pw, const float* __restrict__ pw2, float* __restrict__ Wc){
  int i = blockIdx.x * 256 + threadIdx.x;
  int r = i >> 12, k = i & 4095;
  Wc[i] = (k < SPPOUT) ? pw[(size_t)r * SPPOUT + k] : pw2[(size_t)r * DMODEL + (k - SPPOUT)];
}
__global__ void kbcat(const float* __restrict__ pb, const float* __restrict__ pb2, float* __restrict__ bc){
  int i = blockIdx.x * 256 + threadIdx.x;
  if (i < DMODEL) bc[i] = pb[i] + pb2[i];
}

// SPP pooling + pos-MLP hidden, staged in sorted order: A[b][j][0..4095]
__global__ void kspp(const float* __restrict__ W, const float* __restrict__ off,
                     const int* __restrict__ boxes, const int* __restrict__ sidx,
                     const float* __restrict__ pw1, const float* __restrict__ pb1,
                     float* __restrict__ A){
  int blk = blockIdx.x;
  int b = blk >> 9, j = blk & 511;
  int p = sidx[b * PDIM + j];
  int s0 = boxes[(size_t)(b * PDIM + p) * 2];
  int e0 = boxes[(size_t)(b * PDIM + p) * 2 + 1];
  int start = min(max(s0, 0), TDIM - 1);
  int end   = min(max(e0, 1), TDIM);
  if (end <= start) end = min(start + 1, TDIM);
  int n = end - start;

  int lo[7], hi[7], cb[7], cl[7];
  {
    const int Ls[3] = {1, 2, 4};
    const int Bo[3] = {0, 512, 1536};
    int q = 0;
    for (int li = 0; li < 3; ++li){
      int L = Ls[li];
      for (int i = 0; i < L; ++i){
        lo[q] = start + (i * n) / L;
        hi[q] = start + ((i + 1) * n + L - 1) / L;
        cb[q] = Bo[li] + i;
        cl[q] = L;
        ++q;
      }
    }
  }
  float s_f = (float)s0, e_f = (float)e0;
  float px = (s_f + e_f) * 0.5f / (float)TDIM;
  float py = fmaxf(e_f - s_f, 1.f) / (float)TDIM;
  float* Ar = A + (size_t)(b * PDIM + j) * AKDIM;
  const float* Wb = W + (size_t)b * TDIM * CDIM;
  const float* ob = off + (size_t)b * 8 * CDIM;
  for (int c = threadIdx.x; c < CDIM; c += 256){
#pragma unroll
    for (int q = 0; q < 7; ++q){
      int l = lo[q], h = hi[q];
      float fl = (l == 0) ? 0.f : (Wb[(size_t)(l - 1) * CDIM + c] + ob[((l - 1) >> 8) * CDIM + c]);
      float fh = Wb[(size_t)(h - 1) * CDIM + c] + ob[((h - 1) >> 8) * CDIM + c];
      Ar[cb[q] + c * cl[q]] = (fh - fl) / (float)(h - l);
    }
    float hv = pw1[c * 2] * px + pw1[c * 2 + 1] * py + pb1[c];
    Ar[SPPOUT + c] = fmaxf(hv, 0.f);
  }
}

// C[M,N] = act(alpha * A[M,K] @ B[N,K]^T + bias + resid), batched over z (z -> zb=z/hdiv, zh=z%hdiv)
__global__ __launch_bounds__(256) void gemm_nt(
    int M, int N, int K,
    const float* __restrict__ A, int lda, long long sAb, long long sAh,
    const float* __restrict__ B, int ldb, long long sBb, long long sBh,
    float* __restrict__ C, int ldc, long long sCb, long long sCh,
    int hdiv, float alpha,
    const float* __restrict__ bias,
    const float* __restrict__ resid,
    int act)
{
  __shared__ float As[64][33];
  __shared__ float Bs[64][33];
  int z = blockIdx.z;
  int zb = z / hdiv, zh = z % hdiv;
  A += (size_t)zb * sAb + (size_t)zh * sAh;
  B += (size_t)zb * sBb + (size_t)zh * sBh;
  C += (size_t)zb * sCb + (size_t)zh * sCh;
  int tx = threadIdx.x & 15, ty = threadIdx.x >> 4;
  int rowBase = blockIdx.y * 64, colBase = blockIdx.x * 64;
  float acc[4][4];
#pragma unroll
  for (int i = 0; i < 4; ++i)
#pragma unroll
    for (int j = 0; j < 4; ++j) acc[i][j] = 0.f;

  for (int k0 = 0; k0 < K; k0 += 32){
    for (int i = threadIdx.x; i < 64 * 32; i += 256){
      int kk = i & 31, r = i >> 5;
      int gr = rowBase + r;
      As[r][kk] = (gr < M) ? A[(size_t)gr * lda + k0 + kk] : 0.f;
      int gc = colBase + r;
      Bs[r][kk] = (gc < N) ? B[(size_t)gc * ldb + k0 + kk] : 0.f;
    }
    __syncthreads();
#pragma unroll
    for (int kk = 0; kk < 32; ++kk){
      float av[4], bv[4];
#pragma unroll
      for (int i = 0; i < 4; ++i) av[i] = As[ty * 4 + i][kk];
#pragma unroll
      for (int i = 0; i < 4; ++i) bv[i] = Bs[tx * 4 + i][kk];
#pragma unroll
      for (int i = 0; i < 4; ++i)
#pragma unroll
        for (int j = 0; j < 4; ++j) acc[i][j] += av[i] * bv[j];
    }
    __syncthreads();
  }
#pragma unroll
  for (int i = 0; i < 4; ++i)
#pragma unroll
    for (int j = 0; j < 4; ++j){
      int row = rowBase + ty * 4 + i, col = colBase + tx * 4 + j;
      if (row < M && col < N){
        float v = acc[i][j] * alpha;
        if (bias) v += bias[col];
        if (resid) v += resid[(size_t)row * ldc + col];
        if (act == 1) v = 0.5f * v * (1.f + erff(v * 0.7071067811865476f));
        C[(size_t)row * ldc + col] = v;
      }
    }
}

// C[M,N] = A[M,K] @ B[K,N]   (attention AV), batched over z
__global__ __launch_bounds__(256) void gemm_nn(
    int M, int N, int K,
    const float* __restrict__ A, int lda, long long sAb, long long sAh,
    const float* __restrict__ B, int ldb, long long sBb, long long sBh,
    float* __restrict__ C, int ldc, long long sCb, long long sCh,
    int hdiv)
{
  __shared__ float As[64][33];
  __shared__ float Bs[32][65];
  int z = blockIdx.z;
  int zb = z / hdiv, zh = z % hdiv;
  A += (size_t)zb * sAb + (size_t)zh * sAh;
  B += (size_t)zb * sBb + (size_t)zh * sBh;
  C += (size_t)zb * sCb + (size_t)zh * sCh;
  int tx = threadIdx.x & 15, ty = threadIdx.x >> 4;
  int rowBase = blockIdx.y * 64, colBase = blockIdx.x * 64;
  float acc[4][4];
#pragma unroll
  for (int i = 0; i < 4; ++i)
#pragma unroll
    for (int j = 0; j < 4; ++j) acc[i][j] = 0.f;

  for (int k0 = 0; k0 < K; k0 += 32){
    for (int i = threadIdx.x; i < 64 * 32; i += 256){
      int kk = i & 31, r = i >> 5;
      As[r][kk] = A[(size_t)(rowBase + r) * lda + k0 + kk];
    }
    for (int i = threadIdx.x; i < 32 * 64; i += 256){
      int n = i & 63, kk = i >> 6;
      Bs[kk][n] = B[(size_t)(k0 + kk) * ldb + colBase + n];
    }
    __syncthreads();
#pragma unroll
    for (int kk = 0; kk < 32; ++kk){
      float av[4], bv[4];
#pragma unroll
      for (int i = 0; i < 4; ++i) av[i] = As[ty * 4 + i][kk];
#pragma unroll
      for (int i = 0; i < 4; ++i) bv[i] = Bs[kk][tx * 4 + i];
#pragma unroll
      for (int i = 0; i < 4; ++i)
#pragma unroll
        for (int j = 0; j < 4; ++j) acc[i][j] += av[i] * bv[j];
    }
    __syncthreads();
  }
#pragma unroll
  for (int i = 0; i < 4; ++i)
#pragma unroll
    for (int j = 0; j < 4; ++j){
      int row = rowBase + ty * 4 + i, col = colBase + tx * 4 + j;
      if (row < M && col < N) C[(size_t)row * ldc + col] = acc[i][j];
    }
}

// softmax over 512-wide rows, in place
__global__ void ksm_rows(float* __restrict__ S){
  int row = blockIdx.x, lane = threadIdx.x;
  float* p = S + (size_t)row * 512;
  float v[8]; float m = -1e30f;
#pragma unroll
  for (int i = 0; i < 8; ++i){ v[i] = p[lane + 64 * i]; m = fmaxf(m, v[i]); }
  m = waveMax(m);
  float s = 0.f;
#pragma unroll
  for (int i = 0; i < 8; ++i){ v[i] = expf(v[i] - m); s += v[i]; }
  s = waveSum(s);
  float r = 1.f / s;
#pragma unroll
  for (int i = 0; i < 8; ++i) p[lane + 64 * i] = v[i] * r;
}

__global__ void kln(const float* __restrict__ X, float* __restrict__ Y,
                    const float* __restrict__ g, const float* __restrict__ bb){
  int row = blockIdx.x, lane = threadIdx.x;
  const float* xr = X + (size_t)row * DMODEL;
  float v[8]; float s = 0.f;
#pragma unroll
  for (int i = 0; i < 8; ++i){ v[i] = xr[lane + 64 * i]; s += v[i]; }
  s = waveSum(s);
  float m = s * (1.f / DMODEL);
  float q = 0.f;
#pragma unroll
  for (int i = 0; i < 8; ++i){ float d = v[i] - m; q += d * d; }
  q = waveSum(q);
  float inv = rsqrtf(q * (1.f / DMODEL) + 1e-5f);
  float* yr = Y + (size_t)row * DMODEL;
#pragma unroll
  for (int i = 0; i < 8; ++i){
    int c = lane + 64 * i;
    yr[c] = (v[i] - m) * inv * g[c] + bb[c];
  }
}

// det softmax over P (columns), in sorted space
__global__ void kdetsm(const float* __restrict__ det, float* __restrict__ dp){
  int b = blockIdx.x / NCOUT, c = blockIdx.x % NCOUT, lane = threadIdx.x;
  float v[8]; float m = -1e30f;
#pragma unroll
  for (int i = 0; i < 8; ++i){
    v[i] = det[((size_t)(b * PDIM) + lane + 64 * i) * NCOUT + c];
    m = fmaxf(m, v[i]);
  }
  m = waveMax(m);
  float s = 0.f;
#pragma unroll
  for (int i = 0; i < 8; ++i){ v[i] = expf(v[i] - m); s += v[i]; }
  s = waveSum(s);
  float r = 1.f / s;
#pragma unroll
  for (int i = 0; i < 8; ++i)
    dp[((size_t)(b * PDIM) + lane + 64 * i) * NCOUT + c] = v[i] * r;
}

// class softmax + joint + scatter back to original order + ctx copy + video accumulation
__global__ void kfinal(const float* __restrict__ cls_s, const float* __restrict__ det_s,
                       const float* __restrict__ dps, const float* __restrict__ tok,
                       const int* __restrict__ sidx, float* __restrict__ out){
  int blk = blockIdx.x;
  int b = blk >> 9, j = blk & 511;
  int lane = threadIdx.x;
  int p = sidx[b * PDIM + j];
  float* video = out;
  float* joint = out + 240;
  float* clso  = out + 123120;
  float* deto  = out + 246000;
  float* ctxo  = out + 368880;
  size_t rs = (size_t)(b * PDIM + j) * NCOUT;
  size_t ro = (size_t)(b * PDIM + p) * NCOUT;
  float lc = (lane < NCOUT) ? cls_s[rs + lane] : -1e30f;
  float m = waveMax(lc);
  float e = (lane < NCOUT) ? expf(lc - m) : 0.f;
  float s = waveSum(e);
  float cp = e / s;
  if (lane < NCOUT){
    float dv  = det_s[rs + lane];
    float dpv = dps[rs + lane];
    float jp  = cp * dpv;
    clso[ro + lane] = lc;
    deto[ro + lane] = dv;
    joint[ro + lane] = jp;
    atomicAdd(&video[b * NCOUT + lane], jp);
  }
  const float* tr = tok + (size_t)(b * PDIM + j) * DMODEL;
  float* cr = ctxo + (size_t)(b * PDIM + p) * DMODEL;
  for (int c = lane; c < DMODEL; c += 64) cr[c] = tr[c];
}

extern "C" void kernel_launch(void* const* d_in, const int* in_sizes, int n_in,
                              void* d_out, int out_size, void* d_ws, size_t ws_size,
                              hipStream_t stream) {
  const float* x      = (const float*)d_in[0];
  const int*   boxes  = (const int*)d_in[1];
  const float* proj_w = (const float*)d_in[2];
  const float* proj_b = (const float*)d_in[3];
  const float* pos_w1 = (const float*)d_in[4];
  const float* pos_b1 = (const float*)d_in[5];
  const float* pos_w2 = (const float*)d_in[6];
  const float* pos_b2 = (const float*)d_in[7];
  const float* qkv_w  = (const float*)d_in[8];
  const float* qkv_b  = (const float*)d_in[9];
  const float* out_w  = (const float*)d_in[10];
  const float* out_b  = (const float*)d_in[11];
  const float* ln1_g  = (const float*)d_in[12];
  const float* ln1_b  = (const float*)d_in[13];
  const float* ff1_w  = (const float*)d_in[14];
  const float* ff1_b  = (const float*)d_in[15];
  const float* ff2_w  = (const float*)d_in[16];
  const float* ff2_b  = (const float*)d_in[17];
  const float* ln2_g  = (const float*)d_in[18];
  const float* ln2_b  = (const float*)d_in[19];
  const float* cls_w  = (const float*)d_in[20];
  const float* cls_b  = (const float*)d_in[21];
  const float* det_w  = (const float*)d_in[22];
  const float* det_b  = (const float*)d_in[23];
  float* out = (float*)d_out;
  float* ws  = (float*)d_ws;

  // workspace layout (float offsets)
  const size_t oA    = 0;                       // region1: A (16,777,216 fl) then qkv/hbuf/obuf/x1
  const size_t oQkv  = 0;
  const size_t oHbuf = oQkv + (size_t)BDIM * PDIM * 1536;       //  6,291,456
  const size_t oObuf = oHbuf + (size_t)BDIM * PDIM * 1024;      // 10,485,760
  const size_t oX1   = oObuf + (size_t)BDIM * PDIM * 512;       // 12,582,912
  const size_t oW    = 16777216;                // csumW / S (8,388,608 fl)
  const size_t oTot  = oW + 8388608;
  const size_t oOff  = oTot + 32768;
  const size_t oSidx = oOff + 32768;            // int[4096]
  const size_t oWcat = oSidx + 4096;
  const size_t oBcat = oWcat + 2097152;
  const size_t oTok  = oBcat + 512;
  const size_t oTok2 = oTok + 2097152;
  const size_t oCls  = oTok2 + 2097152;
  const size_t oDet  = oCls + 122880;
  const size_t oDp   = oDet + 122880;

  float* A    = ws + oA;
  float* csum = ws + oW;      // aliases S later
  float* Sb   = ws + oW;
  float* tot  = ws + oTot;
  float* offp = ws + oOff;
  int*   sidx = (int*)(ws + oSidx);
  float* Wcat = ws + oWcat;
  float* bcat = ws + oBcat;
  float* tok  = ws + oTok;
  float* tok2 = ws + oTok2;
  float* qkvp = ws + oQkv;
  float* hbuf = ws + oHbuf;
  float* obuf = ws + oObuf;
  float* x1   = ws + oX1;
  float* clsS = ws + oCls;
  float* detS = ws + oDet;
  float* dpS  = ws + oDp;

  kzero<<<1, 256, 0, stream>>>(out, 240);
  kscan<<<128, 256, 0, stream>>>(x, csum, tot);
  koff<<<16, 256, 0, stream>>>(tot, offp);
  ksort<<<BDIM, 512, 0, stream>>>(boxes, sidx);
  kwcat<<<8192, 256, 0, stream>>>(proj_w, pos_w2, Wcat);
  kbcat<<<2, 256, 0, stream>>>(proj_b, pos_b2, bcat);
  kspp<<<BDIM * PDIM, 256, 0, stream>>>(csum, offp, boxes, sidx, pos_w1, pos_b1, A);

  // G1: tok = A @ Wcat^T + bcat   [4096, 512] K=4096
  gemm_nt<<<dim3(8, 64, 1), 256, 0, stream>>>(
      4096, 512, 4096, A, 4096, 0, 0, Wcat, 4096, 0, 0, tok, 512, 0, 0,
      1, 1.f, bcat, nullptr, 0);

  const float scale = 0.08838834764831845f;  // 1/sqrt(128)
  for (int l = 0; l < 2; ++l){
    const float* qw = qkv_w + (size_t)l * 1536 * 512;
    const float* qb = qkv_b + (size_t)l * 1536;
    const float* ow = out_w + (size_t)l * 512 * 512;
    const float* obv = out_b + (size_t)l * 512;
    const float* f1w = ff1_w + (size_t)l * 1024 * 512;
    const float* f1b = ff1_b + (size_t)l * 1024;
    const float* f2w = ff2_w + (size_t)l * 512 * 1024;
    const float* f2b = ff2_b + (size_t)l * 512;

    // qkv = tok @ qkv_w^T + qkv_b   [4096, 1536]
    gemm_nt<<<dim3(24, 64, 1), 256, 0, stream>>>(
        4096, 1536, 512, tok, 512, 0, 0, qw, 512, 0, 0, qkvp, 1536, 0, 0,
        1, 1.f, qb, nullptr, 0);
    // scores: S[z] = scale * Q K^T, z = b*4+h
    gemm_nt<<<dim3(8, 8, 32), 256, 0, stream>>>(
        512, 512, 128,
        qkvp, 1536, (long long)512 * 1536, 128,
        qkvp + 512, 1536, (long long)512 * 1536, 128,
        Sb, 512, (long long)4 * 512 * 512, (long long)512 * 512,
        4, scale, nullptr, nullptr, 0);
    ksm_rows<<<32 * 512, 64, 0, stream>>>(Sb);
    // O = S @ V -> obuf[b][i][h*128+n]
    gemm_nn<<<dim3(2, 8, 32), 256, 0, stream>>>(
        512, 128, 512,
        Sb, 512, (long long)4 * 512 * 512, (long long)512 * 512,
        qkvp + 1024, 1536, (long long)512 * 1536, 128,
        obuf, 512, (long long)512 * 512, 128, 4);
    // x1 = obuf @ out_w^T + out_b + tok
    gemm_nt<<<dim3(8, 64, 1), 256, 0, stream>>>(
        4096, 512, 512, obuf, 512, 0, 0, ow, 512, 0, 0, x1, 512, 0, 0,
        1, 1.f, obv, tok, 0);
    kln<<<4096, 64, 0, stream>>>(x1, tok2, ln1_g + l * 512, ln1_b + l * 512);
    // hbuf = gelu(tok2 @ ff1^T + b1)
    gemm_nt<<<dim3(16, 64, 1), 256, 0, stream>>>(
        4096, 1024, 512, tok2, 512, 0, 0, f1w, 512, 0, 0, hbuf, 1024, 0, 0,
        1, 1.f, f1b, nullptr, 1);
    // x1 = hbuf @ ff2^T + b2 + tok2
    gemm_nt<<<dim3(8, 64, 1), 256, 0, stream>>>(
        4096, 512, 1024, hbuf, 1024, 0, 0, f2w, 1024, 0, 0, x1, 512, 0, 0,
        1, 1.f, f2b, tok2, 0);
    kln<<<4096, 64, 0, stream>>>(x1, tok, ln2_g + l * 512, ln2_b + l * 512);
  }

  // heads (sorted space)
  gemm_nt<<<dim3(1, 64, 1), 256, 0, stream>>>(
      4096, 30, 512, tok, 512, 0, 0, cls_w, 512, 0, 0, clsS, 30, 0, 0,
      1, 1.f, cls_b, nullptr, 0);
  gemm_nt<<<dim3(1, 64, 1), 256, 0, stream>>>(
      4096, 30, 512, tok, 512, 0, 0, det_w, 512, 0, 0, detS, 30, 0, 0,
      1, 1.f, det_b, nullptr, 0);
  kdetsm<<<BDIM * NCOUT, 64, 0, stream>>>(detS, dpS);
  kfinal<<<BDIM * PDIM, 64, 0, stream>>>(clsS, detS, dpS, tok, sidx, out);
}

// Round 3
// 865.410 us; speedup vs baseline: 3.3222x; 3.3222x over previous
//
#include <hip/hip_runtime.h>

#define TDIM 2048
#define CDIM 512
#define BDIM 8
#define PDIM 512
#define DMODEL 512
#define NCOUT 30
#define SPPOUT 3584
#define AKDIM 4096   // SPPOUT + DMODEL
#define LDK 40       // padded LDS k-stride (bf16 units): 40*2B=80B -> conflict-free

typedef __attribute__((ext_vector_type(8))) short short8;
typedef __attribute__((ext_vector_type(4))) float f32x4;

__device__ __forceinline__ short f2b(float f){
  unsigned u = __float_as_uint(f);
  unsigned r = (u + 0x7fffu + ((u >> 16) & 1u)) >> 16;
  return (short)r;
}

__device__ __forceinline__ float waveSum(float v){
#pragma unroll
  for (int o = 32; o > 0; o >>= 1) v += __shfl_xor(v, o);
  return v;
}
__device__ __forceinline__ float waveMax(float v){
#pragma unroll
  for (int o = 32; o > 0; o >>= 1) v = fmaxf(v, __shfl_xor(v, o));
  return v;
}

__global__ void kzero(float* p, int n){
  int i = blockIdx.x * 256 + threadIdx.x;
  if (i < n) p[i] = 0.f;
}

__global__ void kconv(const float* __restrict__ s, short* __restrict__ d, int n){
  int i = blockIdx.x * 256 + threadIdx.x;
  if (i < n) d[i] = f2b(s[i]);
}

// Chunked inclusive scan along T. W[b][t][c] = sum x[b,c, chunkstart..t], chunk=(t>>8)
__global__ void kscan(const float* __restrict__ x, float* __restrict__ W, float* __restrict__ tot){
  int idx = blockIdx.x;             // b*16 + ch*2 + cg
  int b = idx >> 4, rem = idx & 15, ch = rem >> 1, cg = rem & 1;
  int c = cg * 256 + threadIdx.x;
  const float* xp = x + ((size_t)(b * CDIM + c)) * TDIM + ch * 256;
  float* wp = W + ((size_t)b * TDIM + ch * 256) * CDIM + c;
  float run = 0.f;
  for (int tl = 0; tl < 256; tl += 4){
    float4 v = *(const float4*)(xp + tl);
    run += v.x; wp[(size_t)(tl + 0) * CDIM] = run;
    run += v.y; wp[(size_t)(tl + 1) * CDIM] = run;
    run += v.z; wp[(size_t)(tl + 2) * CDIM] = run;
    run += v.w; wp[(size_t)(tl + 3) * CDIM] = run;
  }
  tot[((size_t)b * 8 + ch) * CDIM + c] = run;
}

__global__ void koff(const float* __restrict__ tot, float* __restrict__ off){
  int b = blockIdx.x >> 1, cg = blockIdx.x & 1;
  int c = cg * 256 + threadIdx.x;
  float run = 0.f;
  for (int ch = 0; ch < 8; ++ch){
    off[((size_t)b * 8 + ch) * CDIM + c] = run;
    run += tot[((size_t)b * 8 + ch) * CDIM + c];
  }
}

// Stable argsort by center: key = ((s+e)<<9) | p  (unique keys -> stable)
__global__ void ksort(const int* __restrict__ boxes, int* __restrict__ sidx){
  __shared__ unsigned key[PDIM];
  int b = blockIdx.x, t = threadIdx.x;
  int s = boxes[(size_t)(b * PDIM + t) * 2];
  int e = boxes[(size_t)(b * PDIM + t) * 2 + 1];
  key[t] = ((unsigned)(s + e) << 9) | (unsigned)t;
  __syncthreads();
  for (int k = 2; k <= PDIM; k <<= 1){
    for (int j = k >> 1; j > 0; j >>= 1){
      int ixj = t ^ j;
      if (ixj > t){
        unsigned a = key[t], c2 = key[ixj];
        bool up = ((t & k) == 0);
        bool doswap = up ? (a > c2) : (a < c2);
        if (doswap){ key[t] = c2; key[ixj] = a; }
      }
      __syncthreads();
    }
  }
  sidx[b * PDIM + t] = (int)(key[t] & 511u);
}

// Build Wcat = [proj_w | pos_w2]  (512 x 4096) as bf16
__global__ void kwcat(const float* __restrict__ pw, const float* __restrict__ pw2, short* __restrict__ Wc){
  int i = blockIdx.x * 256 + threadIdx.x;
  int r = i >> 12, k = i & 4095;
  float v = (k < SPPOUT) ? pw[(size_t)r * SPPOUT + k] : pw2[(size_t)r * DMODEL + (k - SPPOUT)];
  Wc[i] = f2b(v);
}
__global__ void kbcat(const float* __restrict__ pb, const float* __restrict__ pb2, float* __restrict__ bc){
  int i = blockIdx.x * 256 + threadIdx.x;
  if (i < DMODEL) bc[i] = pb[i] + pb2[i];
}

// SPP pooling + pos-MLP hidden, staged in sorted order as bf16: A[b][j][0..4095]
__global__ void kspp(const float* __restrict__ W, const float* __restrict__ off,
                     const int* __restrict__ boxes, const int* __restrict__ sidx,
                     const float* __restrict__ pw1, const float* __restrict__ pb1,
                     short* __restrict__ A){
  int blk = blockIdx.x;
  int b = blk >> 9, j = blk & 511;
  int p = sidx[b * PDIM + j];
  int s0 = boxes[(size_t)(b * PDIM + p) * 2];
  int e0 = boxes[(size_t)(b * PDIM + p) * 2 + 1];
  int start = min(max(s0, 0), TDIM - 1);
  int end   = min(max(e0, 1), TDIM);
  if (end <= start) end = min(start + 1, TDIM);
  int n = end - start;

  int lo[7], hi[7], cb[7], cl[7];
  {
    const int Ls[3] = {1, 2, 4};
    const int Bo[3] = {0, 512, 1536};
    int q = 0;
    for (int li = 0; li < 3; ++li){
      int L = Ls[li];
      for (int i = 0; i < L; ++i){
        lo[q] = start + (i * n) / L;
        hi[q] = start + ((i + 1) * n + L - 1) / L;
        cb[q] = Bo[li] + i;
        cl[q] = L;
        ++q;
      }
    }
  }
  float s_f = (float)s0, e_f = (float)e0;
  float px = (s_f + e_f) * 0.5f / (float)TDIM;
  float py = fmaxf(e_f - s_f, 1.f) / (float)TDIM;
  short* Ar = A + (size_t)(b * PDIM + j) * AKDIM;
  const float* Wb = W + (size_t)b * TDIM * CDIM;
  const float* ob = off + (size_t)b * 8 * CDIM;
  for (int c = threadIdx.x; c < CDIM; c += 256){
#pragma unroll
    for (int q = 0; q < 7; ++q){
      int l = lo[q], h = hi[q];
      float fl = (l == 0) ? 0.f : (Wb[(size_t)(l - 1) * CDIM + c] + ob[((l - 1) >> 8) * CDIM + c]);
      float fh = Wb[(size_t)(h - 1) * CDIM + c] + ob[((h - 1) >> 8) * CDIM + c];
      Ar[cb[q] + c * cl[q]] = f2b((fh - fl) / (float)(h - l));
    }
    float hv = pw1[c * 2] * px + pw1[c * 2 + 1] * py + pb1[c];
    Ar[SPPOUT + c] = f2b(fmaxf(hv, 0.f));
  }
}

// MFMA bf16 GEMM (nt): C[M,N] = act(alpha * A[M,K] @ B[N,K]^T + bias + resid)
// 128x128 tile, 4 waves of 64x64 (4x4 x mfma_16x16x32), batched over z.
// Writes optional f32 (Cf) and/or bf16 (Cb) outputs with identical element indexing.
__global__ __launch_bounds__(256) void gemm_bt(
    int M, int N, int K,
    const short* __restrict__ A, int lda, long long sAb, long long sAh,
    const short* __restrict__ B, int ldb, long long sBb, long long sBh,
    float* __restrict__ Cf, short* __restrict__ Cb, int ldc, long long sCb, long long sCh,
    int hdiv, float alpha,
    const float* __restrict__ bias, const float* __restrict__ resid, int act)
{
  __shared__ short8 As8[128 * LDK / 8];
  __shared__ short8 Bs8[128 * LDK / 8];
  short* As = (short*)As8;
  short* Bs = (short*)Bs8;
  int z = blockIdx.z;
  int zb = z / hdiv, zh = z - zb * hdiv;
  A += (size_t)zb * sAb + (size_t)zh * sAh;
  B += (size_t)zb * sBb + (size_t)zh * sBh;
  size_t coff = (size_t)zb * sCb + (size_t)zh * sCh;
  int rowBase = blockIdx.y * 128, colBase = blockIdx.x * 128;
  int t = threadIdx.x;
  int lane = t & 63;
  int wave = t >> 6;
  int wm = (wave >> 1) * 64, wn = (wave & 1) * 64;
  int lm = lane & 15, quad = lane >> 4;
  int srow = t >> 2, sseg = t & 3;

  f32x4 zero4 = {0.f, 0.f, 0.f, 0.f};
  f32x4 acc[4][4];
#pragma unroll
  for (int i = 0; i < 4; ++i)
#pragma unroll
    for (int j = 0; j < 4; ++j) acc[i][j] = zero4;

  for (int k0 = 0; k0 < K; k0 += 32){
#pragma unroll
    for (int it = 0; it < 2; ++it){
      int r = srow + it * 64;
      int gr = min(rowBase + r, M - 1);            // defensive clamp (grids are exact)
      short8 va = *(const short8*)(A + (size_t)gr * lda + k0 + sseg * 8);
      *(short8*)(As + r * LDK + sseg * 8) = va;
      int gc = colBase + r;
      short8 vb = {0, 0, 0, 0, 0, 0, 0, 0};
      if (gc < N) vb = *(const short8*)(B + (size_t)gc * ldb + k0 + sseg * 8);
      *(short8*)(Bs + r * LDK + sseg * 8) = vb;
    }
    __syncthreads();
    short8 af[4], bfr[4];
#pragma unroll
    for (int i = 0; i < 4; ++i)
      af[i] = *(const short8*)(As + (wm + i * 16 + lm) * LDK + quad * 8);
#pragma unroll
    for (int j = 0; j < 4; ++j)
      bfr[j] = *(const short8*)(Bs + (wn + j * 16 + lm) * LDK + quad * 8);
#pragma unroll
    for (int i = 0; i < 4; ++i)
#pragma unroll
      for (int j = 0; j < 4; ++j)
        acc[i][j] = __builtin_amdgcn_mfma_f32_16x16x32_bf16(af[i], bfr[j], acc[i][j], 0, 0, 0);
    __syncthreads();
  }

#pragma unroll
  for (int i = 0; i < 4; ++i){
#pragma unroll
    for (int j = 0; j < 4; ++j){
#pragma unroll
      for (int r = 0; r < 4; ++r){
        int row = rowBase + wm + i * 16 + quad * 4 + r;
        int col = colBase + wn + j * 16 + lm;
        if (row < M && col < N){
          float v = acc[i][j][r] * alpha;
          if (bias) v += bias[col];
          size_t ci = coff + (size_t)row * ldc + col;
          if (resid) v += resid[ci];
          if (act) v = 0.5f * v * (1.f + erff(v * 0.7071067811865476f));
          if (Cf) Cf[ci] = v;
          if (Cb) Cb[ci] = f2b(v);
        }
      }
    }
  }
}

// softmax over 512-wide rows: f32 in -> bf16 out
__global__ void ksm_rows(const float* __restrict__ S, short* __restrict__ Sb){
  int row = blockIdx.x, lane = threadIdx.x;
  const float* p = S + (size_t)row * 512;
  short* q = Sb + (size_t)row * 512;
  float v[8]; float m = -1e30f;
#pragma unroll
  for (int i = 0; i < 8; ++i){ v[i] = p[lane + 64 * i]; m = fmaxf(m, v[i]); }
  m = waveMax(m);
  float s = 0.f;
#pragma unroll
  for (int i = 0; i < 8; ++i){ v[i] = expf(v[i] - m); s += v[i]; }
  s = waveSum(s);
  float r = 1.f / s;
#pragma unroll
  for (int i = 0; i < 8; ++i) q[lane + 64 * i] = f2b(v[i] * r);
}

// transpose V (from qkv bf16 buffer) into Vt[b*4+h][128][512]
__global__ void kvt(const short* __restrict__ qkvb, short* __restrict__ Vt){
  __shared__ short T[32][33];
  int bh = blockIdx.x, pt = blockIdx.y, nt = blockIdx.z;
  int b = bh >> 2, h = bh & 3;
  int tx = threadIdx.x, ty = threadIdx.y;
  const short* src = qkvb + (size_t)(b * 512) * 1536 + 1024 + h * 128;
  int p0 = pt * 32, n0 = nt * 32;
#pragma unroll
  for (int q = 0; q < 4; ++q)
    T[ty * 4 + q][tx] = src[(size_t)(p0 + ty * 4 + q) * 1536 + n0 + tx];
  __syncthreads();
  short* dst = Vt + (size_t)bh * 128 * 512;
#pragma unroll
  for (int q = 0; q < 4; ++q)
    dst[(size_t)(n0 + ty * 4 + q) * 512 + p0 + tx] = T[tx][ty * 4 + q];
}

// LayerNorm: f32 in -> f32 + bf16 out
__global__ void kln(const float* __restrict__ X, float* __restrict__ Y, short* __restrict__ Yb,
                    const float* __restrict__ g, const float* __restrict__ bb){
  int row = blockIdx.x, lane = threadIdx.x;
  const float* xr = X + (size_t)row * DMODEL;
  float v[8]; float s = 0.f;
#pragma unroll
  for (int i = 0; i < 8; ++i){ v[i] = xr[lane + 64 * i]; s += v[i]; }
  s = waveSum(s);
  float m = s * (1.f / DMODEL);
  float q = 0.f;
#pragma unroll
  for (int i = 0; i < 8; ++i){ float d = v[i] - m; q += d * d; }
  q = waveSum(q);
  float inv = rsqrtf(q * (1.f / DMODEL) + 1e-5f);
  float* yr = Y + (size_t)row * DMODEL;
  short* yb = Yb + (size_t)row * DMODEL;
#pragma unroll
  for (int i = 0; i < 8; ++i){
    int c = lane + 64 * i;
    float o = (v[i] - m) * inv * g[c] + bb[c];
    yr[c] = o;
    yb[c] = f2b(o);
  }
}

// det softmax over P (columns), in sorted space
__global__ void kdetsm(const float* __restrict__ det, float* __restrict__ dp){
  int b = blockIdx.x / NCOUT, c = blockIdx.x % NCOUT, lane = threadIdx.x;
  float v[8]; float m = -1e30f;
#pragma unroll
  for (int i = 0; i < 8; ++i){
    v[i] = det[((size_t)(b * PDIM) + lane + 64 * i) * NCOUT + c];
    m = fmaxf(m, v[i]);
  }
  m = waveMax(m);
  float s = 0.f;
#pragma unroll
  for (int i = 0; i < 8; ++i){ v[i] = expf(v[i] - m); s += v[i]; }
  s = waveSum(s);
  float r = 1.f / s;
#pragma unroll
  for (int i = 0; i < 8; ++i)
    dp[((size_t)(b * PDIM) + lane + 64 * i) * NCOUT + c] = v[i] * r;
}

// class softmax + joint + scatter back to original order + ctx copy + video accumulation
__global__ void kfinal(const float* __restrict__ cls_s, const float* __restrict__ det_s,
                       const float* __restrict__ dps, const float* __restrict__ tok,
                       const int* __restrict__ sidx, float* __restrict__ out){
  int blk = blockIdx.x;
  int b = blk >> 9, j = blk & 511;
  int lane = threadIdx.x;
  int p = sidx[b * PDIM + j];
  float* video = out;
  float* joint = out + 240;
  float* clso  = out + 123120;
  float* deto  = out + 246000;
  float* ctxo  = out + 368880;
  size_t rs = (size_t)(b * PDIM + j) * NCOUT;
  size_t ro = (size_t)(b * PDIM + p) * NCOUT;
  float lc = (lane < NCOUT) ? cls_s[rs + lane] : -1e30f;
  float m = waveMax(lc);
  float e = (lane < NCOUT) ? expf(lc - m) : 0.f;
  float s = waveSum(e);
  float cp = e / s;
  if (lane < NCOUT){
    float dv  = det_s[rs + lane];
    float dpv = dps[rs + lane];
    float jp  = cp * dpv;
    clso[ro + lane] = lc;
    deto[ro + lane] = dv;
    joint[ro + lane] = jp;
    atomicAdd(&video[b * NCOUT + lane], jp);
  }
  const float* tr = tok + (size_t)(b * PDIM + j) * DMODEL;
  float* cr = ctxo + (size_t)(b * PDIM + p) * DMODEL;
  for (int c = lane; c < DMODEL; c += 64) cr[c] = tr[c];
}

extern "C" void kernel_launch(void* const* d_in, const int* in_sizes, int n_in,
                              void* d_out, int out_size, void* d_ws, size_t ws_size,
                              hipStream_t stream) {
  const float* x      = (const float*)d_in[0];
  const int*   boxes  = (const int*)d_in[1];
  const float* proj_w = (const float*)d_in[2];
  const float* proj_b = (const float*)d_in[3];
  const float* pos_w1 = (const float*)d_in[4];
  const float* pos_b1 = (const float*)d_in[5];
  const float* pos_w2 = (const float*)d_in[6];
  const float* pos_b2 = (const float*)d_in[7];
  const float* qkv_w  = (const float*)d_in[8];
  const float* qkv_b  = (const float*)d_in[9];
  const float* out_w  = (const float*)d_in[10];
  const float* out_b  = (const float*)d_in[11];
  const float* ln1_g  = (const float*)d_in[12];
  const float* ln1_b  = (const float*)d_in[13];
  const float* ff1_w  = (const float*)d_in[14];
  const float* ff1_b  = (const float*)d_in[15];
  const float* ff2_w  = (const float*)d_in[16];
  const float* ff2_b  = (const float*)d_in[17];
  const float* ln2_g  = (const float*)d_in[18];
  const float* ln2_b  = (const float*)d_in[19];
  const float* cls_w  = (const float*)d_in[20];
  const float* cls_b  = (const float*)d_in[21];
  const float* det_w  = (const float*)d_in[22];
  const float* det_b  = (const float*)d_in[23];
  float* out = (float*)d_out;
  float* ws  = (float*)d_ws;

  // ---- workspace layout (FLOAT units; bf16 regions sized as shorts/2) ----
  // region1 (9,437,184 fl): Abf [0, 8,388,608) dies after G1, then:
  //   qkvb  [0, 3,145,728)            = 6,291,456 shorts  (full 4096x1536)
  //   Vt    [3,145,728, 4,194,304)    = 2,097,152 shorts
  //   obufb [4,194,304, 5,242,880)    = 2,097,152 shorts
  //   x1    [5,242,880, 7,340,032)    f32, dies after last kln
  //   hbufb [7,340,032, 9,437,184)    = 4,194,304 shorts
  //   clsS/detS/dpS reuse x1's slot after x1 dead
  const size_t oR1    = 0;
  const size_t oS     = 9437184;    // csum then scores S: 8,388,608 fl
  const size_t oSbf   = 17825792;   // 8,388,608 shorts = 4,194,304 fl
  const size_t oTok   = 22020096;   // 2,097,152 fl
  const size_t oTokb  = 24117248;   // 1,048,576 fl
  const size_t oTok2  = 25165824;   // 2,097,152 fl
  const size_t oTok2b = 27262976;   // 1,048,576 fl
  const size_t oWcat  = 28311552;   // 1,048,576 fl
  const size_t oBcat  = 29360128;   // 512 fl
  const size_t oWq    = 29360640;   // 786,432 fl
  const size_t oWo    = 30147072;   // 262,144 fl
  const size_t oWf1   = 30409216;   // 524,288 fl
  const size_t oWf2   = 30933504;   // 524,288 fl
  const size_t oWcls  = 31457792;   // 7,680 fl
  const size_t oWdet  = 31465472;   // 7,680 fl
  const size_t oTot   = 31473152;   // 32,768 fl
  const size_t oOff   = 31505920;   // 32,768 fl
  const size_t oSidx  = 31538688;   // 1,024 fl -> end 31,539,712 fl (126.2 MB)

  short* Abf   = (short*)(ws + oR1);
  short* qkvb  = (short*)(ws + oR1);
  short* Vt    = (short*)(ws + oR1 + 3145728);
  short* obufb = (short*)(ws + oR1 + 4194304);
  float* x1    = ws + oR1 + 5242880;
  short* hbufb = (short*)(ws + oR1 + 7340032);
  float* clsS  = ws + oR1 + 5242880;
  float* detS  = ws + oR1 + 5365760;
  float* dpS   = ws + oR1 + 5488640;
  float* csum  = ws + oS;
  float* S     = ws + oS;
  short* Sbf   = (short*)(ws + oSbf);
  float* tok   = ws + oTok;
  short* tokb  = (short*)(ws + oTokb);
  float* tok2  = ws + oTok2;
  short* tok2b = (short*)(ws + oTok2b);
  short* Wcatb = (short*)(ws + oWcat);
  float* bcat  = ws + oBcat;
  short* Wq    = (short*)(ws + oWq);
  short* Wo    = (short*)(ws + oWo);
  short* Wf1   = (short*)(ws + oWf1);
  short* Wf2   = (short*)(ws + oWf2);
  short* Wcls  = (short*)(ws + oWcls);
  short* Wdet  = (short*)(ws + oWdet);
  float* tot   = ws + oTot;
  float* offp  = ws + oOff;
  int*   sidx  = (int*)(ws + oSidx);

  kzero<<<1, 256, 0, stream>>>(out, 240);
  kscan<<<128, 256, 0, stream>>>(x, csum, tot);
  koff<<<16, 256, 0, stream>>>(tot, offp);
  ksort<<<BDIM, 512, 0, stream>>>(boxes, sidx);
  kwcat<<<8192, 256, 0, stream>>>(proj_w, pos_w2, Wcatb);
  kbcat<<<2, 256, 0, stream>>>(proj_b, pos_b2, bcat);
  kconv<<<6144, 256, 0, stream>>>(qkv_w, Wq, 2 * 1536 * 512);
  kconv<<<2048, 256, 0, stream>>>(out_w, Wo, 2 * 512 * 512);
  kconv<<<4096, 256, 0, stream>>>(ff1_w, Wf1, 2 * 1024 * 512);
  kconv<<<4096, 256, 0, stream>>>(ff2_w, Wf2, 2 * 512 * 1024);
  kconv<<<60, 256, 0, stream>>>(cls_w, Wcls, NCOUT * 512);
  kconv<<<60, 256, 0, stream>>>(det_w, Wdet, NCOUT * 512);
  kspp<<<BDIM * PDIM, 256, 0, stream>>>(csum, offp, boxes, sidx, pos_w1, pos_b1, Abf);

  // G1: tok = Abf @ Wcat^T + bcat   [4096, 512] K=4096  (f32 + bf16 out)
  gemm_bt<<<dim3(4, 32, 1), 256, 0, stream>>>(
      4096, 512, 4096, Abf, 4096, 0, 0, Wcatb, 4096, 0, 0,
      tok, tokb, 512, 0, 0, 1, 1.f, bcat, nullptr, 0);

  const float scale = 0.08838834764831845f;  // 1/sqrt(128)
  for (int l = 0; l < 2; ++l){
    const short* qw  = Wq  + (size_t)l * 1536 * 512;
    const short* ow  = Wo  + (size_t)l * 512 * 512;
    const short* f1w = Wf1 + (size_t)l * 1024 * 512;
    const short* f2w = Wf2 + (size_t)l * 512 * 1024;
    const float* qb  = qkv_b + (size_t)l * 1536;
    const float* obv = out_b + (size_t)l * 512;
    const float* f1b = ff1_b + (size_t)l * 1024;
    const float* f2b_ = ff2_b + (size_t)l * 512;

    // qkv = tok @ qkv_w^T + qkv_b   [4096, 1536] (bf16 out only)
    gemm_bt<<<dim3(12, 32, 1), 256, 0, stream>>>(
        4096, 1536, 512, tokb, 512, 0, 0, qw, 512, 0, 0,
        nullptr, qkvb, 1536, 0, 0, 1, 1.f, qb, nullptr, 0);
    // scores: S[bh] = scale * Q K^T (f32 out)
    gemm_bt<<<dim3(4, 4, 32), 256, 0, stream>>>(
        512, 512, 128,
        qkvb, 1536, (long long)512 * 1536, 128,
        qkvb + 512, 1536, (long long)512 * 1536, 128,
        S, nullptr, 512, (long long)4 * 512 * 512, (long long)512 * 512,
        4, scale, nullptr, nullptr, 0);
    ksm_rows<<<32 * 512, 64, 0, stream>>>(S, Sbf);
    kvt<<<dim3(32, 16, 4), dim3(32, 8), 0, stream>>>(qkvb, Vt);
    // O = P @ V^T -> obufb[b][q][h*128+n] (bf16)
    gemm_bt<<<dim3(1, 4, 32), 256, 0, stream>>>(
        512, 128, 512,
        Sbf, 512, (long long)4 * 512 * 512, (long long)512 * 512,
        Vt, 512, (long long)4 * 128 * 512, (long long)128 * 512,
        nullptr, obufb, 512, (long long)512 * 512, 128,
        4, 1.f, nullptr, nullptr, 0);
    // x1 = obufb @ out_w^T + out_b + tok (f32)
    gemm_bt<<<dim3(4, 32, 1), 256, 0, stream>>>(
        4096, 512, 512, obufb, 512, 0, 0, ow, 512, 0, 0,
        x1, nullptr, 512, 0, 0, 1, 1.f, obv, tok, 0);
    kln<<<4096, 64, 0, stream>>>(x1, tok2, tok2b, ln1_g + l * 512, ln1_b + l * 512);
    // hbuf = gelu(tok2 @ ff1^T + b1) (bf16 only)
    gemm_bt<<<dim3(8, 32, 1), 256, 0, stream>>>(
        4096, 1024, 512, tok2b, 512, 0, 0, f1w, 512, 0, 0,
        nullptr, hbufb, 1024, 0, 0, 1, 1.f, f1b, nullptr, 1);
    // x1 = hbuf @ ff2^T + b2 + tok2 (f32)
    gemm_bt<<<dim3(4, 32, 1), 256, 0, stream>>>(
        4096, 512, 1024, hbufb, 1024, 0, 0, f2w, 1024, 0, 0,
        x1, nullptr, 512, 0, 0, 1, 1.f, f2b_, tok2, 0);
    kln<<<4096, 64, 0, stream>>>(x1, tok, tokb, ln2_g + l * 512, ln2_b + l * 512);
  }

  // heads (sorted space, f32 logits) — these overwrite x1's slot (x1 dead)
  gemm_bt<<<dim3(1, 32, 1), 256, 0, stream>>>(
      4096, NCOUT, 512, tokb, 512, 0, 0, Wcls, 512, 0, 0,
      clsS, nullptr, NCOUT, 0, 0, 1, 1.f, cls_b, nullptr, 0);
  gemm_bt<<<dim3(1, 32, 1), 256, 0, stream>>>(
      4096, NCOUT, 512, tokb, 512, 0, 0, Wdet, 512, 0, 0,
      detS, nullptr, NCOUT, 0, 0, 1, 1.f, det_b, nullptr, 0);
  kdetsm<<<BDIM * NCOUT, 64, 0, stream>>>(detS, dpS);
  kfinal<<<BDIM * PDIM, 64, 0, stream>>>(clsS, detS, dpS, tok, sidx, out);
}

// Round 4
// 610.118 us; speedup vs baseline: 4.7122x; 1.4184x over previous
//
#include <hip/hip_runtime.h>

#define TDIM 2048
#define CDIM 512
#define BDIM 8
#define PDIM 512
#define DMODEL 512
#define NCOUT 30
#define SPPOUT 3584
#define AKDIM 4096   // SPPOUT + DMODEL

typedef __attribute__((ext_vector_type(8))) short short8;
typedef __attribute__((ext_vector_type(4))) float f32x4;

typedef const __attribute__((address_space(1))) void* as1cv;
typedef __attribute__((address_space(3))) void* as3v;

// async global->LDS, 16B per lane; LDS dest must be wave-uniform base + lane*16
__device__ __forceinline__ void gl_lds16(const short* g, short* l){
  __builtin_amdgcn_global_load_lds((as1cv)g, (as3v)l, 16, 0, 0);
}

__device__ __forceinline__ short f2b(float f){
  unsigned u = __float_as_uint(f);
  unsigned r = (u + 0x7fffu + ((u >> 16) & 1u)) >> 16;
  return (short)r;
}

__device__ __forceinline__ float waveSum(float v){
#pragma unroll
  for (int o = 32; o > 0; o >>= 1) v += __shfl_xor(v, o);
  return v;
}
__device__ __forceinline__ float waveMax(float v){
#pragma unroll
  for (int o = 32; o > 0; o >>= 1) v = fmaxf(v, __shfl_xor(v, o));
  return v;
}

__global__ void kzero(float* p, int n){
  int i = blockIdx.x * 256 + threadIdx.x;
  if (i < n) p[i] = 0.f;
}

__global__ void kconv(const float* __restrict__ s, short* __restrict__ d, int n){
  int i = blockIdx.x * 256 + threadIdx.x;
  if (i < n) d[i] = f2b(s[i]);
}

// Chunked inclusive scan along T: 16 chunks of 128. W[b][t][c] = sum x[b,c, chunkstart..t]
__global__ void kscan(const float* __restrict__ x, float* __restrict__ W, float* __restrict__ tot){
  int idx = blockIdx.x;             // b*32 + ch*2 + cg  (256 blocks)
  int b = idx >> 5, rem = idx & 31, ch = rem >> 1, cg = rem & 1;
  int c = cg * 256 + threadIdx.x;
  const float* xp = x + ((size_t)(b * CDIM + c)) * TDIM + ch * 128;
  float* wp = W + ((size_t)b * TDIM + ch * 128) * CDIM + c;
  float run = 0.f;
  for (int tl = 0; tl < 128; tl += 4){
    float4 v = *(const float4*)(xp + tl);
    run += v.x; wp[(size_t)(tl + 0) * CDIM] = run;
    run += v.y; wp[(size_t)(tl + 1) * CDIM] = run;
    run += v.z; wp[(size_t)(tl + 2) * CDIM] = run;
    run += v.w; wp[(size_t)(tl + 3) * CDIM] = run;
  }
  tot[((size_t)b * 16 + ch) * CDIM + c] = run;
}

__global__ void koff(const float* __restrict__ tot, float* __restrict__ off){
  int b = blockIdx.x >> 1, cg = blockIdx.x & 1;
  int c = cg * 256 + threadIdx.x;
  float run = 0.f;
  for (int ch = 0; ch < 16; ++ch){
    off[((size_t)b * 16 + ch) * CDIM + c] = run;
    run += tot[((size_t)b * 16 + ch) * CDIM + c];
  }
}

// Stable argsort by center: key = ((s+e)<<9) | p  (unique keys -> stable)
__global__ void ksort(const int* __restrict__ boxes, int* __restrict__ sidx){
  __shared__ unsigned key[PDIM];
  int b = blockIdx.x, t = threadIdx.x;
  int s = boxes[(size_t)(b * PDIM + t) * 2];
  int e = boxes[(size_t)(b * PDIM + t) * 2 + 1];
  key[t] = ((unsigned)(s + e) << 9) | (unsigned)t;
  __syncthreads();
  for (int k = 2; k <= PDIM; k <<= 1){
    for (int j = k >> 1; j > 0; j >>= 1){
      int ixj = t ^ j;
      if (ixj > t){
        unsigned a = key[t], c2 = key[ixj];
        bool up = ((t & k) == 0);
        bool doswap = up ? (a > c2) : (a < c2);
        if (doswap){ key[t] = c2; key[ixj] = a; }
      }
      __syncthreads();
    }
  }
  sidx[b * PDIM + t] = (int)(key[t] & 511u);
}

// Build Wcat = [proj_w | pos_w2]  (512 x 4096) as bf16
__global__ void kwcat(const float* __restrict__ pw, const float* __restrict__ pw2, short* __restrict__ Wc){
  int i = blockIdx.x * 256 + threadIdx.x;
  int r = i >> 12, k = i & 4095;
  float v = (k < SPPOUT) ? pw[(size_t)r * SPPOUT + k] : pw2[(size_t)r * DMODEL + (k - SPPOUT)];
  Wc[i] = f2b(v);
}
__global__ void kbcat(const float* __restrict__ pb, const float* __restrict__ pb2, float* __restrict__ bc){
  int i = blockIdx.x * 256 + threadIdx.x;
  if (i < DMODEL) bc[i] = pb[i] + pb2[i];
}

// SPP pooling + pos-MLP hidden, staged in sorted order as bf16: A[b][j][0..4095]
__global__ void kspp(const float* __restrict__ W, const float* __restrict__ off,
                     const int* __restrict__ boxes, const int* __restrict__ sidx,
                     const float* __restrict__ pw1, const float* __restrict__ pb1,
                     short* __restrict__ A){
  int blk = blockIdx.x;
  int b = blk >> 9, j = blk & 511;
  int p = sidx[b * PDIM + j];
  int s0 = boxes[(size_t)(b * PDIM + p) * 2];
  int e0 = boxes[(size_t)(b * PDIM + p) * 2 + 1];
  int start = min(max(s0, 0), TDIM - 1);
  int end   = min(max(e0, 1), TDIM);
  if (end <= start) end = min(start + 1, TDIM);
  int n = end - start;

  int lo[7], hi[7], cb[7], cl[7];
  {
    const int Ls[3] = {1, 2, 4};
    const int Bo[3] = {0, 512, 1536};
    int q = 0;
    for (int li = 0; li < 3; ++li){
      int L = Ls[li];
      for (int i = 0; i < L; ++i){
        lo[q] = start + (i * n) / L;
        hi[q] = start + ((i + 1) * n + L - 1) / L;
        cb[q] = Bo[li] + i;
        cl[q] = L;
        ++q;
      }
    }
  }
  float s_f = (float)s0, e_f = (float)e0;
  float px = (s_f + e_f) * 0.5f / (float)TDIM;
  float py = fmaxf(e_f - s_f, 1.f) / (float)TDIM;
  short* Ar = A + (size_t)(b * PDIM + j) * AKDIM;
  const float* Wb = W + (size_t)b * TDIM * CDIM;
  const float* ob = off + (size_t)b * 16 * CDIM;
  for (int c = threadIdx.x; c < CDIM; c += 256){
#pragma unroll
    for (int q = 0; q < 7; ++q){
      int l = lo[q], h = hi[q];
      float fl = (l == 0) ? 0.f : (Wb[(size_t)(l - 1) * CDIM + c] + ob[((l - 1) >> 7) * CDIM + c]);
      float fh = Wb[(size_t)(h - 1) * CDIM + c] + ob[((h - 1) >> 7) * CDIM + c];
      Ar[cb[q] + c * cl[q]] = f2b((fh - fl) / (float)(h - l));
    }
    float hv = pw1[c * 2] * px + pw1[c * 2 + 1] * py + pb1[c];
    Ar[SPPOUT + c] = f2b(fmaxf(hv, 0.f));
  }
}

// MFMA bf16 GEMM (nt): C[M,N] = act(alpha * A[M,K] @ B[N,K]^T + bias + resid)
// BN=128: 4 waves of 64x64; BN=64: 4 waves of 64x32. 128-row tiles, BK=32.
// global_load_lds direct staging (LDS stride 32 shorts, unpadded -> lane-contiguous).
template<int BN>
__global__ __launch_bounds__(256) void gemm_bt(
    int M, int N, int K,
    const short* __restrict__ A, int lda, long long sAb, long long sAh,
    const short* __restrict__ B, int ldb, long long sBb, long long sBh,
    float* __restrict__ Cf, short* __restrict__ Cb, int ldc, long long sCb, long long sCh,
    int hdiv, float alpha,
    const float* __restrict__ bias, const float* __restrict__ resid, int act)
{
  constexpr int JF = BN / 32;                 // B-frags per wave (4 or 2)
  __shared__ short As[128 * 32];
  __shared__ short Bs[BN * 32];
  int z = blockIdx.z;
  int zb = z / hdiv, zh = z - zb * hdiv;
  A += (size_t)zb * sAb + (size_t)zh * sAh;
  B += (size_t)zb * sBb + (size_t)zh * sBh;
  size_t coff = (size_t)zb * sCb + (size_t)zh * sCh;
  int rowBase = blockIdx.y * 128, colBase = blockIdx.x * BN;
  int t = threadIdx.x;
  int lane = t & 63;
  int wave = t >> 6;
  int wm = (wave >> 1) * 64, wn = (wave & 1) * (BN / 2);
  int lm = lane & 15, quad = lane >> 4;
  int srow = t >> 2, sseg = (t & 3) * 8;

  const short* Ag0 = A + (size_t)min(rowBase + srow, M - 1) * lda + sseg;
  const short* Ag1 = A + (size_t)min(rowBase + srow + 64, M - 1) * lda + sseg;
  const short* Bg0 = B + (size_t)min(colBase + srow, N - 1) * ldb + sseg;
  const short* Bg1 = B + (size_t)min(colBase + srow + 64, N - 1) * ldb + sseg;
  short* Al0 = As + t * 8;
  short* Al1 = As + 2048 + t * 8;
  short* Bl0 = Bs + t * 8;
  short* Bl1 = Bs + 2048 + t * 8;

  f32x4 zero4 = {0.f, 0.f, 0.f, 0.f};
  f32x4 acc[4][JF];
#pragma unroll
  for (int i = 0; i < 4; ++i)
#pragma unroll
    for (int j = 0; j < JF; ++j) acc[i][j] = zero4;

  for (int k0 = 0; k0 < K; k0 += 32){
    gl_lds16(Ag0 + k0, Al0);
    gl_lds16(Ag1 + k0, Al1);
    gl_lds16(Bg0 + k0, Bl0);
    if constexpr (BN == 128) gl_lds16(Bg1 + k0, Bl1);
    __syncthreads();
    short8 af[4], bfr[JF];
#pragma unroll
    for (int i = 0; i < 4; ++i)
      af[i] = *(const short8*)(As + (wm + i * 16 + lm) * 32 + quad * 8);
#pragma unroll
    for (int j = 0; j < JF; ++j)
      bfr[j] = *(const short8*)(Bs + (wn + j * 16 + lm) * 32 + quad * 8);
#pragma unroll
    for (int i = 0; i < 4; ++i)
#pragma unroll
      for (int j = 0; j < JF; ++j)
        acc[i][j] = __builtin_amdgcn_mfma_f32_16x16x32_bf16(af[i], bfr[j], acc[i][j], 0, 0, 0);
    __syncthreads();
  }

#pragma unroll
  for (int i = 0; i < 4; ++i){
#pragma unroll
    for (int j = 0; j < JF; ++j){
#pragma unroll
      for (int r = 0; r < 4; ++r){
        int row = rowBase + wm + i * 16 + quad * 4 + r;
        int col = colBase + wn + j * 16 + lm;
        if (row < M && col < N){
          float v = acc[i][j][r] * alpha;
          if (bias) v += bias[col];
          size_t ci = coff + (size_t)row * ldc + col;
          if (resid) v += resid[ci];
          if (act) v = 0.5f * v * (1.f + erff(v * 0.7071067811865476f));
          if (Cf) Cf[ci] = v;
          if (Cb) Cb[ci] = f2b(v);
        }
      }
    }
  }
}

// reduce 4 split-K partial slabs + bias -> tok f32 + bf16
__global__ void kredG1(const float* __restrict__ part, const float* __restrict__ bias,
                       float* __restrict__ tok, short* __restrict__ tokb){
  int i = blockIdx.x * 256 + threadIdx.x;   // over 4096*512
  float v = part[i] + part[i + 2097152] + part[i + 4194304] + part[i + 6291456] + bias[i & 511];
  tok[i] = v;
  tokb[i] = f2b(v);
}

// softmax over 512-wide rows: f32 in -> bf16 out
__global__ void ksm_rows(const float* __restrict__ S, short* __restrict__ Sb){
  int row = blockIdx.x, lane = threadIdx.x;
  const float* p = S + (size_t)row * 512;
  short* q = Sb + (size_t)row * 512;
  float v[8]; float m = -1e30f;
#pragma unroll
  for (int i = 0; i < 8; ++i){ v[i] = p[lane + 64 * i]; m = fmaxf(m, v[i]); }
  m = waveMax(m);
  float s = 0.f;
#pragma unroll
  for (int i = 0; i < 8; ++i){ v[i] = expf(v[i] - m); s += v[i]; }
  s = waveSum(s);
  float r = 1.f / s;
#pragma unroll
  for (int i = 0; i < 8; ++i) q[lane + 64 * i] = f2b(v[i] * r);
}

// transpose V (from qkv bf16 buffer) into Vt[b*4+h][128][512]
__global__ void kvt(const short* __restrict__ qkvb, short* __restrict__ Vt){
  __shared__ short T[32][33];
  int bh = blockIdx.x, pt = blockIdx.y, nt = blockIdx.z;
  int b = bh >> 2, h = bh & 3;
  int tx = threadIdx.x, ty = threadIdx.y;
  const short* src = qkvb + (size_t)(b * 512) * 1536 + 1024 + h * 128;
  int p0 = pt * 32, n0 = nt * 32;
#pragma unroll
  for (int q = 0; q < 4; ++q)
    T[ty * 4 + q][tx] = src[(size_t)(p0 + ty * 4 + q) * 1536 + n0 + tx];
  __syncthreads();
  short* dst = Vt + (size_t)bh * 128 * 512;
#pragma unroll
  for (int q = 0; q < 4; ++q)
    dst[(size_t)(n0 + ty * 4 + q) * 512 + p0 + tx] = T[tx][ty * 4 + q];
}

// LayerNorm: f32 in -> f32 + bf16 out
__global__ void kln(const float* __restrict__ X, float* __restrict__ Y, short* __restrict__ Yb,
                    const float* __restrict__ g, const float* __restrict__ bb){
  int row = blockIdx.x, lane = threadIdx.x;
  const float* xr = X + (size_t)row * DMODEL;
  float v[8]; float s = 0.f;
#pragma unroll
  for (int i = 0; i < 8; ++i){ v[i] = xr[lane + 64 * i]; s += v[i]; }
  s = waveSum(s);
  float m = s * (1.f / DMODEL);
  float q = 0.f;
#pragma unroll
  for (int i = 0; i < 8; ++i){ float d = v[i] - m; q += d * d; }
  q = waveSum(q);
  float inv = rsqrtf(q * (1.f / DMODEL) + 1e-5f);
  float* yr = Y + (size_t)row * DMODEL;
  short* yb = Yb + (size_t)row * DMODEL;
#pragma unroll
  for (int i = 0; i < 8; ++i){
    int c = lane + 64 * i;
    float o = (v[i] - m) * inv * g[c] + bb[c];
    yr[c] = o;
    yb[c] = f2b(o);
  }
}

// det softmax over P (columns), in sorted space
__global__ void kdetsm(const float* __restrict__ det, float* __restrict__ dp){
  int b = blockIdx.x / NCOUT, c = blockIdx.x % NCOUT, lane = threadIdx.x;
  float v[8]; float m = -1e30f;
#pragma unroll
  for (int i = 0; i < 8; ++i){
    v[i] = det[((size_t)(b * PDIM) + lane + 64 * i) * NCOUT + c];
    m = fmaxf(m, v[i]);
  }
  m = waveMax(m);
  float s = 0.f;
#pragma unroll
  for (int i = 0; i < 8; ++i){ v[i] = expf(v[i] - m); s += v[i]; }
  s = waveSum(s);
  float r = 1.f / s;
#pragma unroll
  for (int i = 0; i < 8; ++i)
    dp[((size_t)(b * PDIM) + lane + 64 * i) * NCOUT + c] = v[i] * r;
}

// class softmax + joint + scatter back to original order + ctx copy + video accumulation
__global__ void kfinal(const float* __restrict__ cls_s, const float* __restrict__ det_s,
                       const float* __restrict__ dps, const float* __restrict__ tok,
                       const int* __restrict__ sidx, float* __restrict__ out){
  int blk = blockIdx.x;
  int b = blk >> 9, j = blk & 511;
  int lane = threadIdx.x;
  int p = sidx[b * PDIM + j];
  float* video = out;
  float* joint = out + 240;
  float* clso  = out + 123120;
  float* deto  = out + 246000;
  float* ctxo  = out + 368880;
  size_t rs = (size_t)(b * PDIM + j) * NCOUT;
  size_t ro = (size_t)(b * PDIM + p) * NCOUT;
  float lc = (lane < NCOUT) ? cls_s[rs + lane] : -1e30f;
  float m = waveMax(lc);
  float e = (lane < NCOUT) ? expf(lc - m) : 0.f;
  float s = waveSum(e);
  float cp = e / s;
  if (lane < NCOUT){
    float dv  = det_s[rs + lane];
    float dpv = dps[rs + lane];
    float jp  = cp * dpv;
    clso[ro + lane] = lc;
    deto[ro + lane] = dv;
    joint[ro + lane] = jp;
    atomicAdd(&video[b * NCOUT + lane], jp);
  }
  const float* tr = tok + (size_t)(b * PDIM + j) * DMODEL;
  float* cr = ctxo + (size_t)(b * PDIM + p) * DMODEL;
  for (int c = lane; c < DMODEL; c += 64) cr[c] = tr[c];
}

extern "C" void kernel_launch(void* const* d_in, const int* in_sizes, int n_in,
                              void* d_out, int out_size, void* d_ws, size_t ws_size,
                              hipStream_t stream) {
  const float* x      = (const float*)d_in[0];
  const int*   boxes  = (const int*)d_in[1];
  const float* proj_w = (const float*)d_in[2];
  const float* proj_b = (const float*)d_in[3];
  const float* pos_w1 = (const float*)d_in[4];
  const float* pos_b1 = (const float*)d_in[5];
  const float* pos_w2 = (const float*)d_in[6];
  const float* pos_b2 = (const float*)d_in[7];
  const float* qkv_w  = (const float*)d_in[8];
  const float* qkv_b  = (const float*)d_in[9];
  const float* out_w  = (const float*)d_in[10];
  const float* out_b  = (const float*)d_in[11];
  const float* ln1_g  = (const float*)d_in[12];
  const float* ln1_b  = (const float*)d_in[13];
  const float* ff1_w  = (const float*)d_in[14];
  const float* ff1_b  = (const float*)d_in[15];
  const float* ff2_w  = (const float*)d_in[16];
  const float* ff2_b  = (const float*)d_in[17];
  const float* ln2_g  = (const float*)d_in[18];
  const float* ln2_b  = (const float*)d_in[19];
  const float* cls_w  = (const float*)d_in[20];
  const float* cls_b  = (const float*)d_in[21];
  const float* det_w  = (const float*)d_in[22];
  const float* det_b  = (const float*)d_in[23];
  float* out = (float*)d_out;
  float* ws  = (float*)d_ws;

  // ---- workspace layout (FLOAT units) ----
  // region1 (9,437,184 fl): Abf dies after G1, then qkvb/Vt/obufb/x1/hbufb; heads reuse x1 slot.
  const size_t oR1    = 0;
  const size_t oS     = 9437184;    // csum, then G1 split-K partials, then scores S (8,388,608 fl)
  const size_t oSbf   = 17825792;   // 8,388,608 shorts = 4,194,304 fl
  const size_t oTok   = 22020096;   // 2,097,152 fl
  const size_t oTokb  = 24117248;   // 1,048,576 fl
  const size_t oTok2  = 25165824;   // 2,097,152 fl
  const size_t oTok2b = 27262976;   // 1,048,576 fl
  const size_t oWcat  = 28311552;   // 1,048,576 fl
  const size_t oBcat  = 29360128;   // 512 fl
  const size_t oWq    = 29360640;   // 786,432 fl
  const size_t oWo    = 30147072;   // 262,144 fl
  const size_t oWf1   = 30409216;   // 524,288 fl
  const size_t oWf2   = 30933504;   // 524,288 fl
  const size_t oWcls  = 31457792;   // 7,680 fl
  const size_t oWdet  = 31465472;   // 7,680 fl
  const size_t oTot   = 31473152;   // 65,536 fl (8b x 16ch x 512c)
  const size_t oOff   = 31538688;   // 65,536 fl
  const size_t oSidx  = 31604224;   // 1,024 fl -> end 31,605,248 fl (~126.4 MB)

  short* Abf   = (short*)(ws + oR1);
  short* qkvb  = (short*)(ws + oR1);
  short* Vt    = (short*)(ws + oR1 + 3145728);
  short* obufb = (short*)(ws + oR1 + 4194304);
  float* x1    = ws + oR1 + 5242880;
  short* hbufb = (short*)(ws + oR1 + 7340032);
  float* clsS  = ws + oR1 + 5242880;
  float* detS  = ws + oR1 + 5365760;
  float* dpS   = ws + oR1 + 5488640;
  float* csum  = ws + oS;
  float* Cpart = ws + oS;
  float* S     = ws + oS;
  short* Sbf   = (short*)(ws + oSbf);
  float* tok   = ws + oTok;
  short* tokb  = (short*)(ws + oTokb);
  float* tok2  = ws + oTok2;
  short* tok2b = (short*)(ws + oTok2b);
  short* Wcatb = (short*)(ws + oWcat);
  float* bcat  = ws + oBcat;
  short* Wq    = (short*)(ws + oWq);
  short* Wo    = (short*)(ws + oWo);
  short* Wf1   = (short*)(ws + oWf1);
  short* Wf2   = (short*)(ws + oWf2);
  short* Wcls  = (short*)(ws + oWcls);
  short* Wdet  = (short*)(ws + oWdet);
  float* tot   = ws + oTot;
  float* offp  = ws + oOff;
  int*   sidx  = (int*)(ws + oSidx);

  kzero<<<1, 256, 0, stream>>>(out, 240);
  kscan<<<256, 256, 0, stream>>>(x, csum, tot);
  koff<<<16, 256, 0, stream>>>(tot, offp);
  ksort<<<BDIM, 512, 0, stream>>>(boxes, sidx);
  kwcat<<<8192, 256, 0, stream>>>(proj_w, pos_w2, Wcatb);
  kbcat<<<2, 256, 0, stream>>>(proj_b, pos_b2, bcat);
  kconv<<<6144, 256, 0, stream>>>(qkv_w, Wq, 2 * 1536 * 512);
  kconv<<<2048, 256, 0, stream>>>(out_w, Wo, 2 * 512 * 512);
  kconv<<<4096, 256, 0, stream>>>(ff1_w, Wf1, 2 * 1024 * 512);
  kconv<<<4096, 256, 0, stream>>>(ff2_w, Wf2, 2 * 512 * 1024);
  kconv<<<60, 256, 0, stream>>>(cls_w, Wcls, NCOUT * 512);
  kconv<<<60, 256, 0, stream>>>(det_w, Wdet, NCOUT * 512);
  kspp<<<BDIM * PDIM, 256, 0, stream>>>(csum, offp, boxes, sidx, pos_w1, pos_b1, Abf);

  // G1 split-K: partials[z] = Abf[:, z*1024:(z+1)*1024] @ Wcat[:, same]^T   (512 blocks)
  gemm_bt<128><<<dim3(4, 32, 4), 256, 0, stream>>>(
      4096, 512, 1024, Abf, 4096, 1024, 0, Wcatb, 4096, 1024, 0,
      Cpart, nullptr, 512, 2097152, 0, 1, 1.f, nullptr, nullptr, 0);
  kredG1<<<8192, 256, 0, stream>>>(Cpart, bcat, tok, tokb);

  const float scale = 0.08838834764831845f;  // 1/sqrt(128)
  for (int l = 0; l < 2; ++l){
    const short* qw  = Wq  + (size_t)l * 1536 * 512;
    const short* ow  = Wo  + (size_t)l * 512 * 512;
    const short* f1w = Wf1 + (size_t)l * 1024 * 512;
    const short* f2w = Wf2 + (size_t)l * 512 * 1024;
    const float* qb  = qkv_b + (size_t)l * 1536;
    const float* obv = out_b + (size_t)l * 512;
    const float* f1b = ff1_b + (size_t)l * 1024;
    const float* f2b_ = ff2_b + (size_t)l * 512;

    // qkv = tok @ qkv_w^T + qkv_b   [4096, 1536] (bf16 out; 768 blocks)
    gemm_bt<64><<<dim3(24, 32, 1), 256, 0, stream>>>(
        4096, 1536, 512, tokb, 512, 0, 0, qw, 512, 0, 0,
        nullptr, qkvb, 1536, 0, 0, 1, 1.f, qb, nullptr, 0);
    // scores: S[bh] = scale * Q K^T (f32 out; 512 blocks)
    gemm_bt<128><<<dim3(4, 4, 32), 256, 0, stream>>>(
        512, 512, 128,
        qkvb, 1536, (long long)512 * 1536, 128,
        qkvb + 512, 1536, (long long)512 * 1536, 128,
        S, nullptr, 512, (long long)4 * 512 * 512, (long long)512 * 512,
        4, scale, nullptr, nullptr, 0);
    ksm_rows<<<32 * 512, 64, 0, stream>>>(S, Sbf);
    kvt<<<dim3(32, 16, 4), dim3(32, 8), 0, stream>>>(qkvb, Vt);
    // O = P @ V^T -> obufb[b][q][h*128+n] (bf16; 256 blocks)
    gemm_bt<64><<<dim3(2, 4, 32), 256, 0, stream>>>(
        512, 128, 512,
        Sbf, 512, (long long)4 * 512 * 512, (long long)512 * 512,
        Vt, 512, (long long)4 * 128 * 512, (long long)128 * 512,
        nullptr, obufb, 512, (long long)512 * 512, 128,
        4, 1.f, nullptr, nullptr, 0);
    // x1 = obufb @ out_w^T + out_b + tok (f32; 256 blocks)
    gemm_bt<64><<<dim3(8, 32, 1), 256, 0, stream>>>(
        4096, 512, 512, obufb, 512, 0, 0, ow, 512, 0, 0,
        x1, nullptr, 512, 0, 0, 1, 1.f, obv, tok, 0);
    kln<<<4096, 64, 0, stream>>>(x1, tok2, tok2b, ln1_g + l * 512, ln1_b + l * 512);
    // hbuf = gelu(tok2 @ ff1^T + b1) (bf16; 512 blocks)
    gemm_bt<64><<<dim3(16, 32, 1), 256, 0, stream>>>(
        4096, 1024, 512, tok2b, 512, 0, 0, f1w, 512, 0, 0,
        nullptr, hbufb, 1024, 0, 0, 1, 1.f, f1b, nullptr, 1);
    // x1 = hbuf @ ff2^T + b2 + tok2 (f32; 256 blocks)
    gemm_bt<64><<<dim3(8, 32, 1), 256, 0, stream>>>(
        4096, 512, 1024, hbufb, 1024, 0, 0, f2w, 1024, 0, 0,
        x1, nullptr, 512, 0, 0, 1, 1.f, f2b_, tok2, 0);
    kln<<<4096, 64, 0, stream>>>(x1, tok, tokb, ln2_g + l * 512, ln2_b + l * 512);
  }

  // heads (sorted space, f32 logits) — overwrite x1's slot (x1 dead)
  gemm_bt<64><<<dim3(1, 32, 1), 256, 0, stream>>>(
      4096, NCOUT, 512, tokb, 512, 0, 0, Wcls, 512, 0, 0,
      clsS, nullptr, NCOUT, 0, 0, 1, 1.f, cls_b, nullptr, 0);
  gemm_bt<64><<<dim3(1, 32, 1), 256, 0, stream>>>(
      4096, NCOUT, 512, tokb, 512, 0, 0, Wdet, 512, 0, 0,
      detS, nullptr, NCOUT, 0, 0, 1, 1.f, det_b, nullptr, 0);
  kdetsm<<<BDIM * NCOUT, 64, 0, stream>>>(detS, dpS);
  kfinal<<<BDIM * PDIM, 64, 0, stream>>>(clsS, detS, dpS, tok, sidx, out);
}

// Round 6
// 567.107 us; speedup vs baseline: 5.0696x; 1.0758x over previous
//
#include <hip/hip_runtime.h>

#define TDIM 2048
#define CDIM 512
#define BDIM 8
#define PDIM 512
#define DMODEL 512
#define NCOUT 30
#define SPPOUT 3584
#define AKDIM 4096   // SPPOUT + DMODEL

typedef __attribute__((ext_vector_type(8))) short short8;
typedef __attribute__((ext_vector_type(4))) float f32x4;

typedef const __attribute__((address_space(1))) void* as1cv;
typedef __attribute__((address_space(3))) void* as3v;

// async global->LDS, 16B per lane; LDS dest must be wave-uniform base + lane*16
__device__ __forceinline__ void gl_lds16(const short* g, short* l){
  __builtin_amdgcn_global_load_lds((as1cv)g, (as3v)l, 16, 0, 0);
}

__device__ __forceinline__ short f2b(float f){
  unsigned u = __float_as_uint(f);
  unsigned r = (u + 0x7fffu + ((u >> 16) & 1u)) >> 16;
  return (short)r;
}

__device__ __forceinline__ float waveSum(float v){
#pragma unroll
  for (int o = 32; o > 0; o >>= 1) v += __shfl_xor(v, o);
  return v;
}
__device__ __forceinline__ float waveMax(float v){
#pragma unroll
  for (int o = 32; o > 0; o >>= 1) v = fmaxf(v, __shfl_xor(v, o));
  return v;
}

__global__ void kzero(float* p, int n){
  int i = blockIdx.x * 256 + threadIdx.x;
  if (i < n) p[i] = 0.f;
}

// fused weight bf16 conversion: qkv|out|ff1|ff2|cls|det into one contiguous dest
__global__ void kprep(const float* __restrict__ q, const float* __restrict__ o,
                      const float* __restrict__ f1, const float* __restrict__ f2,
                      const float* __restrict__ cl, const float* __restrict__ dt,
                      short* __restrict__ d){
  int i = blockIdx.x * 256 + threadIdx.x;   // 4,225,024 total
  float v;
  if (i < 1572864) v = q[i];
  else if (i < 2097152) v = o[i - 1572864];
  else if (i < 3145728) v = f1[i - 2097152];
  else if (i < 4194304) v = f2[i - 3145728];
  else if (i < 4209664) v = cl[i - 4194304];
  else v = dt[i - 4209664];
  d[i] = f2b(v);
}

// Chunked inclusive scan along T: 16 chunks of 128. W[b][t][c] = sum x[b,c, chunkstart..t]
__global__ void kscan(const float* __restrict__ x, float* __restrict__ W, float* __restrict__ tot){
  int idx = blockIdx.x;             // b*32 + ch*2 + cg  (256 blocks)
  int b = idx >> 5, rem = idx & 31, ch = rem >> 1, cg = rem & 1;
  int c = cg * 256 + threadIdx.x;
  const float* xp = x + ((size_t)(b * CDIM + c)) * TDIM + ch * 128;
  float* wp = W + ((size_t)b * TDIM + ch * 128) * CDIM + c;
  float run = 0.f;
  for (int tl = 0; tl < 128; tl += 4){
    float4 v = *(const float4*)(xp + tl);
    run += v.x; wp[(size_t)(tl + 0) * CDIM] = run;
    run += v.y; wp[(size_t)(tl + 1) * CDIM] = run;
    run += v.z; wp[(size_t)(tl + 2) * CDIM] = run;
    run += v.w; wp[(size_t)(tl + 3) * CDIM] = run;
  }
  tot[((size_t)b * 16 + ch) * CDIM + c] = run;
}

__global__ void koff(const float* __restrict__ tot, float* __restrict__ off){
  int b = blockIdx.x >> 1, cg = blockIdx.x & 1;
  int c = cg * 256 + threadIdx.x;
  float run = 0.f;
  for (int ch = 0; ch < 16; ++ch){
    off[((size_t)b * 16 + ch) * CDIM + c] = run;
    run += tot[((size_t)b * 16 + ch) * CDIM + c];
  }
}

// Stable argsort by center: key = ((s+e)<<9) | p  (unique keys -> stable)
__global__ void ksort(const int* __restrict__ boxes, int* __restrict__ sidx){
  __shared__ unsigned key[PDIM];
  int b = blockIdx.x, t = threadIdx.x;
  int s = boxes[(size_t)(b * PDIM + t) * 2];
  int e = boxes[(size_t)(b * PDIM + t) * 2 + 1];
  key[t] = ((unsigned)(s + e) << 9) | (unsigned)t;
  __syncthreads();
  for (int k = 2; k <= PDIM; k <<= 1){
    for (int j = k >> 1; j > 0; j >>= 1){
      int ixj = t ^ j;
      if (ixj > t){
        unsigned a = key[t], c2 = key[ixj];
        bool up = ((t & k) == 0);
        bool doswap = up ? (a > c2) : (a < c2);
        if (doswap){ key[t] = c2; key[ixj] = a; }
      }
      __syncthreads();
    }
  }
  sidx[b * PDIM + t] = (int)(key[t] & 511u);
}

// Build Wcat = [proj_w | pos_w2]  (512 x 4096) as bf16
__global__ void kwcat(const float* __restrict__ pw, const float* __restrict__ pw2, short* __restrict__ Wc){
  int i = blockIdx.x * 256 + threadIdx.x;
  int r = i >> 12, k = i & 4095;
  float v = (k < SPPOUT) ? pw[(size_t)r * SPPOUT + k] : pw2[(size_t)r * DMODEL + (k - SPPOUT)];
  Wc[i] = f2b(v);
}

// proj/pos bias sum (512) + concatenated head bias (60)
__global__ void kbcat(const float* __restrict__ pb, const float* __restrict__ pb2,
                      const float* __restrict__ cb, const float* __restrict__ db,
                      float* __restrict__ bc, float* __restrict__ bh){
  int i = blockIdx.x * 256 + threadIdx.x;
  if (i < DMODEL) bc[i] = pb[i] + pb2[i];
  if (blockIdx.x == 0 && i < 60) bh[i] = (i < 30) ? cb[i] : db[i - 30];
}

// SPP pooling + pos-MLP hidden, staged in sorted order as bf16: A[b][j][0..4095]
__global__ void kspp(const float* __restrict__ W, const float* __restrict__ off,
                     const int* __restrict__ boxes, const int* __restrict__ sidx,
                     const float* __restrict__ pw1, const float* __restrict__ pb1,
                     short* __restrict__ A){
  int blk = blockIdx.x;
  int b = blk >> 9, j = blk & 511;
  int p = sidx[b * PDIM + j];
  int s0 = boxes[(size_t)(b * PDIM + p) * 2];
  int e0 = boxes[(size_t)(b * PDIM + p) * 2 + 1];
  int start = min(max(s0, 0), TDIM - 1);
  int end   = min(max(e0, 1), TDIM);
  if (end <= start) end = min(start + 1, TDIM);
  int n = end - start;

  int lo[7], hi[7], cb[7], cl[7];
  {
    const int Ls[3] = {1, 2, 4};
    const int Bo[3] = {0, 512, 1536};
    int q = 0;
    for (int li = 0; li < 3; ++li){
      int L = Ls[li];
      for (int i = 0; i < L; ++i){
        lo[q] = start + (i * n) / L;
        hi[q] = start + ((i + 1) * n + L - 1) / L;
        cb[q] = Bo[li] + i;
        cl[q] = L;
        ++q;
      }
    }
  }
  float s_f = (float)s0, e_f = (float)e0;
  float px = (s_f + e_f) * 0.5f / (float)TDIM;
  float py = fmaxf(e_f - s_f, 1.f) / (float)TDIM;
  short* Ar = A + (size_t)(b * PDIM + j) * AKDIM;
  const float* Wb = W + (size_t)b * TDIM * CDIM;
  const float* ob = off + (size_t)b * 16 * CDIM;
  for (int c = threadIdx.x; c < CDIM; c += 256){
#pragma unroll
    for (int q = 0; q < 7; ++q){
      int l = lo[q], h = hi[q];
      float fl = (l == 0) ? 0.f : (Wb[(size_t)(l - 1) * CDIM + c] + ob[((l - 1) >> 7) * CDIM + c]);
      float fh = Wb[(size_t)(h - 1) * CDIM + c] + ob[((h - 1) >> 7) * CDIM + c];
      Ar[cb[q] + c * cl[q]] = f2b((fh - fl) / (float)(h - l));
    }
    float hv = pw1[c * 2] * px + pw1[c * 2 + 1] * py + pb1[c];
    Ar[SPPOUT + c] = f2b(fmaxf(hv, 0.f));
  }
}

// MFMA bf16 GEMM (nt): C[M,N] = act(alpha * A[M,K] @ B[N,K]^T + bias + resid)
// 128-row tiles, BK=64, XOR-swizzled LDS (conflict-free frag reads).
// BN=128: 4 waves of 64x64; BN=64: 4 waves of 64x32. K must be a multiple of 64.
template<int BN>
__global__ __launch_bounds__(256) void gemm_bt(
    int M, int N, int K,
    const short* __restrict__ A, int lda, long long sAb, long long sAh,
    const short* __restrict__ B, int ldb, long long sBb, long long sBh,
    float* __restrict__ Cf, short* __restrict__ Cb, int ldc, long long sCb, long long sCh,
    int hdiv, float alpha,
    const float* __restrict__ bias, const float* __restrict__ resid, int act)
{
  constexpr int JF = BN / 32;                 // B-frags per wave / B staging batches
  __shared__ short As[128 * 64];
  __shared__ short Bs[BN * 64];
  int z = blockIdx.z;
  int zb = z / hdiv, zh = z - zb * hdiv;
  A += (size_t)zb * sAb + (size_t)zh * sAh;
  B += (size_t)zb * sBb + (size_t)zh * sBh;
  size_t coff = (size_t)zb * sCb + (size_t)zh * sCh;
  int rowBase = blockIdx.y * 128, colBase = blockIdx.x * BN;
  int t = threadIdx.x;
  int lane = t & 63;
  int wave = t >> 6;
  int wm = (wave >> 1) * 64, wn = (wave & 1) * (BN / 2);
  int lm = lane & 15, quad = lane >> 4;
  // staging: thread t loads row (t>>3)+32*it, k-group swizzled by row
  int srow = t >> 3;
  int skw = ((t & 7) * 8) ^ ((srow & 7) * 8);

  const short* Agp[4];
#pragma unroll
  for (int it = 0; it < 4; ++it)
    Agp[it] = A + (size_t)min(rowBase + srow + it * 32, M - 1) * lda + skw;
  const short* Bgp[JF];
#pragma unroll
  for (int it = 0; it < JF; ++it)
    Bgp[it] = B + (size_t)min(colBase + srow + it * 32, N - 1) * ldb + skw;

  f32x4 zero4 = {0.f, 0.f, 0.f, 0.f};
  f32x4 acc[4][JF];
#pragma unroll
  for (int i = 0; i < 4; ++i)
#pragma unroll
    for (int j = 0; j < JF; ++j) acc[i][j] = zero4;

  int axr = (lm & 7) * 8;                     // read-side XOR (row&7)*8; wm/wn/i*16 are 8-aligned
  for (int k0 = 0; k0 < K; k0 += 64){
#pragma unroll
    for (int it = 0; it < 4; ++it) gl_lds16(Agp[it] + k0, As + it * 2048 + t * 8);
#pragma unroll
    for (int it = 0; it < JF; ++it) gl_lds16(Bgp[it] + k0, Bs + it * 2048 + t * 8);
    __syncthreads();
#pragma unroll
    for (int h = 0; h < 2; ++h){
      int koff = (h * 32 + quad * 8) ^ axr;
      short8 af[4], bfr[JF];
#pragma unroll
      for (int i = 0; i < 4; ++i)
        af[i] = *(const short8*)(As + (wm + i * 16 + lm) * 64 + koff);
#pragma unroll
      for (int j = 0; j < JF; ++j)
        bfr[j] = *(const short8*)(Bs + (wn + j * 16 + lm) * 64 + koff);
#pragma unroll
      for (int i = 0; i < 4; ++i)
#pragma unroll
        for (int j = 0; j < JF; ++j)
          acc[i][j] = __builtin_amdgcn_mfma_f32_16x16x32_bf16(af[i], bfr[j], acc[i][j], 0, 0, 0);
    }
    __syncthreads();
  }

#pragma unroll
  for (int i = 0; i < 4; ++i){
#pragma unroll
    for (int j = 0; j < JF; ++j){
#pragma unroll
      for (int r = 0; r < 4; ++r){
        int row = rowBase + wm + i * 16 + quad * 4 + r;
        int col = colBase + wn + j * 16 + lm;
        if (row < M && col < N){
          float v = acc[i][j][r] * alpha;
          if (bias) v += bias[col];
          size_t ci = coff + (size_t)row * ldc + col;
          if (resid) v += resid[ci];
          if (act) v = 0.5f * v * (1.f + erff(v * 0.7071067811865476f));
          if (Cf) Cf[ci] = v;
          if (Cb) Cb[ci] = f2b(v);
        }
      }
    }
  }
}

// reduce 4 split-K partial slabs + bias -> tok f32 + bf16
__global__ void kredG1(const float* __restrict__ part, const float* __restrict__ bias,
                       float* __restrict__ tok, short* __restrict__ tokb){
  int i = blockIdx.x * 256 + threadIdx.x;   // over 4096*512
  float v = part[i] + part[i + 2097152] + part[i + 4194304] + part[i + 6291456] + bias[i & 511];
  tok[i] = v;
  tokb[i] = f2b(v);
}

// softmax over 512-wide rows: f32 in -> bf16 out
__global__ void ksm_rows(const float* __restrict__ S, short* __restrict__ Sb){
  int row = blockIdx.x, lane = threadIdx.x;
  const float* p = S + (size_t)row * 512;
  short* q = Sb + (size_t)row * 512;
  float v[8]; float m = -1e30f;
#pragma unroll
  for (int i = 0; i < 8; ++i){ v[i] = p[lane + 64 * i]; m = fmaxf(m, v[i]); }
  m = waveMax(m);
  float s = 0.f;
#pragma unroll
  for (int i = 0; i < 8; ++i){ v[i] = expf(v[i] - m); s += v[i]; }
  s = waveSum(s);
  float r = 1.f / s;
#pragma unroll
  for (int i = 0; i < 8; ++i) q[lane + 64 * i] = f2b(v[i] * r);
}

// transpose V (from qkv bf16 buffer) into Vt[b*4+h][128][512]
__global__ void kvt(const short* __restrict__ qkvb, short* __restrict__ Vt){
  __shared__ short T[32][33];
  int bh = blockIdx.x, pt = blockIdx.y, nt = blockIdx.z;
  int b = bh >> 2, h = bh & 3;
  int tx = threadIdx.x, ty = threadIdx.y;
  const short* src = qkvb + (size_t)(b * 512) * 1536 + 1024 + h * 128;
  int p0 = pt * 32, n0 = nt * 32;
#pragma unroll
  for (int q = 0; q < 4; ++q)
    T[ty * 4 + q][tx] = src[(size_t)(p0 + ty * 4 + q) * 1536 + n0 + tx];
  __syncthreads();
  short* dst = Vt + (size_t)bh * 128 * 512;
#pragma unroll
  for (int q = 0; q < 4; ++q)
    dst[(size_t)(n0 + ty * 4 + q) * 512 + p0 + tx] = T[tx][ty * 4 + q];
}

// LayerNorm: f32 in -> f32 + bf16 out
__global__ void kln(const float* __restrict__ X, float* __restrict__ Y, short* __restrict__ Yb,
                    const float* __restrict__ g, const float* __restrict__ bb){
  int row = blockIdx.x, lane = threadIdx.x;
  const float* xr = X + (size_t)row * DMODEL;
  float v[8]; float s = 0.f;
#pragma unroll
  for (int i = 0; i < 8; ++i){ v[i] = xr[lane + 64 * i]; s += v[i]; }
  s = waveSum(s);
  float m = s * (1.f / DMODEL);
  float q = 0.f;
#pragma unroll
  for (int i = 0; i < 8; ++i){ float d = v[i] - m; q += d * d; }
  q = waveSum(q);
  float inv = rsqrtf(q * (1.f / DMODEL) + 1e-5f);
  float* yr = Y + (size_t)row * DMODEL;
  short* yb = Yb + (size_t)row * DMODEL;
#pragma unroll
  for (int i = 0; i < 8; ++i){
    int c = lane + 64 * i;
    float o = (v[i] - m) * inv * g[c] + bb[c];
    yr[c] = o;
    yb[c] = f2b(o);
  }
}

// det softmax over P (columns), reading det part (cols 30..59) of headS [4096][60]
__global__ void kdetsm(const float* __restrict__ hd, float* __restrict__ dp){
  int b = blockIdx.x / NCOUT, c = blockIdx.x % NCOUT, lane = threadIdx.x;
  float v[8]; float m = -1e30f;
#pragma unroll
  for (int i = 0; i < 8; ++i){
    v[i] = hd[((size_t)(b * PDIM) + lane + 64 * i) * 60 + 30 + c];
    m = fmaxf(m, v[i]);
  }
  m = waveMax(m);
  float s = 0.f;
#pragma unroll
  for (int i = 0; i < 8; ++i){ v[i] = expf(v[i] - m); s += v[i]; }
  s = waveSum(s);
  float r = 1.f / s;
#pragma unroll
  for (int i = 0; i < 8; ++i)
    dp[((size_t)(b * PDIM) + lane + 64 * i) * NCOUT + c] = v[i] * r;
}

// class softmax + joint + scatter back to original order + ctx copy + video accumulation
__global__ void kfinal(const float* __restrict__ hd, const float* __restrict__ dps,
                       const float* __restrict__ tok, const int* __restrict__ sidx,
                       float* __restrict__ out){
  int blk = blockIdx.x;
  int b = blk >> 9, j = blk & 511;
  int lane = threadIdx.x;
  int p = sidx[b * PDIM + j];
  float* video = out;
  float* joint = out + 240;
  float* clso  = out + 123120;
  float* deto  = out + 246000;
  float* ctxo  = out + 368880;
  size_t rs60 = (size_t)(b * PDIM + j) * 60;
  size_t rs30 = (size_t)(b * PDIM + j) * NCOUT;
  size_t ro = (size_t)(b * PDIM + p) * NCOUT;
  float lc = (lane < NCOUT) ? hd[rs60 + lane] : -1e30f;
  float m = waveMax(lc);
  float e = (lane < NCOUT) ? expf(lc - m) : 0.f;
  float s = waveSum(e);
  float cp = e / s;
  if (lane < NCOUT){
    float dv  = hd[rs60 + 30 + lane];
    float dpv = dps[rs30 + lane];
    float jp  = cp * dpv;
    clso[ro + lane] = lc;
    deto[ro + lane] = dv;
    joint[ro + lane] = jp;
    atomicAdd(&video[b * NCOUT + lane], jp);
  }
  const float* tr = tok + (size_t)(b * PDIM + j) * DMODEL;
  float* cr = ctxo + (size_t)(b * PDIM + p) * DMODEL;
  for (int c = lane; c < DMODEL; c += 64) cr[c] = tr[c];
}

extern "C" void kernel_launch(void* const* d_in, const int* in_sizes, int n_in,
                              void* d_out, int out_size, void* d_ws, size_t ws_size,
                              hipStream_t stream) {
  const float* x      = (const float*)d_in[0];
  const int*   boxes  = (const int*)d_in[1];
  const float* proj_w = (const float*)d_in[2];
  const float* proj_b = (const float*)d_in[3];
  const float* pos_w1 = (const float*)d_in[4];
  const float* pos_b1 = (const float*)d_in[5];
  const float* pos_w2 = (const float*)d_in[6];
  const float* pos_b2 = (const float*)d_in[7];
  const float* qkv_w  = (const float*)d_in[8];
  const float* qkv_b  = (const float*)d_in[9];
  const float* out_w  = (const float*)d_in[10];
  const float* out_b  = (const float*)d_in[11];
  const float* ln1_g  = (const float*)d_in[12];
  const float* ln1_b  = (const float*)d_in[13];
  const float* ff1_w  = (const float*)d_in[14];
  const float* ff1_b  = (const float*)d_in[15];
  const float* ff2_w  = (const float*)d_in[16];
  const float* ff2_b  = (const float*)d_in[17];
  const float* ln2_g  = (const float*)d_in[18];
  const float* ln2_b  = (const float*)d_in[19];
  const float* cls_w  = (const float*)d_in[20];
  const float* cls_b  = (const float*)d_in[21];
  const float* det_w  = (const float*)d_in[22];
  const float* det_b  = (const float*)d_in[23];
  float* out = (float*)d_out;
  float* ws  = (float*)d_ws;

  // ---- workspace layout (FLOAT units) ----
  const size_t oR1    = 0;
  const size_t oS     = 9437184;    // csum, then G1 split-K partials, then scores S (8,388,608 fl)
  const size_t oSbf   = 17825792;   // 8,388,608 shorts = 4,194,304 fl
  const size_t oTok   = 22020096;   // 2,097,152 fl
  const size_t oTokb  = 24117248;   // 1,048,576 fl
  const size_t oTok2  = 25165824;   // 2,097,152 fl
  const size_t oTok2b = 27262976;   // 1,048,576 fl
  const size_t oWcat  = 28311552;   // 1,048,576 fl
  const size_t oBcat  = 29360128;   // 512 fl
  const size_t oWq    = 29360640;   // 786,432 fl   (kprep dest base; contiguous through oWdet)
  const size_t oWo    = 30147072;   // 262,144 fl
  const size_t oWf1   = 30409216;   // 524,288 fl
  const size_t oWf2   = 30933504;   // 524,288 fl
  const size_t oWcls  = 31457792;   // 7,680 fl
  const size_t oWdet  = 31465472;   // 7,680 fl
  const size_t oTot   = 31473152;   // 65,536 fl; bhead aliases its start (tot dead after koff)
  const size_t oOff   = 31538688;   // 65,536 fl
  const size_t oSidx  = 31604224;   // int[4096] = 4,096 fl (NOT 1,024 — round-5 bug) -> end 31,608,320
  const size_t oBhead = oTot;       // 64 fl, reuses dead tot region (kbcat ordered after koff)

  short* Abf   = (short*)(ws + oR1);
  short* qkvb  = (short*)(ws + oR1);
  short* Vt    = (short*)(ws + oR1 + 3145728);
  short* obufb = (short*)(ws + oR1 + 4194304);
  float* x1    = ws + oR1 + 5242880;
  short* hbufb = (short*)(ws + oR1 + 7340032);
  float* headS = ws + oR1 + 5242880;              // [4096][60] after x1 dead
  float* dpS   = ws + oR1 + 5488640;
  float* csum  = ws + oS;
  float* Cpart = ws + oS;
  float* S     = ws + oS;
  short* Sbf   = (short*)(ws + oSbf);
  float* tok   = ws + oTok;
  short* tokb  = (short*)(ws + oTokb);
  float* tok2  = ws + oTok2;
  short* tok2b = (short*)(ws + oTok2b);
  short* Wcatb = (short*)(ws + oWcat);
  float* bcat  = ws + oBcat;
  short* Wq    = (short*)(ws + oWq);
  short* Wo    = (short*)(ws + oWo);
  short* Wf1   = (short*)(ws + oWf1);
  short* Wf2   = (short*)(ws + oWf2);
  short* Whead = (short*)(ws + oWcls);            // cls||det rows: [60][512]
  float* tot   = ws + oTot;
  float* offp  = ws + oOff;
  int*   sidx  = (int*)(ws + oSidx);
  float* bhead = ws + oBhead;

  kzero<<<1, 256, 0, stream>>>(out, 240);
  kscan<<<256, 256, 0, stream>>>(x, csum, tot);
  koff<<<16, 256, 0, stream>>>(tot, offp);
  ksort<<<BDIM, 512, 0, stream>>>(boxes, sidx);
  kwcat<<<8192, 256, 0, stream>>>(proj_w, pos_w2, Wcatb);
  kbcat<<<2, 256, 0, stream>>>(proj_b, pos_b2, cls_b, det_b, bcat, bhead);
  kprep<<<16504, 256, 0, stream>>>(qkv_w, out_w, ff1_w, ff2_w, cls_w, det_w, Wq);
  kspp<<<BDIM * PDIM, 256, 0, stream>>>(csum, offp, boxes, sidx, pos_w1, pos_b1, Abf);

  // G1 split-K: partials[z] = Abf[:, z*1024:(z+1)*1024] @ Wcat[:, same]^T   (512 blocks)
  gemm_bt<128><<<dim3(4, 32, 4), 256, 0, stream>>>(
      4096, 512, 1024, Abf, 4096, 1024, 0, Wcatb, 4096, 1024, 0,
      Cpart, nullptr, 512, 2097152, 0, 1, 1.f, nullptr, nullptr, 0);
  kredG1<<<8192, 256, 0, stream>>>(Cpart, bcat, tok, tokb);

  const float scale = 0.08838834764831845f;  // 1/sqrt(128)
  for (int l = 0; l < 2; ++l){
    const short* qw  = Wq  + (size_t)l * 1536 * 512;
    const short* ow  = Wo  + (size_t)l * 512 * 512;
    const short* f1w = Wf1 + (size_t)l * 1024 * 512;
    const short* f2w = Wf2 + (size_t)l * 512 * 1024;
    const float* qb  = qkv_b + (size_t)l * 1536;
    const float* obv = out_b + (size_t)l * 512;
    const float* f1b = ff1_b + (size_t)l * 1024;
    const float* f2b_ = ff2_b + (size_t)l * 512;

    // qkv = tok @ qkv_w^T + qkv_b   [4096, 1536] (bf16 out; 768 blocks)
    gemm_bt<64><<<dim3(24, 32, 1), 256, 0, stream>>>(
        4096, 1536, 512, tokb, 512, 0, 0, qw, 512, 0, 0,
        nullptr, qkvb, 1536, 0, 0, 1, 1.f, qb, nullptr, 0);
    // scores: S[bh] = scale * Q K^T (f32 out; 512 blocks)
    gemm_bt<128><<<dim3(4, 4, 32), 256, 0, stream>>>(
        512, 512, 128,
        qkvb, 1536, (long long)512 * 1536, 128,
        qkvb + 512, 1536, (long long)512 * 1536, 128,
        S, nullptr, 512, (long long)4 * 512 * 512, (long long)512 * 512,
        4, scale, nullptr, nullptr, 0);
    ksm_rows<<<32 * 512, 64, 0, stream>>>(S, Sbf);
    kvt<<<dim3(32, 16, 4), dim3(32, 8), 0, stream>>>(qkvb, Vt);
    // O = P @ V^T -> obufb[b][q][h*128+n] (bf16; 256 blocks)
    gemm_bt<64><<<dim3(2, 4, 32), 256, 0, stream>>>(
        512, 128, 512,
        Sbf, 512, (long long)4 * 512 * 512, (long long)512 * 512,
        Vt, 512, (long long)4 * 128 * 512, (long long)128 * 512,
        nullptr, obufb, 512, (long long)512 * 512, 128,
        4, 1.f, nullptr, nullptr, 0);
    // x1 = obufb @ out_w^T + out_b + tok (f32; 256 blocks)
    gemm_bt<64><<<dim3(8, 32, 1), 256, 0, stream>>>(
        4096, 512, 512, obufb, 512, 0, 0, ow, 512, 0, 0,
        x1, nullptr, 512, 0, 0, 1, 1.f, obv, tok, 0);
    kln<<<4096, 64, 0, stream>>>(x1, tok2, tok2b, ln1_g + l * 512, ln1_b + l * 512);
    // hbuf = gelu(tok2 @ ff1^T + b1) (bf16; 512 blocks)
    gemm_bt<64><<<dim3(16, 32, 1), 256, 0, stream>>>(
        4096, 1024, 512, tok2b, 512, 0, 0, f1w, 512, 0, 0,
        nullptr, hbufb, 1024, 0, 0, 1, 1.f, f1b, nullptr, 1);
    // x1 = hbuf @ ff2^T + b2 + tok2 (f32; 256 blocks)
    gemm_bt<64><<<dim3(8, 32, 1), 256, 0, stream>>>(
        4096, 512, 1024, hbufb, 1024, 0, 0, f2w, 1024, 0, 0,
        x1, nullptr, 512, 0, 0, 1, 1.f, f2b_, tok2, 0);
    kln<<<4096, 64, 0, stream>>>(x1, tok, tokb, ln2_g + l * 512, ln2_b + l * 512);
  }

  // fused heads: headS[4096][60] = tok @ [cls_w;det_w]^T + [cls_b;det_b]
  gemm_bt<64><<<dim3(1, 32, 1), 256, 0, stream>>>(
      4096, 60, 512, tokb, 512, 0, 0, Whead, 512, 0, 0,
      headS, nullptr, 60, 0, 0, 1, 1.f, bhead, nullptr, 0);
  kdetsm<<<BDIM * NCOUT, 64, 0, stream>>>(headS, dpS);
  kfinal<<<BDIM * PDIM, 64, 0, stream>>>(headS, dpS, tok, sidx, out);
}

// Round 8
// 549.652 us; speedup vs baseline: 5.2306x; 1.0318x over previous
//
#include <hip/hip_runtime.h>

#define TDIM 2048
#define CDIM 512
#define BDIM 8
#define PDIM 512
#define DMODEL 512
#define NCOUT 30
#define SPPOUT 3584
#define AKDIM 4096   // SPPOUT + DMODEL

typedef __attribute__((ext_vector_type(8))) short short8;
typedef __attribute__((ext_vector_type(4))) float f32x4;

typedef const __attribute__((address_space(1))) void* as1cv;
typedef __attribute__((address_space(3))) void* as3v;

// async global->LDS, 16B per lane; LDS dest must be wave-uniform base + lane*16
__device__ __forceinline__ void gl_lds16(const short* g, short* l){
  __builtin_amdgcn_global_load_lds((as1cv)g, (as3v)l, 16, 0, 0);
}

__device__ __forceinline__ short f2b(float f){
  unsigned u = __float_as_uint(f);
  unsigned r = (u + 0x7fffu + ((u >> 16) & 1u)) >> 16;
  return (short)r;
}

__device__ __forceinline__ float waveSum(float v){
#pragma unroll
  for (int o = 32; o > 0; o >>= 1) v += __shfl_xor(v, o);
  return v;
}
__device__ __forceinline__ float waveMax(float v){
#pragma unroll
  for (int o = 32; o > 0; o >>= 1) v = fmaxf(v, __shfl_xor(v, o));
  return v;
}

__global__ void kzero(float* p, int n){
  int i = blockIdx.x * 256 + threadIdx.x;
  if (i < n) p[i] = 0.f;
}

// fused prep: Wcat bf16 | all layer+head weights bf16 | bcat & bhead biases
__global__ void kprep2(const float* __restrict__ pw, const float* __restrict__ pw2,
                       const float* __restrict__ qw, const float* __restrict__ ow,
                       const float* __restrict__ f1, const float* __restrict__ f2,
                       const float* __restrict__ cl, const float* __restrict__ dt,
                       const float* __restrict__ pb, const float* __restrict__ pb2,
                       const float* __restrict__ cb, const float* __restrict__ db,
                       short* __restrict__ Wc, short* __restrict__ Wd,
                       float* __restrict__ bc, float* __restrict__ bh){
  int i = blockIdx.x * 256 + threadIdx.x;
  if (i < 2097152){
    int r = i >> 12, k = i & 4095;
    float v = (k < SPPOUT) ? pw[(size_t)r * SPPOUT + k] : pw2[(size_t)r * DMODEL + (k - SPPOUT)];
    Wc[i] = f2b(v);
  } else if (i < 6322176){
    int j = i - 2097152;
    float v;
    if (j < 1572864) v = qw[j];
    else if (j < 2097152) v = ow[j - 1572864];
    else if (j < 3145728) v = f1[j - 2097152];
    else if (j < 4194304) v = f2[j - 3145728];
    else if (j < 4209664) v = cl[j - 4194304];
    else v = dt[j - 4209664];
    Wd[j] = f2b(v);
  } else {
    int k = i - 6322176;
    if (k < 512) bc[k] = pb[k] + pb2[k];
    else if (k < 572) bh[k - 512] = (k < 542) ? cb[k - 512] : db[k - 542];
  }
}

// Chunked inclusive scan along T: 16 chunks of 128. W[b][t][c] = sum x[b,c, chunkstart..t]
__global__ void kscan(const float* __restrict__ x, float* __restrict__ W, float* __restrict__ tot){
  int idx = blockIdx.x;             // b*32 + ch*2 + cg  (256 blocks)
  int b = idx >> 5, rem = idx & 31, ch = rem >> 1, cg = rem & 1;
  int c = cg * 256 + threadIdx.x;
  const float* xp = x + ((size_t)(b * CDIM + c)) * TDIM + ch * 128;
  float* wp = W + ((size_t)b * TDIM + ch * 128) * CDIM + c;
  float run = 0.f;
  for (int tl = 0; tl < 128; tl += 4){
    float4 v = *(const float4*)(xp + tl);
    run += v.x; wp[(size_t)(tl + 0) * CDIM] = run;
    run += v.y; wp[(size_t)(tl + 1) * CDIM] = run;
    run += v.z; wp[(size_t)(tl + 2) * CDIM] = run;
    run += v.w; wp[(size_t)(tl + 3) * CDIM] = run;
  }
  tot[((size_t)b * 16 + ch) * CDIM + c] = run;
}

__global__ void koff(const float* __restrict__ tot, float* __restrict__ off){
  int b = blockIdx.x >> 1, cg = blockIdx.x & 1;
  int c = cg * 256 + threadIdx.x;
  float run = 0.f;
  for (int ch = 0; ch < 16; ++ch){
    off[((size_t)b * 16 + ch) * CDIM + c] = run;
    run += tot[((size_t)b * 16 + ch) * CDIM + c];
  }
}

// Stable argsort by center: key = ((s+e)<<9) | p  (unique keys -> stable)
__global__ void ksort(const int* __restrict__ boxes, int* __restrict__ sidx){
  __shared__ unsigned key[PDIM];
  int b = blockIdx.x, t = threadIdx.x;
  int s = boxes[(size_t)(b * PDIM + t) * 2];
  int e = boxes[(size_t)(b * PDIM + t) * 2 + 1];
  key[t] = ((unsigned)(s + e) << 9) | (unsigned)t;
  __syncthreads();
  for (int k = 2; k <= PDIM; k <<= 1){
    for (int j = k >> 1; j > 0; j >>= 1){
      int ixj = t ^ j;
      if (ixj > t){
        unsigned a = key[t], c2 = key[ixj];
        bool up = ((t & k) == 0);
        bool doswap = up ? (a > c2) : (a < c2);
        if (doswap){ key[t] = c2; key[ixj] = a; }
      }
      __syncthreads();
    }
  }
  sidx[b * PDIM + t] = (int)(key[t] & 511u);
}

// SPP pooling + pos-MLP hidden, staged in sorted order as bf16: A[b][j][0..4095]
__global__ void kspp(const float* __restrict__ W, const float* __restrict__ off,
                     const int* __restrict__ boxes, const int* __restrict__ sidx,
                     const float* __restrict__ pw1, const float* __restrict__ pb1,
                     short* __restrict__ A){
  int blk = blockIdx.x;
  int b = blk >> 9, j = blk & 511;
  int p = sidx[b * PDIM + j];
  int s0 = boxes[(size_t)(b * PDIM + p) * 2];
  int e0 = boxes[(size_t)(b * PDIM + p) * 2 + 1];
  int start = min(max(s0, 0), TDIM - 1);
  int end   = min(max(e0, 1), TDIM);
  if (end <= start) end = min(start + 1, TDIM);
  int n = end - start;

  int lo[7], hi[7], cb[7], cl[7];
  {
    const int Ls[3] = {1, 2, 4};
    const int Bo[3] = {0, 512, 1536};
    int q = 0;
    for (int li = 0; li < 3; ++li){
      int L = Ls[li];
      for (int i = 0; i < L; ++i){
        lo[q] = start + (i * n) / L;
        hi[q] = start + ((i + 1) * n + L - 1) / L;
        cb[q] = Bo[li] + i;
        cl[q] = L;
        ++q;
      }
    }
  }
  float s_f = (float)s0, e_f = (float)e0;
  float px = (s_f + e_f) * 0.5f / (float)TDIM;
  float py = fmaxf(e_f - s_f, 1.f) / (float)TDIM;
  short* Ar = A + (size_t)(b * PDIM + j) * AKDIM;
  const float* Wb = W + (size_t)b * TDIM * CDIM;
  const float* ob = off + (size_t)b * 16 * CDIM;
  for (int c = threadIdx.x; c < CDIM; c += 256){
#pragma unroll
    for (int q = 0; q < 7; ++q){
      int l = lo[q], h = hi[q];
      float fl = (l == 0) ? 0.f : (Wb[(size_t)(l - 1) * CDIM + c] + ob[((l - 1) >> 7) * CDIM + c]);
      float fh = Wb[(size_t)(h - 1) * CDIM + c] + ob[((h - 1) >> 7) * CDIM + c];
      Ar[cb[q] + c * cl[q]] = f2b((fh - fl) / (float)(h - l));
    }
    float hv = pw1[c * 2] * px + pw1[c * 2 + 1] * py + pb1[c];
    Ar[SPPOUT + c] = f2b(fmaxf(hv, 0.f));
  }
}

// MFMA bf16 GEMM (nt): C[M,N] = act(alpha * A[M,K] @ B[N,K]^T + bias + resid)
// 128-row tiles, BK=64, XOR-swizzled LDS (conflict-free frag reads).
// BN=128: 4 waves of 64x64; BN=64: 4 waves of 64x32. K must be a multiple of 64.
template<int BN>
__global__ __launch_bounds__(256) void gemm_bt(
    int M, int N, int K,
    const short* __restrict__ A, int lda, long long sAb, long long sAh,
    const short* __restrict__ B, int ldb, long long sBb, long long sBh,
    float* __restrict__ Cf, short* __restrict__ Cb, int ldc, long long sCb, long long sCh,
    int hdiv, float alpha,
    const float* __restrict__ bias, const float* __restrict__ resid, int act)
{
  constexpr int JF = BN / 32;                 // B-frags per wave / B staging batches
  __shared__ short As[128 * 64];
  __shared__ short Bs[BN * 64];
  int z = blockIdx.z;
  int zb = z / hdiv, zh = z - zb * hdiv;
  A += (size_t)zb * sAb + (size_t)zh * sAh;
  B += (size_t)zb * sBb + (size_t)zh * sBh;
  size_t coff = (size_t)zb * sCb + (size_t)zh * sCh;
  int rowBase = blockIdx.y * 128, colBase = blockIdx.x * BN;
  int t = threadIdx.x;
  int lane = t & 63;
  int wave = t >> 6;
  int wm = (wave >> 1) * 64, wn = (wave & 1) * (BN / 2);
  int lm = lane & 15, quad = lane >> 4;
  // staging: thread t loads row (t>>3)+32*it, k-group swizzled by row
  int srow = t >> 3;
  int skw = ((t & 7) * 8) ^ ((srow & 7) * 8);

  const short* Agp[4];
#pragma unroll
  for (int it = 0; it < 4; ++it)
    Agp[it] = A + (size_t)min(rowBase + srow + it * 32, M - 1) * lda + skw;
  const short* Bgp[JF];
#pragma unroll
  for (int it = 0; it < JF; ++it)
    Bgp[it] = B + (size_t)min(colBase + srow + it * 32, N - 1) * ldb + skw;

  f32x4 zero4 = {0.f, 0.f, 0.f, 0.f};
  f32x4 acc[4][JF];
#pragma unroll
  for (int i = 0; i < 4; ++i)
#pragma unroll
    for (int j = 0; j < JF; ++j) acc[i][j] = zero4;

  int axr = (lm & 7) * 8;                     // read-side XOR (row&7)*8; wm/wn/i*16 are 8-aligned
  for (int k0 = 0; k0 < K; k0 += 64){
#pragma unroll
    for (int it = 0; it < 4; ++it) gl_lds16(Agp[it] + k0, As + it * 2048 + t * 8);
#pragma unroll
    for (int it = 0; it < JF; ++it) gl_lds16(Bgp[it] + k0, Bs + it * 2048 + t * 8);
    __syncthreads();
#pragma unroll
    for (int h = 0; h < 2; ++h){
      int koff = (h * 32 + quad * 8) ^ axr;
      short8 af[4], bfr[JF];
#pragma unroll
      for (int i = 0; i < 4; ++i)
        af[i] = *(const short8*)(As + (wm + i * 16 + lm) * 64 + koff);
#pragma unroll
      for (int j = 0; j < JF; ++j)
        bfr[j] = *(const short8*)(Bs + (wn + j * 16 + lm) * 64 + koff);
#pragma unroll
      for (int i = 0; i < 4; ++i)
#pragma unroll
        for (int j = 0; j < JF; ++j)
          acc[i][j] = __builtin_amdgcn_mfma_f32_16x16x32_bf16(af[i], bfr[j], acc[i][j], 0, 0, 0);
    }
    __syncthreads();
  }

#pragma unroll
  for (int i = 0; i < 4; ++i){
#pragma unroll
    for (int j = 0; j < JF; ++j){
#pragma unroll
      for (int r = 0; r < 4; ++r){
        int row = rowBase + wm + i * 16 + quad * 4 + r;
        int col = colBase + wn + j * 16 + lm;
        if (row < M && col < N){
          float v = acc[i][j][r] * alpha;
          if (bias) v += bias[col];
          size_t ci = coff + (size_t)row * ldc + col;
          if (resid) v += resid[ci];
          if (act) v = 0.5f * v * (1.f + erff(v * 0.7071067811865476f));
          if (Cf) Cf[ci] = v;
          if (Cb) Cb[ci] = f2b(v);
        }
      }
    }
  }
}

// reduce 4 split-K partial slabs + bias -> tok f32 + bf16
__global__ void kredG1(const float* __restrict__ part, const float* __restrict__ bias,
                       float* __restrict__ tok, short* __restrict__ tokb){
  int i = blockIdx.x * 256 + threadIdx.x;   // over 4096*512
  float v = part[i] + part[i + 2097152] + part[i + 4194304] + part[i + 6291456] + bias[i & 511];
  tok[i] = v;
  tokb[i] = f2b(v);
}

// reduce 2 split-K PV partial slabs [bh][q][n] -> bf16 obufb in [b][q][h*128+n]
__global__ void kredPV(const float* __restrict__ part, short* __restrict__ ob){
  int i = blockIdx.x * 256 + threadIdx.x;   // output index: [b][q][h][n], 2,097,152 total
  int n = i & 127;
  int h = (i >> 7) & 3;
  int q = (i >> 9) & 511;
  int b = i >> 18;
  int src = (((b << 2) + h) << 16) + (q << 7) + n;
  ob[i] = f2b(part[src] + part[src + 2097152]);
}

// fused: reduce 2 split-K slabs + bias + residual + LayerNorm -> f32 + bf16
__global__ void klnR(const float* __restrict__ part, const float* __restrict__ bias,
                     const float* __restrict__ resid,
                     const float* __restrict__ g, const float* __restrict__ bb,
                     float* __restrict__ Yf, short* __restrict__ Yb){
  int row = blockIdx.x, lane = threadIdx.x;
  size_t base = (size_t)row * DMODEL;
  float v[8]; float s = 0.f;
#pragma unroll
  for (int i = 0; i < 8; ++i){
    int c = lane + 64 * i;
    v[i] = part[base + c] + part[base + c + 2097152] + bias[c] + resid[base + c];
    s += v[i];
  }
  s = waveSum(s);
  float m = s * (1.f / DMODEL);
  float q = 0.f;
#pragma unroll
  for (int i = 0; i < 8; ++i){ float d = v[i] - m; q += d * d; }
  q = waveSum(q);
  float inv = rsqrtf(q * (1.f / DMODEL) + 1e-5f);
#pragma unroll
  for (int i = 0; i < 8; ++i){
    int c = lane + 64 * i;
    float o = (v[i] - m) * inv * g[c] + bb[c];
    Yf[base + c] = o;
    Yb[base + c] = f2b(o);
  }
}

// fused attention-mid: blocks [0,4096): row softmax S->Sbf (4 rows/block, wave per row);
// blocks [4096,6144): V transpose qkvb->Vt
__global__ void kattn(const float* __restrict__ S, short* __restrict__ Sb,
                      const short* __restrict__ qkvb, short* __restrict__ Vt){
  __shared__ short T[32][33];
  int blk = blockIdx.x, t = threadIdx.x;
  if (blk < 4096){
    int row = blk * 4 + (t >> 6), lane = t & 63;
    const float* p = S + (size_t)row * 512;
    short* q = Sb + (size_t)row * 512;
    float v[8]; float m = -1e30f;
#pragma unroll
    for (int i = 0; i < 8; ++i){ v[i] = p[lane + 64 * i]; m = fmaxf(m, v[i]); }
    m = waveMax(m);
    float s = 0.f;
#pragma unroll
    for (int i = 0; i < 8; ++i){ v[i] = expf(v[i] - m); s += v[i]; }
    s = waveSum(s);
    float r = 1.f / s;
#pragma unroll
    for (int i = 0; i < 8; ++i) q[lane + 64 * i] = f2b(v[i] * r);
  } else {
    int bid = blk - 4096;
    int bh = bid >> 6, pt = (bid >> 2) & 15, nt = bid & 3;
    int b = bh >> 2, h = bh & 3;
    int tx = t & 31, ty = t >> 5;
    const short* src = qkvb + (size_t)(b * 512) * 1536 + 1024 + h * 128;
    int p0 = pt * 32, n0 = nt * 32;
#pragma unroll
    for (int q = 0; q < 4; ++q)
      T[ty * 4 + q][tx] = src[(size_t)(p0 + ty * 4 + q) * 1536 + n0 + tx];
    __syncthreads();
    short* dst = Vt + (size_t)bh * 128 * 512;
#pragma unroll
    for (int q = 0; q < 4; ++q)
      dst[(size_t)(n0 + ty * 4 + q) * 512 + p0 + tx] = T[tx][ty * 4 + q];
  }
}

// det softmax over P (columns), reading det part (cols 30..59) of headS [4096][60]
__global__ void kdetsm(const float* __restrict__ hd, float* __restrict__ dp){
  int b = blockIdx.x / NCOUT, c = blockIdx.x % NCOUT, lane = threadIdx.x;
  float v[8]; float m = -1e30f;
#pragma unroll
  for (int i = 0; i < 8; ++i){
    v[i] = hd[((size_t)(b * PDIM) + lane + 64 * i) * 60 + 30 + c];
    m = fmaxf(m, v[i]);
  }
  m = waveMax(m);
  float s = 0.f;
#pragma unroll
  for (int i = 0; i < 8; ++i){ v[i] = expf(v[i] - m); s += v[i]; }
  s = waveSum(s);
  float r = 1.f / s;
#pragma unroll
  for (int i = 0; i < 8; ++i)
    dp[((size_t)(b * PDIM) + lane + 64 * i) * NCOUT + c] = v[i] * r;
}

// class softmax + joint + scatter back to original order + ctx copy + video accumulation
__global__ void kfinal(const float* __restrict__ hd, const float* __restrict__ dps,
                       const float* __restrict__ tok, const int* __restrict__ sidx,
                       float* __restrict__ out){
  int blk = blockIdx.x;
  int b = blk >> 9, j = blk & 511;
  int lane = threadIdx.x;
  int p = sidx[b * PDIM + j];
  float* video = out;
  float* joint = out + 240;
  float* clso  = out + 123120;
  float* deto  = out + 246000;
  float* ctxo  = out + 368880;
  size_t rs60 = (size_t)(b * PDIM + j) * 60;
  size_t rs30 = (size_t)(b * PDIM + j) * NCOUT;
  size_t ro = (size_t)(b * PDIM + p) * NCOUT;
  float lc = (lane < NCOUT) ? hd[rs60 + lane] : -1e30f;
  float m = waveMax(lc);
  float e = (lane < NCOUT) ? expf(lc - m) : 0.f;
  float s = waveSum(e);
  float cp = e / s;
  if (lane < NCOUT){
    float dv  = hd[rs60 + 30 + lane];
    float dpv = dps[rs30 + lane];
    float jp  = cp * dpv;
    clso[ro + lane] = lc;
    deto[ro + lane] = dv;
    joint[ro + lane] = jp;
    atomicAdd(&video[b * NCOUT + lane], jp);
  }
  const float* tr = tok + (size_t)(b * PDIM + j) * DMODEL;
  float* cr = ctxo + (size_t)(b * PDIM + p) * DMODEL;
  for (int c = lane; c < DMODEL; c += 64) cr[c] = tr[c];
}

extern "C" void kernel_launch(void* const* d_in, const int* in_sizes, int n_in,
                              void* d_out, int out_size, void* d_ws, size_t ws_size,
                              hipStream_t stream) {
  const float* x      = (const float*)d_in[0];
  const int*   boxes  = (const int*)d_in[1];
  const float* proj_w = (const float*)d_in[2];
  const float* proj_b = (const float*)d_in[3];
  const float* pos_w1 = (const float*)d_in[4];
  const float* pos_b1 = (const float*)d_in[5];
  const float* pos_w2 = (const float*)d_in[6];
  const float* pos_b2 = (const float*)d_in[7];
  const float* qkv_w  = (const float*)d_in[8];
  const float* qkv_b  = (const float*)d_in[9];
  const float* out_w  = (const float*)d_in[10];
  const float* out_b  = (const float*)d_in[11];
  const float* ln1_g  = (const float*)d_in[12];
  const float* ln1_b  = (const float*)d_in[13];
  const float* ff1_w  = (const float*)d_in[14];
  const float* ff1_b  = (const float*)d_in[15];
  const float* ff2_w  = (const float*)d_in[16];
  const float* ff2_b  = (const float*)d_in[17];
  const float* ln2_g  = (const float*)d_in[18];
  const float* ln2_b  = (const float*)d_in[19];
  const float* cls_w  = (const float*)d_in[20];
  const float* cls_b  = (const float*)d_in[21];
  const float* det_w  = (const float*)d_in[22];
  const float* det_b  = (const float*)d_in[23];
  float* out = (float*)d_out;
  float* ws  = (float*)d_ws;

  // ---- workspace layout (FLOAT units) ----
  // region1 (9,437,184 fl): Abf [0, 8,388,608) dies after G1, then:
  //   qkvb  [0, 3,145,728) | Vt [3,145,728, 4,194,304) | obufb [4,194,304, 5,242,880)
  //   hbufb [5,242,880, 7,340,032) | headS/dpS at [7,340,032, ...) after layers
  // oS (8,388,608 fl) time-shared: csum -> G1 Cpart(4x2.1M) -> scores S -> PV partials(2x2.1M)
  //   -> out-proj partials(2x2.1M) -> ff2 partials(2x2.1M), per layer.
  const size_t oR1    = 0;
  const size_t oS     = 9437184;
  const size_t oSbf   = 17825792;   // 8,388,608 shorts = 4,194,304 fl
  const size_t oTok   = 22020096;   // 2,097,152 fl
  const size_t oTokb  = 24117248;   // 1,048,576 fl
  const size_t oTok2  = 25165824;   // 2,097,152 fl
  const size_t oTok2b = 27262976;   // 1,048,576 fl
  const size_t oWcat  = 28311552;   // 1,048,576 fl
  const size_t oBcat  = 29360128;   // 512 fl
  const size_t oWq    = 29360640;   // kprep2 dest base; contiguous qkv|out|ff1|ff2|cls|det
  const size_t oWo    = 30147072;
  const size_t oWf1   = 30409216;
  const size_t oWf2   = 30933504;
  const size_t oWcls  = 31457792;
  const size_t oTot   = 31473152;   // 65,536 fl; bhead aliases its start (tot dead after koff)
  const size_t oOff   = 31538688;   // 65,536 fl
  const size_t oSidx  = 31604224;   // int[4096] = 4,096 fl -> end 31,608,320 (~126.4 MB)
  const size_t oBhead = oTot;

  short* Abf   = (short*)(ws + oR1);
  short* qkvb  = (short*)(ws + oR1);
  short* Vt    = (short*)(ws + oR1 + 3145728);
  short* obufb = (short*)(ws + oR1 + 4194304);
  short* hbufb = (short*)(ws + oR1 + 5242880);
  float* headS = ws + oR1 + 7340032;              // [4096][60] after layers (hbufb dead)
  float* dpS   = ws + oR1 + 7585792;
  float* csum  = ws + oS;
  float* Cpart = ws + oS;
  float* S     = ws + oS;
  float* Cp2   = ws + oS;                          // 2-slab partials (PV / out-proj / ff2)
  short* Sbf   = (short*)(ws + oSbf);
  float* tok   = ws + oTok;
  short* tokb  = (short*)(ws + oTokb);
  float* tok2  = ws + oTok2;
  short* tok2b = (short*)(ws + oTok2b);
  short* Wcatb = (short*)(ws + oWcat);
  float* bcat  = ws + oBcat;
  short* Wq    = (short*)(ws + oWq);
  short* Wo    = (short*)(ws + oWo);
  short* Wf1   = (short*)(ws + oWf1);
  short* Wf2   = (short*)(ws + oWf2);
  short* Whead = (short*)(ws + oWcls);            // cls||det rows: [60][512]
  float* tot   = ws + oTot;
  float* offp  = ws + oOff;
  int*   sidx  = (int*)(ws + oSidx);
  float* bhead = ws + oBhead;

  kzero<<<1, 256, 0, stream>>>(out, 240);
  kscan<<<256, 256, 0, stream>>>(x, csum, tot);
  koff<<<16, 256, 0, stream>>>(tot, offp);
  ksort<<<BDIM, 512, 0, stream>>>(boxes, sidx);
  kprep2<<<24699, 256, 0, stream>>>(proj_w, pos_w2, qkv_w, out_w, ff1_w, ff2_w, cls_w, det_w,
                                    proj_b, pos_b2, cls_b, det_b, Wcatb, Wq, bcat, bhead);
  kspp<<<BDIM * PDIM, 256, 0, stream>>>(csum, offp, boxes, sidx, pos_w1, pos_b1, Abf);

  // G1 split-K-4 x BN=64: 1024 blocks (4/CU)
  gemm_bt<64><<<dim3(8, 32, 4), 256, 0, stream>>>(
      4096, 512, 1024, Abf, 4096, 1024, 0, Wcatb, 4096, 1024, 0,
      Cpart, nullptr, 512, 2097152, 0, 1, 1.f, nullptr, nullptr, 0);
  kredG1<<<8192, 256, 0, stream>>>(Cpart, bcat, tok, tokb);

  const float scale = 0.08838834764831845f;  // 1/sqrt(128)
  for (int l = 0; l < 2; ++l){
    const short* qw  = Wq  + (size_t)l * 1536 * 512;
    const short* ow  = Wo  + (size_t)l * 512 * 512;
    const short* f1w = Wf1 + (size_t)l * 1024 * 512;
    const short* f2w = Wf2 + (size_t)l * 512 * 1024;
    const float* qb  = qkv_b + (size_t)l * 1536;
    const float* obv = out_b + (size_t)l * 512;
    const float* f1b = ff1_b + (size_t)l * 1024;
    const float* f2b_ = ff2_b + (size_t)l * 512;

    // qkv = tok @ qkv_w^T + qkv_b   [4096, 1536] (bf16 out; 768 blocks, 3/CU)
    gemm_bt<64><<<dim3(24, 32, 1), 256, 0, stream>>>(
        4096, 1536, 512, tokb, 512, 0, 0, qw, 512, 0, 0,
        nullptr, qkvb, 1536, 0, 0, 1, 1.f, qb, nullptr, 0);
    // scores: S[bh] = scale * Q K^T (f32; 512 blocks)
    gemm_bt<128><<<dim3(4, 4, 32), 256, 0, stream>>>(
        512, 512, 128,
        qkvb, 1536, (long long)512 * 1536, 128,
        qkvb + 512, 1536, (long long)512 * 1536, 128,
        S, nullptr, 512, (long long)4 * 512 * 512, (long long)512 * 512,
        4, scale, nullptr, nullptr, 0);
    // softmax + V-transpose fused (6144 blocks)
    kattn<<<6144, 256, 0, stream>>>(S, Sbf, qkvb, Vt);
    // PV split-K-2: z = kslab*32 + bh (512 blocks, 2/CU), partials [kslab][bh][q][n]
    gemm_bt<64><<<dim3(2, 4, 64), 256, 0, stream>>>(
        512, 128, 256,
        Sbf, 512, 256, (long long)512 * 512,
        Vt, 512, 256, (long long)128 * 512,
        Cp2, nullptr, 128, 2097152, (long long)512 * 128,
        32, 1.f, nullptr, nullptr, 0);
    kredPV<<<8192, 256, 0, stream>>>(Cp2, obufb);
    // out-proj split-K-2 (512 blocks), then fused reduce+bias+resid+LN1
    gemm_bt<64><<<dim3(8, 32, 2), 256, 0, stream>>>(
        4096, 512, 256, obufb, 512, 256, 0, ow, 512, 256, 0,
        Cp2, nullptr, 512, 2097152, 0, 1, 1.f, nullptr, nullptr, 0);
    klnR<<<4096, 64, 0, stream>>>(Cp2, obv, tok, ln1_g + l * 512, ln1_b + l * 512, tok2, tok2b);
    // hbuf = gelu(tok2 @ ff1^T + b1) (bf16; 512 blocks)
    gemm_bt<64><<<dim3(16, 32, 1), 256, 0, stream>>>(
        4096, 1024, 512, tok2b, 512, 0, 0, f1w, 512, 0, 0,
        nullptr, hbufb, 1024, 0, 0, 1, 1.f, f1b, nullptr, 1);
    // ff2 split-K-2 (512 blocks), then fused reduce+bias+resid+LN2
    gemm_bt<64><<<dim3(8, 32, 2), 256, 0, stream>>>(
        4096, 512, 512, hbufb, 1024, 512, 0, f2w, 1024, 512, 0,
        Cp2, nullptr, 512, 2097152, 0, 1, 1.f, nullptr, nullptr, 0);
    klnR<<<4096, 64, 0, stream>>>(Cp2, f2b_, tok2, ln2_g + l * 512, ln2_b + l * 512, tok, tokb);
  }

  // fused heads: headS[4096][60] = tok @ [cls_w;det_w]^T + [cls_b;det_b]
  gemm_bt<64><<<dim3(1, 32, 1), 256, 0, stream>>>(
      4096, 60, 512, tokb, 512, 0, 0, Whead, 512, 0, 0,
      headS, nullptr, 60, 0, 0, 1, 1.f, bhead, nullptr, 0);
  kdetsm<<<BDIM * NCOUT, 64, 0, stream>>>(headS, dpS);
  kfinal<<<BDIM * PDIM, 64, 0, stream>>>(headS, dpS, tok, sidx, out);
}

// Round 9
// 543.788 us; speedup vs baseline: 5.2870x; 1.0108x over previous
//
#include <hip/hip_runtime.h>

#define TDIM 2048
#define CDIM 512
#define BDIM 8
#define PDIM 512
#define DMODEL 512
#define NCOUT 30
#define SPPOUT 3584
#define AKDIM 4096   // SPPOUT + DMODEL

typedef __attribute__((ext_vector_type(8))) short short8;
typedef __attribute__((ext_vector_type(4))) float f32x4;

typedef const __attribute__((address_space(1))) void* as1cv;
typedef __attribute__((address_space(3))) void* as3v;

// async global->LDS, 16B per lane; LDS dest must be wave-uniform base + lane*16
__device__ __forceinline__ void gl_lds16(const short* g, short* l){
  __builtin_amdgcn_global_load_lds((as1cv)g, (as3v)l, 16, 0, 0);
}

__device__ __forceinline__ short f2b(float f){
  unsigned u = __float_as_uint(f);
  unsigned r = (u + 0x7fffu + ((u >> 16) & 1u)) >> 16;
  return (short)r;
}

__device__ __forceinline__ float waveSum(float v){
#pragma unroll
  for (int o = 32; o > 0; o >>= 1) v += __shfl_xor(v, o);
  return v;
}
__device__ __forceinline__ float waveMax(float v){
#pragma unroll
  for (int o = 32; o > 0; o >>= 1) v = fmaxf(v, __shfl_xor(v, o));
  return v;
}

// fused prep: Wcat bf16 | all layer+head weights bf16 | bcat & bhead biases
__global__ void kprep2(const float* __restrict__ pw, const float* __restrict__ pw2,
                       const float* __restrict__ qw, const float* __restrict__ ow,
                       const float* __restrict__ f1, const float* __restrict__ f2,
                       const float* __restrict__ cl, const float* __restrict__ dt,
                       const float* __restrict__ pb, const float* __restrict__ pb2,
                       const float* __restrict__ cb, const float* __restrict__ db,
                       short* __restrict__ Wc, short* __restrict__ Wd,
                       float* __restrict__ bc, float* __restrict__ bh){
  int i = blockIdx.x * 256 + threadIdx.x;
  if (i < 2097152){
    int r = i >> 12, k = i & 4095;
    float v = (k < SPPOUT) ? pw[(size_t)r * SPPOUT + k] : pw2[(size_t)r * DMODEL + (k - SPPOUT)];
    Wc[i] = f2b(v);
  } else if (i < 6322176){
    int j = i - 2097152;
    float v;
    if (j < 1572864) v = qw[j];
    else if (j < 2097152) v = ow[j - 1572864];
    else if (j < 3145728) v = f1[j - 2097152];
    else if (j < 4194304) v = f2[j - 3145728];
    else if (j < 4209664) v = cl[j - 4194304];
    else v = dt[j - 4209664];
    Wd[j] = f2b(v);
  } else {
    int k = i - 6322176;
    if (k < 512) bc[k] = pb[k] + pb2[k];
    else if (k < 572) bh[k - 512] = (k < 542) ? cb[k - 512] : db[k - 542];
  }
}

// Chunked inclusive scan along T: 16 chunks of 128. W[b][t][c] = sum x[b,c, chunkstart..t]
__global__ void kscan(const float* __restrict__ x, float* __restrict__ W, float* __restrict__ tot){
  int idx = blockIdx.x;             // b*32 + ch*2 + cg  (256 blocks)
  int b = idx >> 5, rem = idx & 31, ch = rem >> 1, cg = rem & 1;
  int c = cg * 256 + threadIdx.x;
  const float* xp = x + ((size_t)(b * CDIM + c)) * TDIM + ch * 128;
  float* wp = W + ((size_t)b * TDIM + ch * 128) * CDIM + c;
  float run = 0.f;
  for (int tl = 0; tl < 128; tl += 4){
    float4 v = *(const float4*)(xp + tl);
    run += v.x; wp[(size_t)(tl + 0) * CDIM] = run;
    run += v.y; wp[(size_t)(tl + 1) * CDIM] = run;
    run += v.z; wp[(size_t)(tl + 2) * CDIM] = run;
    run += v.w; wp[(size_t)(tl + 3) * CDIM] = run;
  }
  tot[((size_t)b * 16 + ch) * CDIM + c] = run;
}

__global__ void koff(const float* __restrict__ tot, float* __restrict__ off){
  int b = blockIdx.x >> 1, cg = blockIdx.x & 1;
  int c = cg * 256 + threadIdx.x;
  float run = 0.f;
  for (int ch = 0; ch < 16; ++ch){
    off[((size_t)b * 16 + ch) * CDIM + c] = run;
    run += tot[((size_t)b * 16 + ch) * CDIM + c];
  }
}

// Stable argsort by center (+ zero the video-prob output region in block 0)
__global__ void ksort(const int* __restrict__ boxes, int* __restrict__ sidx, float* __restrict__ out){
  __shared__ unsigned key[PDIM];
  int b = blockIdx.x, t = threadIdx.x;
  if (b == 0 && t < 240) out[t] = 0.f;
  int s = boxes[(size_t)(b * PDIM + t) * 2];
  int e = boxes[(size_t)(b * PDIM + t) * 2 + 1];
  key[t] = ((unsigned)(s + e) << 9) | (unsigned)t;
  __syncthreads();
  for (int k = 2; k <= PDIM; k <<= 1){
    for (int j = k >> 1; j > 0; j >>= 1){
      int ixj = t ^ j;
      if (ixj > t){
        unsigned a = key[t], c2 = key[ixj];
        bool up = ((t & k) == 0);
        bool doswap = up ? (a > c2) : (a < c2);
        if (doswap){ key[t] = c2; key[ixj] = a; }
      }
      __syncthreads();
    }
  }
  sidx[b * PDIM + t] = (int)(key[t] & 511u);
}

// SPP pooling + pos-MLP hidden, staged in sorted order as bf16: A[b][j][0..4095]
__global__ void kspp(const float* __restrict__ W, const float* __restrict__ off,
                     const int* __restrict__ boxes, const int* __restrict__ sidx,
                     const float* __restrict__ pw1, const float* __restrict__ pb1,
                     short* __restrict__ A){
  int blk = blockIdx.x;
  int b = blk >> 9, j = blk & 511;
  int p = sidx[b * PDIM + j];
  int s0 = boxes[(size_t)(b * PDIM + p) * 2];
  int e0 = boxes[(size_t)(b * PDIM + p) * 2 + 1];
  int start = min(max(s0, 0), TDIM - 1);
  int end   = min(max(e0, 1), TDIM);
  if (end <= start) end = min(start + 1, TDIM);
  int n = end - start;

  int lo[7], hi[7], cb[7], cl[7];
  {
    const int Ls[3] = {1, 2, 4};
    const int Bo[3] = {0, 512, 1536};
    int q = 0;
    for (int li = 0; li < 3; ++li){
      int L = Ls[li];
      for (int i = 0; i < L; ++i){
        lo[q] = start + (i * n) / L;
        hi[q] = start + ((i + 1) * n + L - 1) / L;
        cb[q] = Bo[li] + i;
        cl[q] = L;
        ++q;
      }
    }
  }
  float s_f = (float)s0, e_f = (float)e0;
  float px = (s_f + e_f) * 0.5f / (float)TDIM;
  float py = fmaxf(e_f - s_f, 1.f) / (float)TDIM;
  short* Ar = A + (size_t)(b * PDIM + j) * AKDIM;
  const float* Wb = W + (size_t)b * TDIM * CDIM;
  const float* ob = off + (size_t)b * 16 * CDIM;
  for (int c = threadIdx.x; c < CDIM; c += 256){
#pragma unroll
    for (int q = 0; q < 7; ++q){
      int l = lo[q], h = hi[q];
      float fl = (l == 0) ? 0.f : (Wb[(size_t)(l - 1) * CDIM + c] + ob[((l - 1) >> 7) * CDIM + c]);
      float fh = Wb[(size_t)(h - 1) * CDIM + c] + ob[((h - 1) >> 7) * CDIM + c];
      Ar[cb[q] + c * cl[q]] = f2b((fh - fl) / (float)(h - l));
    }
    float hv = pw1[c * 2] * px + pw1[c * 2 + 1] * py + pb1[c];
    Ar[SPPOUT + c] = f2b(fmaxf(hv, 0.f));
  }
}

// MFMA bf16 GEMM (nt): C[M,N] = act(alpha * A[M,K] @ B[N,K]^T + bias + resid)
// 128-row tiles, BK=64, XOR-swizzled LDS (conflict-free frag reads).
// SWZ=1: XCD-locality remap for the (8,32,4) G1 grid (each XCD owns 4 row-tiles).
template<int BN, int SWZ = 0>
__global__ __launch_bounds__(256) void gemm_bt(
    int M, int N, int K,
    const short* __restrict__ A, int lda, long long sAb, long long sAh,
    const short* __restrict__ B, int ldb, long long sBb, long long sBh,
    float* __restrict__ Cf, short* __restrict__ Cb, int ldc, long long sCb, long long sCh,
    int hdiv, float alpha,
    const float* __restrict__ bias, const float* __restrict__ resid, int act)
{
  constexpr int JF = BN / 32;                 // B-frags per wave / B staging batches
  __shared__ short As[128 * 64];
  __shared__ short Bs[BN * 64];
  int bx = blockIdx.x, by = blockIdx.y, bz = blockIdx.z;
  if constexpr (SWZ){                         // valid for grid (8,32,4) only
    int flat = (bz * 32 + by) * 8 + bx;
    int wl = flat >> 3;
    by = (flat & 7) * 4 + (wl & 3);
    bx = (wl >> 2) & 7;
    bz = wl >> 5;
  }
  int zb = bz / hdiv, zh = bz - zb * hdiv;
  A += (size_t)zb * sAb + (size_t)zh * sAh;
  B += (size_t)zb * sBb + (size_t)zh * sBh;
  size_t coff = (size_t)zb * sCb + (size_t)zh * sCh;
  int rowBase = by * 128, colBase = bx * BN;
  int t = threadIdx.x;
  int lane = t & 63;
  int wave = t >> 6;
  int wm = (wave >> 1) * 64, wn = (wave & 1) * (BN / 2);
  int lm = lane & 15, quad = lane >> 4;
  int srow = t >> 3;
  int skw = ((t & 7) * 8) ^ ((srow & 7) * 8);

  const short* Agp[4];
#pragma unroll
  for (int it = 0; it < 4; ++it)
    Agp[it] = A + (size_t)min(rowBase + srow + it * 32, M - 1) * lda + skw;
  const short* Bgp[JF];
#pragma unroll
  for (int it = 0; it < JF; ++it)
    Bgp[it] = B + (size_t)min(colBase + srow + it * 32, N - 1) * ldb + skw;

  f32x4 zero4 = {0.f, 0.f, 0.f, 0.f};
  f32x4 acc[4][JF];
#pragma unroll
  for (int i = 0; i < 4; ++i)
#pragma unroll
    for (int j = 0; j < JF; ++j) acc[i][j] = zero4;

  int axr = (lm & 7) * 8;
  for (int k0 = 0; k0 < K; k0 += 64){
#pragma unroll
    for (int it = 0; it < 4; ++it) gl_lds16(Agp[it] + k0, As + it * 2048 + t * 8);
#pragma unroll
    for (int it = 0; it < JF; ++it) gl_lds16(Bgp[it] + k0, Bs + it * 2048 + t * 8);
    __syncthreads();
#pragma unroll
    for (int h = 0; h < 2; ++h){
      int koff = (h * 32 + quad * 8) ^ axr;
      short8 af[4], bfr[JF];
#pragma unroll
      for (int i = 0; i < 4; ++i)
        af[i] = *(const short8*)(As + (wm + i * 16 + lm) * 64 + koff);
#pragma unroll
      for (int j = 0; j < JF; ++j)
        bfr[j] = *(const short8*)(Bs + (wn + j * 16 + lm) * 64 + koff);
#pragma unroll
      for (int i = 0; i < 4; ++i)
#pragma unroll
        for (int j = 0; j < JF; ++j)
          acc[i][j] = __builtin_amdgcn_mfma_f32_16x16x32_bf16(af[i], bfr[j], acc[i][j], 0, 0, 0);
    }
    __syncthreads();
  }

#pragma unroll
  for (int i = 0; i < 4; ++i){
#pragma unroll
    for (int j = 0; j < JF; ++j){
#pragma unroll
      for (int r = 0; r < 4; ++r){
        int row = rowBase + wm + i * 16 + quad * 4 + r;
        int col = colBase + wn + j * 16 + lm;
        if (row < M && col < N){
          float v = acc[i][j][r] * alpha;
          if (bias) v += bias[col];
          size_t ci = coff + (size_t)row * ldc + col;
          if (resid) v += resid[ci];
          if (act) v = 0.5f * v * (1.f + erff(v * 0.7071067811865476f));
          if (Cf) Cf[ci] = v;
          if (Cb) Cb[ci] = f2b(v);
        }
      }
    }
  }
}

// reduce 4 split-K partial slabs + bias -> tok f32 + bf16
__global__ void kredG1(const float* __restrict__ part, const float* __restrict__ bias,
                       float* __restrict__ tok, short* __restrict__ tokb){
  int i = blockIdx.x * 256 + threadIdx.x;   // over 4096*512
  float v = part[i] + part[i + 2097152] + part[i + 4194304] + part[i + 6291456] + bias[i & 511];
  tok[i] = v;
  tokb[i] = f2b(v);
}

// transpose V (from qkv bf16 buffer) into Vt[b*4+h][128][512]
__global__ void kvt(const short* __restrict__ qkvb, short* __restrict__ Vt){
  __shared__ short T[32][33];
  int bh = blockIdx.x, pt = blockIdx.y, nt = blockIdx.z;
  int b = bh >> 2, h = bh & 3;
  int tx = threadIdx.x, ty = threadIdx.y;
  const short* src = qkvb + (size_t)(b * 512) * 1536 + 1024 + h * 128;
  int p0 = pt * 32, n0 = nt * 32;
#pragma unroll
  for (int q = 0; q < 4; ++q)
    T[ty * 4 + q][tx] = src[(size_t)(p0 + ty * 4 + q) * 1536 + n0 + tx];
  __syncthreads();
  short* dst = Vt + (size_t)bh * 128 * 512;
#pragma unroll
  for (int q = 0; q < 4; ++q)
    dst[(size_t)(n0 + ty * 4 + q) * 512 + p0 + tx] = T[tx][ty * 4 + q];
}

// Fused flash attention: one block per (bh, 64-q-row tile); 4 waves x 16 q-rows.
// S=QK^T via MFMA (frags direct from qkvb), online softmax on C-layout,
// P through wave-private swizzled LDS (C->A layout), O += P@V (B-frags from Vt),
// final O/l written to ob[b][q][h*128+d].
__global__ __launch_bounds__(256) void kflash(const short* __restrict__ qkvb,
                                              const short* __restrict__ Vt,
                                              short* __restrict__ ob){
  __shared__ short P[4][1024];
  int bid = blockIdx.x;                 // qt*32 + bh  (same-bh blocks 32 apart -> same XCD)
  int bh = bid & 31, qt = bid >> 5;
  int b = bh >> 2, h = bh & 3;
  int t = threadIdx.x;
  int w = t >> 6, lane = t & 63;
  int lm = lane & 15, quad = lane >> 4;
  const float scale = 0.08838834764831845f;  // 1/sqrt(128)

  // Q frags (held in regs): A[m=lm -> q-row][k=d]
  const short* qbase = qkvb + (size_t)(b * 512 + qt * 64 + w * 16 + lm) * 1536 + h * 128 + quad * 8;
  short8 qf[4];
#pragma unroll
  for (int s = 0; s < 4; ++s) qf[s] = *(const short8*)(qbase + s * 32);

  const short* kbase = qkvb + (size_t)(b * 512) * 1536 + 512 + h * 128 + quad * 8;
  const short* vbase = Vt + (size_t)bh * 65536 + (size_t)lm * 512 + quad * 8;

  f32x4 zero4 = {0.f, 0.f, 0.f, 0.f};
  f32x4 Of[8];
#pragma unroll
  for (int i = 0; i < 8; ++i) Of[i] = zero4;
  float mrun[4] = {-1e30f, -1e30f, -1e30f, -1e30f};
  float lrun[4] = {0.f, 0.f, 0.f, 0.f};
  short* Pw = &P[w][0];

  for (int kt = 0; kt < 8; ++kt){
    // S = Q @ K_tile^T  (64 keys): C[q=quad*4+r][key=j*16+lm]
    f32x4 Sf[4];
#pragma unroll
    for (int j = 0; j < 4; ++j) Sf[j] = zero4;
#pragma unroll
    for (int s = 0; s < 4; ++s){
#pragma unroll
      for (int j = 0; j < 4; ++j){
        short8 kf = *(const short8*)(kbase + (size_t)(kt * 64 + j * 16 + lm) * 1536 + s * 32);
        Sf[j] = __builtin_amdgcn_mfma_f32_16x16x32_bf16(qf[s], kf, Sf[j], 0, 0, 0);
      }
    }
    // online softmax per q-row r
    float alpha[4];
#pragma unroll
    for (int r = 0; r < 4; ++r){
      float mx = fmaxf(fmaxf(Sf[0][r], Sf[1][r]), fmaxf(Sf[2][r], Sf[3][r])) * scale;
#pragma unroll
      for (int o = 1; o < 16; o <<= 1) mx = fmaxf(mx, __shfl_xor(mx, o));
      float mnew = fmaxf(mrun[r], mx);
      alpha[r] = expf(mrun[r] - mnew);
      float psum = 0.f;
#pragma unroll
      for (int j = 0; j < 4; ++j){
        float p = expf(Sf[j][r] * scale - mnew);
        Sf[j][r] = p;
        psum += p;
      }
#pragma unroll
      for (int o = 1; o < 16; o <<= 1) psum += __shfl_xor(psum, o);
      lrun[r] = lrun[r] * alpha[r] + psum;
      mrun[r] = mnew;
    }
#pragma unroll
    for (int i = 0; i < 8; ++i)
#pragma unroll
      for (int r = 0; r < 4; ++r) Of[i][r] *= alpha[r];
    // P -> LDS (bf16), swizzled: elem (q,key) at q*64 + (key ^ ((q&7)*8))
#pragma unroll
    for (int j = 0; j < 4; ++j)
#pragma unroll
      for (int r = 0; r < 4; ++r){
        int q = quad * 4 + r;
        int key = j * 16 + lm;
        Pw[q * 64 + (key ^ ((q & 7) * 8))] = f2b(Sf[j][r]);
      }
    // PV: A[m=lm -> q][k=key] from LDS; B[n=d][k=key] from Vt
#pragma unroll
    for (int ts = 0; ts < 2; ++ts){
      short8 pa = *(const short8*)(Pw + lm * 64 + (((ts * 32 + quad * 8) ^ ((lm & 7) * 8))));
#pragma unroll
      for (int jd = 0; jd < 8; ++jd){
        short8 vf = *(const short8*)(vbase + (size_t)(jd * 16) * 512 + kt * 64 + ts * 32);
        Of[jd] = __builtin_amdgcn_mfma_f32_16x16x32_bf16(pa, vf, Of[jd], 0, 0, 0);
      }
    }
  }
  // epilogue: O/l -> ob[b][q][h*128+d]
  float inv[4];
#pragma unroll
  for (int r = 0; r < 4; ++r) inv[r] = 1.f / lrun[r];
  int qg = qt * 64 + w * 16 + quad * 4;
#pragma unroll
  for (int jd = 0; jd < 8; ++jd)
#pragma unroll
    for (int r = 0; r < 4; ++r){
      size_t ci = ((size_t)(b * 512 + qg + r)) * 512 + h * 128 + jd * 16 + lm;
      ob[ci] = f2b(Of[jd][r] * inv[r]);
    }
}

// fused: reduce 2 split-K slabs + bias + residual + LayerNorm -> f32 + bf16
__global__ void klnR(const float* __restrict__ part, const float* __restrict__ bias,
                     const float* __restrict__ resid,
                     const float* __restrict__ g, const float* __restrict__ bb,
                     float* __restrict__ Yf, short* __restrict__ Yb){
  int row = blockIdx.x, lane = threadIdx.x;
  size_t base = (size_t)row * DMODEL;
  float v[8]; float s = 0.f;
#pragma unroll
  for (int i = 0; i < 8; ++i){
    int c = lane + 64 * i;
    v[i] = part[base + c] + part[base + c + 2097152] + bias[c] + resid[base + c];
    s += v[i];
  }
  s = waveSum(s);
  float m = s * (1.f / DMODEL);
  float q = 0.f;
#pragma unroll
  for (int i = 0; i < 8; ++i){ float d = v[i] - m; q += d * d; }
  q = waveSum(q);
  float inv = rsqrtf(q * (1.f / DMODEL) + 1e-5f);
#pragma unroll
  for (int i = 0; i < 8; ++i){
    int c = lane + 64 * i;
    float o = (v[i] - m) * inv * g[c] + bb[c];
    Yf[base + c] = o;
    Yb[base + c] = f2b(o);
  }
}

// det softmax over P (columns), reading det part (cols 30..59) of headS [4096][60]
__global__ void kdetsm(const float* __restrict__ hd, float* __restrict__ dp){
  int b = blockIdx.x / NCOUT, c = blockIdx.x % NCOUT, lane = threadIdx.x;
  float v[8]; float m = -1e30f;
#pragma unroll
  for (int i = 0; i < 8; ++i){
    v[i] = hd[((size_t)(b * PDIM) + lane + 64 * i) * 60 + 30 + c];
    m = fmaxf(m, v[i]);
  }
  m = waveMax(m);
  float s = 0.f;
#pragma unroll
  for (int i = 0; i < 8; ++i){ v[i] = expf(v[i] - m); s += v[i]; }
  s = waveSum(s);
  float r = 1.f / s;
#pragma unroll
  for (int i = 0; i < 8; ++i)
    dp[((size_t)(b * PDIM) + lane + 64 * i) * NCOUT + c] = v[i] * r;
}

// class softmax + joint + scatter back to original order + ctx copy + video accumulation
__global__ void kfinal(const float* __restrict__ hd, const float* __restrict__ dps,
                       const float* __restrict__ tok, const int* __restrict__ sidx,
                       float* __restrict__ out){
  int blk = blockIdx.x;
  int b = blk >> 9, j = blk & 511;
  int lane = threadIdx.x;
  int p = sidx[b * PDIM + j];
  float* video = out;
  float* joint = out + 240;
  float* clso  = out + 123120;
  float* deto  = out + 246000;
  float* ctxo  = out + 368880;
  size_t rs60 = (size_t)(b * PDIM + j) * 60;
  size_t rs30 = (size_t)(b * PDIM + j) * NCOUT;
  size_t ro = (size_t)(b * PDIM + p) * NCOUT;
  float lc = (lane < NCOUT) ? hd[rs60 + lane] : -1e30f;
  float m = waveMax(lc);
  float e = (lane < NCOUT) ? expf(lc - m) : 0.f;
  float s = waveSum(e);
  float cp = e / s;
  if (lane < NCOUT){
    float dv  = hd[rs60 + 30 + lane];
    float dpv = dps[rs30 + lane];
    float jp  = cp * dpv;
    clso[ro + lane] = lc;
    deto[ro + lane] = dv;
    joint[ro + lane] = jp;
    atomicAdd(&video[b * NCOUT + lane], jp);
  }
  const float* tr = tok + (size_t)(b * PDIM + j) * DMODEL;
  float* cr = ctxo + (size_t)(b * PDIM + p) * DMODEL;
  for (int c = lane; c < DMODEL; c += 64) cr[c] = tr[c];
}

extern "C" void kernel_launch(void* const* d_in, const int* in_sizes, int n_in,
                              void* d_out, int out_size, void* d_ws, size_t ws_size,
                              hipStream_t stream) {
  const float* x      = (const float*)d_in[0];
  const int*   boxes  = (const int*)d_in[1];
  const float* proj_w = (const float*)d_in[2];
  const float* proj_b = (const float*)d_in[3];
  const float* pos_w1 = (const float*)d_in[4];
  const float* pos_b1 = (const float*)d_in[5];
  const float* pos_w2 = (const float*)d_in[6];
  const float* pos_b2 = (const float*)d_in[7];
  const float* qkv_w  = (const float*)d_in[8];
  const float* qkv_b  = (const float*)d_in[9];
  const float* out_w  = (const float*)d_in[10];
  const float* out_b  = (const float*)d_in[11];
  const float* ln1_g  = (const float*)d_in[12];
  const float* ln1_b  = (const float*)d_in[13];
  const float* ff1_w  = (const float*)d_in[14];
  const float* ff1_b  = (const float*)d_in[15];
  const float* ff2_w  = (const float*)d_in[16];
  const float* ff2_b  = (const float*)d_in[17];
  const float* ln2_g  = (const float*)d_in[18];
  const float* ln2_b  = (const float*)d_in[19];
  const float* cls_w  = (const float*)d_in[20];
  const float* cls_b  = (const float*)d_in[21];
  const float* det_w  = (const float*)d_in[22];
  const float* det_b  = (const float*)d_in[23];
  float* out = (float*)d_out;
  float* ws  = (float*)d_ws;

  // ---- workspace layout (FLOAT units) ----
  const size_t oR1    = 0;
  const size_t oS     = 9437184;    // csum, then G1 split-K partials, then out-proj/ff2 partials
  const size_t oTok   = 22020096;   // 2,097,152 fl
  const size_t oTokb  = 24117248;   // 1,048,576 fl
  const size_t oTok2  = 25165824;   // 2,097,152 fl
  const size_t oTok2b = 27262976;   // 1,048,576 fl
  const size_t oWcat  = 28311552;   // 1,048,576 fl
  const size_t oBcat  = 29360128;   // 512 fl
  const size_t oWq    = 29360640;   // kprep2 dest base; contiguous qkv|out|ff1|ff2|cls|det
  const size_t oWo    = 30147072;
  const size_t oWf1   = 30409216;
  const size_t oWf2   = 30933504;
  const size_t oWcls  = 31457792;
  const size_t oTot   = 31473152;   // 65,536 fl; bhead aliases its start (tot dead after koff)
  const size_t oOff   = 31538688;   // 65,536 fl
  const size_t oSidx  = 31604224;   // int[4096] = 4,096 fl -> end 31,608,320 (~126.4 MB)
  const size_t oBhead = oTot;

  short* Abf   = (short*)(ws + oR1);
  short* qkvb  = (short*)(ws + oR1);
  short* Vt    = (short*)(ws + oR1 + 3145728);
  short* obufb = (short*)(ws + oR1 + 4194304);
  short* hbufb = (short*)(ws + oR1 + 5242880);
  float* headS = ws + oR1 + 7340032;              // [4096][60] after layers (hbufb dead)
  float* dpS   = ws + oR1 + 7585792;
  float* csum  = ws + oS;
  float* Cpart = ws + oS;
  float* Cp2   = ws + oS;                          // 2-slab partials (out-proj / ff2)
  float* tok   = ws + oTok;
  short* tokb  = (short*)(ws + oTokb);
  float* tok2  = ws + oTok2;
  short* tok2b = (short*)(ws + oTok2b);
  short* Wcatb = (short*)(ws + oWcat);
  float* bcat  = ws + oBcat;
  short* Wq    = (short*)(ws + oWq);
  short* Wo    = (short*)(ws + oWo);
  short* Wf1   = (short*)(ws + oWf1);
  short* Wf2   = (short*)(ws + oWf2);
  short* Whead = (short*)(ws + oWcls);            // cls||det rows: [60][512]
  float* tot   = ws + oTot;
  float* offp  = ws + oOff;
  int*   sidx  = (int*)(ws + oSidx);
  float* bhead = ws + oBhead;

  kscan<<<256, 256, 0, stream>>>(x, csum, tot);
  koff<<<16, 256, 0, stream>>>(tot, offp);
  ksort<<<BDIM, 512, 0, stream>>>(boxes, sidx, out);
  kprep2<<<24699, 256, 0, stream>>>(proj_w, pos_w2, qkv_w, out_w, ff1_w, ff2_w, cls_w, det_w,
                                    proj_b, pos_b2, cls_b, det_b, Wcatb, Wq, bcat, bhead);
  kspp<<<BDIM * PDIM, 256, 0, stream>>>(csum, offp, boxes, sidx, pos_w1, pos_b1, Abf);

  // G1 split-K-4 x BN=64, XCD-swizzled: 1024 blocks (4/CU)
  gemm_bt<64, 1><<<dim3(8, 32, 4), 256, 0, stream>>>(
      4096, 512, 1024, Abf, 4096, 1024, 0, Wcatb, 4096, 1024, 0,
      Cpart, nullptr, 512, 2097152, 0, 1, 1.f, nullptr, nullptr, 0);
  kredG1<<<8192, 256, 0, stream>>>(Cpart, bcat, tok, tokb);

  for (int l = 0; l < 2; ++l){
    const short* qw  = Wq  + (size_t)l * 1536 * 512;
    const short* ow  = Wo  + (size_t)l * 512 * 512;
    const short* f1w = Wf1 + (size_t)l * 1024 * 512;
    const short* f2w = Wf2 + (size_t)l * 512 * 1024;
    const float* qb  = qkv_b + (size_t)l * 1536;
    const float* obv = out_b + (size_t)l * 512;
    const float* f1b = ff1_b + (size_t)l * 1024;
    const float* f2b_ = ff2_b + (size_t)l * 512;

    // qkv = tok @ qkv_w^T + qkv_b   [4096, 1536] (bf16 out; 768 blocks, 3/CU)
    gemm_bt<64><<<dim3(24, 32, 1), 256, 0, stream>>>(
        4096, 1536, 512, tokb, 512, 0, 0, qw, 512, 0, 0,
        nullptr, qkvb, 1536, 0, 0, 1, 1.f, qb, nullptr, 0);
    // V transpose for flash B-frags
    kvt<<<dim3(32, 16, 4), dim3(32, 8), 0, stream>>>(qkvb, Vt);
    // fused flash attention -> obufb[b][q][h*128+d]
    kflash<<<256, 256, 0, stream>>>(qkvb, Vt, obufb);
    // out-proj split-K-2 (512 blocks), then fused reduce+bias+resid+LN1
    gemm_bt<64><<<dim3(8, 32, 2), 256, 0, stream>>>(
        4096, 512, 256, obufb, 512, 256, 0, ow, 512, 256, 0,
        Cp2, nullptr, 512, 2097152, 0, 1, 1.f, nullptr, nullptr, 0);
    klnR<<<4096, 64, 0, stream>>>(Cp2, obv, tok, ln1_g + l * 512, ln1_b + l * 512, tok2, tok2b);
    // hbuf = gelu(tok2 @ ff1^T + b1) (bf16; 512 blocks)
    gemm_bt<64><<<dim3(16, 32, 1), 256, 0, stream>>>(
        4096, 1024, 512, tok2b, 512, 0, 0, f1w, 512, 0, 0,
        nullptr, hbufb, 1024, 0, 0, 1, 1.f, f1b, nullptr, 1);
    // ff2 split-K-2 (512 blocks), then fused reduce+bias+resid+LN2
    gemm_bt<64><<<dim3(8, 32, 2), 256, 0, stream>>>(
        4096, 512, 512, hbufb, 1024, 512, 0, f2w, 1024, 512, 0,
        Cp2, nullptr, 512, 2097152, 0, 1, 1.f, nullptr, nullptr, 0);
    klnR<<<4096, 64, 0, stream>>>(Cp2, f2b_, tok2, ln2_g + l * 512, ln2_b + l * 512, tok, tokb);
  }

  // fused heads: headS[4096][60] = tok @ [cls_w;det_w]^T + [cls_b;det_b]
  gemm_bt<64><<<dim3(1, 32, 1), 256, 0, stream>>>(
      4096, 60, 512, tokb, 512, 0, 0, Whead, 512, 0, 0,
      headS, nullptr, 60, 0, 0, 1, 1.f, bhead, nullptr, 0);
  kdetsm<<<BDIM * NCOUT, 64, 0, stream>>>(headS, dpS);
  kfinal<<<BDIM * PDIM, 64, 0, stream>>>(headS, dpS, tok, sidx, out);
}

// Round 10
// 507.507 us; speedup vs baseline: 5.6650x; 1.0715x over previous
//
#include <hip/hip_runtime.h>

#define TDIM 2048
#define CDIM 512
#define BDIM 8
#define PDIM 512
#define DMODEL 512
#define NCOUT 30
#define SPPOUT 3584
#define AKDIM 4096   // SPPOUT + DMODEL

typedef __attribute__((ext_vector_type(8))) short short8;
typedef __attribute__((ext_vector_type(4))) float f32x4;

typedef const __attribute__((address_space(1))) void* as1cv;
typedef __attribute__((address_space(3))) void* as3v;

// async global->LDS, 16B per lane; LDS dest must be wave-uniform base + lane*16
__device__ __forceinline__ void gl_lds16(const short* g, short* l){
  __builtin_amdgcn_global_load_lds((as1cv)g, (as3v)l, 16, 0, 0);
}

__device__ __forceinline__ short f2b(float f){
  unsigned u = __float_as_uint(f);
  unsigned r = (u + 0x7fffu + ((u >> 16) & 1u)) >> 16;
  return (short)r;
}

__device__ __forceinline__ float waveSum(float v){
#pragma unroll
  for (int o = 32; o > 0; o >>= 1) v += __shfl_xor(v, o);
  return v;
}
__device__ __forceinline__ float waveMax(float v){
#pragma unroll
  for (int o = 32; o > 0; o >>= 1) v = fmaxf(v, __shfl_xor(v, o));
  return v;
}

// fused prep: Wcat bf16 | all layer+head weights bf16 | bcat & bhead biases
__global__ void kprep2(const float* __restrict__ pw, const float* __restrict__ pw2,
                       const float* __restrict__ qw, const float* __restrict__ ow,
                       const float* __restrict__ f1, const float* __restrict__ f2,
                       const float* __restrict__ cl, const float* __restrict__ dt,
                       const float* __restrict__ pb, const float* __restrict__ pb2,
                       const float* __restrict__ cb, const float* __restrict__ db,
                       short* __restrict__ Wc, short* __restrict__ Wd,
                       float* __restrict__ bc, float* __restrict__ bh){
  int i = blockIdx.x * 256 + threadIdx.x;
  if (i < 2097152){
    int r = i >> 12, k = i & 4095;
    float v = (k < SPPOUT) ? pw[(size_t)r * SPPOUT + k] : pw2[(size_t)r * DMODEL + (k - SPPOUT)];
    Wc[i] = f2b(v);
  } else if (i < 6322176){
    int j = i - 2097152;
    float v;
    if (j < 1572864) v = qw[j];
    else if (j < 2097152) v = ow[j - 1572864];
    else if (j < 3145728) v = f1[j - 2097152];
    else if (j < 4194304) v = f2[j - 3145728];
    else if (j < 4209664) v = cl[j - 4194304];
    else v = dt[j - 4209664];
    Wd[j] = f2b(v);
  } else {
    int k = i - 6322176;
    if (k < 512) bc[k] = pb[k] + pb2[k];
    else if (k < 572) bh[k - 512] = (k < 542) ? cb[k - 512] : db[k - 542];
  }
}

// Chunked inclusive scan along T: 16 chunks of 128. W[b][t][c] = sum x[b,c, chunkstart..t]
__global__ void kscan(const float* __restrict__ x, float* __restrict__ W, float* __restrict__ tot){
  int idx = blockIdx.x;             // b*32 + ch*2 + cg  (256 blocks)
  int b = idx >> 5, rem = idx & 31, ch = rem >> 1, cg = rem & 1;
  int c = cg * 256 + threadIdx.x;
  const float* xp = x + ((size_t)(b * CDIM + c)) * TDIM + ch * 128;
  float* wp = W + ((size_t)b * TDIM + ch * 128) * CDIM + c;
  float run = 0.f;
  for (int tl = 0; tl < 128; tl += 4){
    float4 v = *(const float4*)(xp + tl);
    run += v.x; wp[(size_t)(tl + 0) * CDIM] = run;
    run += v.y; wp[(size_t)(tl + 1) * CDIM] = run;
    run += v.z; wp[(size_t)(tl + 2) * CDIM] = run;
    run += v.w; wp[(size_t)(tl + 3) * CDIM] = run;
  }
  tot[((size_t)b * 16 + ch) * CDIM + c] = run;
}

__global__ void koff(const float* __restrict__ tot, float* __restrict__ off){
  int b = blockIdx.x >> 1, cg = blockIdx.x & 1;
  int c = cg * 256 + threadIdx.x;
  float run = 0.f;
  for (int ch = 0; ch < 16; ++ch){
    off[((size_t)b * 16 + ch) * CDIM + c] = run;
    run += tot[((size_t)b * 16 + ch) * CDIM + c];
  }
}

// Stable argsort by center (+ zero the video-prob output region in block 0)
__global__ void ksort(const int* __restrict__ boxes, int* __restrict__ sidx, float* __restrict__ out){
  __shared__ unsigned key[PDIM];
  int b = blockIdx.x, t = threadIdx.x;
  if (b == 0 && t < 240) out[t] = 0.f;
  int s = boxes[(size_t)(b * PDIM + t) * 2];
  int e = boxes[(size_t)(b * PDIM + t) * 2 + 1];
  key[t] = ((unsigned)(s + e) << 9) | (unsigned)t;
  __syncthreads();
  for (int k = 2; k <= PDIM; k <<= 1){
    for (int j = k >> 1; j > 0; j >>= 1){
      int ixj = t ^ j;
      if (ixj > t){
        unsigned a = key[t], c2 = key[ixj];
        bool up = ((t & k) == 0);
        bool doswap = up ? (a > c2) : (a < c2);
        if (doswap){ key[t] = c2; key[ixj] = a; }
      }
      __syncthreads();
    }
  }
  sidx[b * PDIM + t] = (int)(key[t] & 511u);
}

// SPP pooling + pos-MLP hidden, staged in sorted order as bf16: A[b][j][0..4095]
__global__ void kspp(const float* __restrict__ W, const float* __restrict__ off,
                     const int* __restrict__ boxes, const int* __restrict__ sidx,
                     const float* __restrict__ pw1, const float* __restrict__ pb1,
                     short* __restrict__ A){
  int blk = blockIdx.x;
  int b = blk >> 9, j = blk & 511;
  int p = sidx[b * PDIM + j];
  int s0 = boxes[(size_t)(b * PDIM + p) * 2];
  int e0 = boxes[(size_t)(b * PDIM + p) * 2 + 1];
  int start = min(max(s0, 0), TDIM - 1);
  int end   = min(max(e0, 1), TDIM);
  if (end <= start) end = min(start + 1, TDIM);
  int n = end - start;

  int lo[7], hi[7], cb[7], cl[7];
  {
    const int Ls[3] = {1, 2, 4};
    const int Bo[3] = {0, 512, 1536};
    int q = 0;
    for (int li = 0; li < 3; ++li){
      int L = Ls[li];
      for (int i = 0; i < L; ++i){
        lo[q] = start + (i * n) / L;
        hi[q] = start + ((i + 1) * n + L - 1) / L;
        cb[q] = Bo[li] + i;
        cl[q] = L;
        ++q;
      }
    }
  }
  float s_f = (float)s0, e_f = (float)e0;
  float px = (s_f + e_f) * 0.5f / (float)TDIM;
  float py = fmaxf(e_f - s_f, 1.f) / (float)TDIM;
  short* Ar = A + (size_t)(b * PDIM + j) * AKDIM;
  const float* Wb = W + (size_t)b * TDIM * CDIM;
  const float* ob = off + (size_t)b * 16 * CDIM;
  for (int c = threadIdx.x; c < CDIM; c += 256){
#pragma unroll
    for (int q = 0; q < 7; ++q){
      int l = lo[q], h = hi[q];
      float fl = (l == 0) ? 0.f : (Wb[(size_t)(l - 1) * CDIM + c] + ob[((l - 1) >> 7) * CDIM + c]);
      float fh = Wb[(size_t)(h - 1) * CDIM + c] + ob[((h - 1) >> 7) * CDIM + c];
      Ar[cb[q] + c * cl[q]] = f2b((fh - fl) / (float)(h - l));
    }
    float hv = pw1[c * 2] * px + pw1[c * 2 + 1] * py + pb1[c];
    Ar[SPPOUT + c] = f2b(fmaxf(hv, 0.f));
  }
}

// MFMA bf16 GEMM (nt): C[M,N] = act(alpha * A[M,K] @ B[N,K]^T + bias + resid)
// 128-row tiles, BK=64, XOR-swizzled LDS (conflict-free frag reads).
// SWZ=1: XCD-locality remap for the (8,32,4) G1 grid (each XCD owns 4 row-tiles).
template<int BN, int SWZ = 0>
__global__ __launch_bounds__(256) void gemm_bt(
    int M, int N, int K,
    const short* __restrict__ A, int lda, long long sAb, long long sAh,
    const short* __restrict__ B, int ldb, long long sBb, long long sBh,
    float* __restrict__ Cf, short* __restrict__ Cb, int ldc, long long sCb, long long sCh,
    int hdiv, float alpha,
    const float* __restrict__ bias, const float* __restrict__ resid, int act)
{
  constexpr int JF = BN / 32;                 // B-frags per wave / B staging batches
  __shared__ short As[128 * 64];
  __shared__ short Bs[BN * 64];
  int bx = blockIdx.x, by = blockIdx.y, bz = blockIdx.z;
  if constexpr (SWZ){                         // valid for grid (8,32,4) only
    int flat = (bz * 32 + by) * 8 + bx;
    int wl = flat >> 3;
    by = (flat & 7) * 4 + (wl & 3);
    bx = (wl >> 2) & 7;
    bz = wl >> 5;
  }
  int zb = bz / hdiv, zh = bz - zb * hdiv;
  A += (size_t)zb * sAb + (size_t)zh * sAh;
  B += (size_t)zb * sBb + (size_t)zh * sBh;
  size_t coff = (size_t)zb * sCb + (size_t)zh * sCh;
  int rowBase = by * 128, colBase = bx * BN;
  int t = threadIdx.x;
  int lane = t & 63;
  int wave = t >> 6;
  int wm = (wave >> 1) * 64, wn = (wave & 1) * (BN / 2);
  int lm = lane & 15, quad = lane >> 4;
  int srow = t >> 3;
  int skw = ((t & 7) * 8) ^ ((srow & 7) * 8);

  const short* Agp[4];
#pragma unroll
  for (int it = 0; it < 4; ++it)
    Agp[it] = A + (size_t)min(rowBase + srow + it * 32, M - 1) * lda + skw;
  const short* Bgp[JF];
#pragma unroll
  for (int it = 0; it < JF; ++it)
    Bgp[it] = B + (size_t)min(colBase + srow + it * 32, N - 1) * ldb + skw;

  f32x4 zero4 = {0.f, 0.f, 0.f, 0.f};
  f32x4 acc[4][JF];
#pragma unroll
  for (int i = 0; i < 4; ++i)
#pragma unroll
    for (int j = 0; j < JF; ++j) acc[i][j] = zero4;

  int axr = (lm & 7) * 8;
  for (int k0 = 0; k0 < K; k0 += 64){
#pragma unroll
    for (int it = 0; it < 4; ++it) gl_lds16(Agp[it] + k0, As + it * 2048 + t * 8);
#pragma unroll
    for (int it = 0; it < JF; ++it) gl_lds16(Bgp[it] + k0, Bs + it * 2048 + t * 8);
    __syncthreads();
#pragma unroll
    for (int h = 0; h < 2; ++h){
      int koff = (h * 32 + quad * 8) ^ axr;
      short8 af[4], bfr[JF];
#pragma unroll
      for (int i = 0; i < 4; ++i)
        af[i] = *(const short8*)(As + (wm + i * 16 + lm) * 64 + koff);
#pragma unroll
      for (int j = 0; j < JF; ++j)
        bfr[j] = *(const short8*)(Bs + (wn + j * 16 + lm) * 64 + koff);
#pragma unroll
      for (int i = 0; i < 4; ++i)
#pragma unroll
        for (int j = 0; j < JF; ++j)
          acc[i][j] = __builtin_amdgcn_mfma_f32_16x16x32_bf16(af[i], bfr[j], acc[i][j], 0, 0, 0);
    }
    __syncthreads();
  }

#pragma unroll
  for (int i = 0; i < 4; ++i){
#pragma unroll
    for (int j = 0; j < JF; ++j){
#pragma unroll
      for (int r = 0; r < 4; ++r){
        int row = rowBase + wm + i * 16 + quad * 4 + r;
        int col = colBase + wn + j * 16 + lm;
        if (row < M && col < N){
          float v = acc[i][j][r] * alpha;
          if (bias) v += bias[col];
          size_t ci = coff + (size_t)row * ldc + col;
          if (resid) v += resid[ci];
          if (act) v = 0.5f * v * (1.f + erff(v * 0.7071067811865476f));
          if (Cf) Cf[ci] = v;
          if (Cb) Cb[ci] = f2b(v);
        }
      }
    }
  }
}

// reduce 4 split-K partial slabs + bias -> tok f32 + bf16
__global__ void kredG1(const float* __restrict__ part, const float* __restrict__ bias,
                       float* __restrict__ tok, short* __restrict__ tokb){
  int i = blockIdx.x * 256 + threadIdx.x;   // over 4096*512
  float v = part[i] + part[i + 2097152] + part[i + 4194304] + part[i + 6291456] + bias[i & 511];
  tok[i] = v;
  tokb[i] = f2b(v);
}

// transpose V (from qkv bf16 buffer) into Vt[b*4+h][128][512]
__global__ void kvt(const short* __restrict__ qkvb, short* __restrict__ Vt){
  __shared__ short T[32][33];
  int bh = blockIdx.x, pt = blockIdx.y, nt = blockIdx.z;
  int b = bh >> 2, h = bh & 3;
  int tx = threadIdx.x, ty = threadIdx.y;
  const short* src = qkvb + (size_t)(b * 512) * 1536 + 1024 + h * 128;
  int p0 = pt * 32, n0 = nt * 32;
#pragma unroll
  for (int q = 0; q < 4; ++q)
    T[ty * 4 + q][tx] = src[(size_t)(p0 + ty * 4 + q) * 1536 + n0 + tx];
  __syncthreads();
  short* dst = Vt + (size_t)bh * 128 * 512;
#pragma unroll
  for (int q = 0; q < 4; ++q)
    dst[(size_t)(n0 + ty * 4 + q) * 512 + p0 + tx] = T[tx][ty * 4 + q];
}

// Fused flash attention, split-KV: 1024 blocks = (qt 0..31 of 16 q-rows) x (bh 0..31).
// 4 waves per block, wave w handles keys [w*128,(w+1)*128) with online softmax (2 kt iters),
// then 4-way (m,l,O) merge via LDS. P round-trips through wave-private LDS (aliases Ofs).
__global__ __launch_bounds__(256) void kflash(const short* __restrict__ qkvb,
                                              const short* __restrict__ Vt,
                                              short* __restrict__ ob){
  __shared__ float Ofs[4][16][128];           // 32 KB; first 2KB of each wave's quarter aliases P
  __shared__ float Ml[4][16], Ll[4][16], Fw[4][16], Linv[16];
  int bid = blockIdx.x;                       // qt*32 + bh (same-bh blocks 32 apart -> same XCD)
  int bh = bid & 31, qt = bid >> 5;
  int b = bh >> 2, h = bh & 3;
  int t = threadIdx.x;
  int w = t >> 6, lane = t & 63;
  int lm = lane & 15, quad = lane >> 4;
  const float scale = 0.08838834764831845f;   // 1/sqrt(128)

  // Q frags: A[m=lm -> q-row qt*16+lm][k=dim]
  const short* qbase = qkvb + (size_t)(b * 512 + qt * 16 + lm) * 1536 + h * 128 + quad * 8;
  short8 qf[4];
#pragma unroll
  for (int s = 0; s < 4; ++s) qf[s] = *(const short8*)(qbase + s * 32);

  const short* kbase = qkvb + (size_t)(b * 512) * 1536 + 512 + h * 128 + quad * 8;
  const short* vbase = Vt + (size_t)bh * 65536 + (size_t)lm * 512 + quad * 8;

  f32x4 zero4 = {0.f, 0.f, 0.f, 0.f};
  f32x4 Of[8];
#pragma unroll
  for (int i = 0; i < 8; ++i) Of[i] = zero4;
  float mrun[4] = {-1e30f, -1e30f, -1e30f, -1e30f};
  float lrun[4] = {0.f, 0.f, 0.f, 0.f};
  short* Pw = (short*)&Ofs[w][0][0];          // 16x64 bf16 = 2KB, wave-private

#pragma unroll
  for (int kt = 0; kt < 2; ++kt){
    int kb = w * 128 + kt * 64;
    // S = Q @ K_tile^T: C[q=quad*4+r][key=j*16+lm]
    f32x4 Sf[4];
#pragma unroll
    for (int j = 0; j < 4; ++j) Sf[j] = zero4;
#pragma unroll
    for (int s = 0; s < 4; ++s){
#pragma unroll
      for (int j = 0; j < 4; ++j){
        short8 kf = *(const short8*)(kbase + (size_t)(kb + j * 16 + lm) * 1536 + s * 32);
        Sf[j] = __builtin_amdgcn_mfma_f32_16x16x32_bf16(qf[s], kf, Sf[j], 0, 0, 0);
      }
    }
    // online softmax per q-row r (16-lane reduce within quad group)
    float alpha[4];
#pragma unroll
    for (int r = 0; r < 4; ++r){
      float mx = fmaxf(fmaxf(Sf[0][r], Sf[1][r]), fmaxf(Sf[2][r], Sf[3][r])) * scale;
#pragma unroll
      for (int o = 1; o < 16; o <<= 1) mx = fmaxf(mx, __shfl_xor(mx, o));
      float mnew = fmaxf(mrun[r], mx);
      alpha[r] = expf(mrun[r] - mnew);
      float psum = 0.f;
#pragma unroll
      for (int j = 0; j < 4; ++j){
        float p = expf(Sf[j][r] * scale - mnew);
        Sf[j][r] = p;
        psum += p;
      }
#pragma unroll
      for (int o = 1; o < 16; o <<= 1) psum += __shfl_xor(psum, o);
      lrun[r] = lrun[r] * alpha[r] + psum;
      mrun[r] = mnew;
    }
#pragma unroll
    for (int i = 0; i < 8; ++i)
#pragma unroll
      for (int r = 0; r < 4; ++r) Of[i][r] *= alpha[r];
    // P -> LDS (bf16), swizzled: elem (q,key) at q*64 + (key ^ ((q&7)*8))
#pragma unroll
    for (int j = 0; j < 4; ++j)
#pragma unroll
      for (int r = 0; r < 4; ++r){
        int q = quad * 4 + r;
        int key = j * 16 + lm;
        Pw[q * 64 + (key ^ ((q & 7) * 8))] = f2b(Sf[j][r]);
      }
    // PV: A[m=lm -> q][k=key-sub] from LDS; B[n=d][k=key] from Vt
#pragma unroll
    for (int ts = 0; ts < 2; ++ts){
      short8 pa = *(const short8*)(Pw + lm * 64 + (((ts * 32 + quad * 8) ^ ((lm & 7) * 8))));
#pragma unroll
      for (int jd = 0; jd < 8; ++jd){
        short8 vf = *(const short8*)(vbase + (size_t)(jd * 16) * 512 + kb + ts * 32);
        Of[jd] = __builtin_amdgcn_mfma_f32_16x16x32_bf16(pa, vf, Of[jd], 0, 0, 0);
      }
    }
  }

  // stage wave partials (overwrites P region; P dead)
#pragma unroll
  for (int jd = 0; jd < 8; ++jd)
#pragma unroll
    for (int r = 0; r < 4; ++r)
      Ofs[w][quad * 4 + r][jd * 16 + lm] = Of[jd][r];
  if (lm == 0){
#pragma unroll
    for (int r = 0; r < 4; ++r){
      Ml[w][quad * 4 + r] = mrun[r];
      Ll[w][quad * 4 + r] = lrun[r];
    }
  }
  __syncthreads();

  // merge factors: threads 0..63 -> (wv, row)
  if (t < 64){
    int wv = t >> 4, row = t & 15;
    float M = fmaxf(fmaxf(Ml[0][row], Ml[1][row]), fmaxf(Ml[2][row], Ml[3][row]));
    Fw[wv][row] = expf(Ml[wv][row] - M);
    if (wv == 0){
      float lsum = Ll[0][row] * expf(Ml[0][row] - M) + Ll[1][row] * expf(Ml[1][row] - M)
                 + Ll[2][row] * expf(Ml[2][row] - M) + Ll[3][row] * expf(Ml[3][row] - M);
      Linv[row] = 1.f / lsum;
    }
  }
  __syncthreads();

  // combine + write: thread -> (row = t>>4, 8 dims at (t&15)*8)
  {
    int row = t >> 4, dbase = (t & 15) * 8;
    float f0 = Fw[0][row], f1 = Fw[1][row], f2v = Fw[2][row], f3 = Fw[3][row];
    float li = Linv[row];
    short* dst = ob + ((size_t)(b * 512 + qt * 16 + row)) * 512 + h * 128 + dbase;
#pragma unroll
    for (int u = 0; u < 8; ++u){
      float v = Ofs[0][row][dbase + u] * f0 + Ofs[1][row][dbase + u] * f1
              + Ofs[2][row][dbase + u] * f2v + Ofs[3][row][dbase + u] * f3;
      dst[u] = f2b(v * li);
    }
  }
}

// fused: reduce 2 split-K slabs + bias + residual + LayerNorm -> f32 + bf16
__global__ void klnR(const float* __restrict__ part, const float* __restrict__ bias,
                     const float* __restrict__ resid,
                     const float* __restrict__ g, const float* __restrict__ bb,
                     float* __restrict__ Yf, short* __restrict__ Yb){
  int row = blockIdx.x, lane = threadIdx.x;
  size_t base = (size_t)row * DMODEL;
  float v[8]; float s = 0.f;
#pragma unroll
  for (int i = 0; i < 8; ++i){
    int c = lane + 64 * i;
    v[i] = part[base + c] + part[base + c + 2097152] + bias[c] + resid[base + c];
    s += v[i];
  }
  s = waveSum(s);
  float m = s * (1.f / DMODEL);
  float q = 0.f;
#pragma unroll
  for (int i = 0; i < 8; ++i){ float d = v[i] - m; q += d * d; }
  q = waveSum(q);
  float inv = rsqrtf(q * (1.f / DMODEL) + 1e-5f);
#pragma unroll
  for (int i = 0; i < 8; ++i){
    int c = lane + 64 * i;
    float o = (v[i] - m) * inv * g[c] + bb[c];
    Yf[base + c] = o;
    Yb[base + c] = f2b(o);
  }
}

// det softmax over P (columns), reading det part (cols 30..59) of headS [4096][60]
__global__ void kdetsm(const float* __restrict__ hd, float* __restrict__ dp){
  int b = blockIdx.x / NCOUT, c = blockIdx.x % NCOUT, lane = threadIdx.x;
  float v[8]; float m = -1e30f;
#pragma unroll
  for (int i = 0; i < 8; ++i){
    v[i] = hd[((size_t)(b * PDIM) + lane + 64 * i) * 60 + 30 + c];
    m = fmaxf(m, v[i]);
  }
  m = waveMax(m);
  float s = 0.f;
#pragma unroll
  for (int i = 0; i < 8; ++i){ v[i] = expf(v[i] - m); s += v[i]; }
  s = waveSum(s);
  float r = 1.f / s;
#pragma unroll
  for (int i = 0; i < 8; ++i)
    dp[((size_t)(b * PDIM) + lane + 64 * i) * NCOUT + c] = v[i] * r;
}

// class softmax + joint + scatter back to original order + ctx copy + video accumulation
__global__ void kfinal(const float* __restrict__ hd, const float* __restrict__ dps,
                       const float* __restrict__ tok, const int* __restrict__ sidx,
                       float* __restrict__ out){
  int blk = blockIdx.x;
  int b = blk >> 9, j = blk & 511;
  int lane = threadIdx.x;
  int p = sidx[b * PDIM + j];
  float* video = out;
  float* joint = out + 240;
  float* clso  = out + 123120;
  float* deto  = out + 246000;
  float* ctxo  = out + 368880;
  size_t rs60 = (size_t)(b * PDIM + j) * 60;
  size_t rs30 = (size_t)(b * PDIM + j) * NCOUT;
  size_t ro = (size_t)(b * PDIM + p) * NCOUT;
  float lc = (lane < NCOUT) ? hd[rs60 + lane] : -1e30f;
  float m = waveMax(lc);
  float e = (lane < NCOUT) ? expf(lc - m) : 0.f;
  float s = waveSum(e);
  float cp = e / s;
  if (lane < NCOUT){
    float dv  = hd[rs60 + 30 + lane];
    float dpv = dps[rs30 + lane];
    float jp  = cp * dpv;
    clso[ro + lane] = lc;
    deto[ro + lane] = dv;
    joint[ro + lane] = jp;
    atomicAdd(&video[b * NCOUT + lane], jp);
  }
  const float* tr = tok + (size_t)(b * PDIM + j) * DMODEL;
  float* cr = ctxo + (size_t)(b * PDIM + p) * DMODEL;
  for (int c = lane; c < DMODEL; c += 64) cr[c] = tr[c];
}

extern "C" void kernel_launch(void* const* d_in, const int* in_sizes, int n_in,
                              void* d_out, int out_size, void* d_ws, size_t ws_size,
                              hipStream_t stream) {
  const float* x      = (const float*)d_in[0];
  const int*   boxes  = (const int*)d_in[1];
  const float* proj_w = (const float*)d_in[2];
  const float* proj_b = (const float*)d_in[3];
  const float* pos_w1 = (const float*)d_in[4];
  const float* pos_b1 = (const float*)d_in[5];
  const float* pos_w2 = (const float*)d_in[6];
  const float* pos_b2 = (const float*)d_in[7];
  const float* qkv_w  = (const float*)d_in[8];
  const float* qkv_b  = (const float*)d_in[9];
  const float* out_w  = (const float*)d_in[10];
  const float* out_b  = (const float*)d_in[11];
  const float* ln1_g  = (const float*)d_in[12];
  const float* ln1_b  = (const float*)d_in[13];
  const float* ff1_w  = (const float*)d_in[14];
  const float* ff1_b  = (const float*)d_in[15];
  const float* ff2_w  = (const float*)d_in[16];
  const float* ff2_b  = (const float*)d_in[17];
  const float* ln2_g  = (const float*)d_in[18];
  const float* ln2_b  = (const float*)d_in[19];
  const float* cls_w  = (const float*)d_in[20];
  const float* cls_b  = (const float*)d_in[21];
  const float* det_w  = (const float*)d_in[22];
  const float* det_b  = (const float*)d_in[23];
  float* out = (float*)d_out;
  float* ws  = (float*)d_ws;

  // ---- workspace layout (FLOAT units) ----
  const size_t oR1    = 0;
  const size_t oS     = 9437184;    // csum, then G1 split-K partials, then out-proj/ff2 partials
  const size_t oTok   = 22020096;   // 2,097,152 fl
  const size_t oTokb  = 24117248;   // 1,048,576 fl
  const size_t oTok2  = 25165824;   // 2,097,152 fl
  const size_t oTok2b = 27262976;   // 1,048,576 fl
  const size_t oWcat  = 28311552;   // 1,048,576 fl
  const size_t oBcat  = 29360128;   // 512 fl
  const size_t oWq    = 29360640;   // kprep2 dest base; contiguous qkv|out|ff1|ff2|cls|det
  const size_t oWo    = 30147072;
  const size_t oWf1   = 30409216;
  const size_t oWf2   = 30933504;
  const size_t oWcls  = 31457792;
  const size_t oTot   = 31473152;   // 65,536 fl; bhead aliases its start (tot dead after koff)
  const size_t oOff   = 31538688;   // 65,536 fl
  const size_t oSidx  = 31604224;   // int[4096] = 4,096 fl -> end 31,608,320 (~126.4 MB)
  const size_t oBhead = oTot;

  short* Abf   = (short*)(ws + oR1);
  short* qkvb  = (short*)(ws + oR1);
  short* Vt    = (short*)(ws + oR1 + 3145728);
  short* obufb = (short*)(ws + oR1 + 4194304);
  short* hbufb = (short*)(ws + oR1 + 5242880);
  float* headS = ws + oR1 + 7340032;              // [4096][60] after layers (hbufb dead)
  float* dpS   = ws + oR1 + 7585792;
  float* csum  = ws + oS;
  float* Cpart = ws + oS;
  float* Cp2   = ws + oS;                          // 2-slab partials (out-proj / ff2)
  float* tok   = ws + oTok;
  short* tokb  = (short*)(ws + oTokb);
  float* tok2  = ws + oTok2;
  short* tok2b = (short*)(ws + oTok2b);
  short* Wcatb = (short*)(ws + oWcat);
  float* bcat  = ws + oBcat;
  short* Wq    = (short*)(ws + oWq);
  short* Wo    = (short*)(ws + oWo);
  short* Wf1   = (short*)(ws + oWf1);
  short* Wf2   = (short*)(ws + oWf2);
  short* Whead = (short*)(ws + oWcls);            // cls||det rows: [60][512]
  float* tot   = ws + oTot;
  float* offp  = ws + oOff;
  int*   sidx  = (int*)(ws + oSidx);
  float* bhead = ws + oBhead;

  kscan<<<256, 256, 0, stream>>>(x, csum, tot);
  koff<<<16, 256, 0, stream>>>(tot, offp);
  ksort<<<BDIM, 512, 0, stream>>>(boxes, sidx, out);
  kprep2<<<24699, 256, 0, stream>>>(proj_w, pos_w2, qkv_w, out_w, ff1_w, ff2_w, cls_w, det_w,
                                    proj_b, pos_b2, cls_b, det_b, Wcatb, Wq, bcat, bhead);
  kspp<<<BDIM * PDIM, 256, 0, stream>>>(csum, offp, boxes, sidx, pos_w1, pos_b1, Abf);

  // G1 split-K-4 x BN=64, XCD-swizzled: 1024 blocks (4/CU)
  gemm_bt<64, 1><<<dim3(8, 32, 4), 256, 0, stream>>>(
      4096, 512, 1024, Abf, 4096, 1024, 0, Wcatb, 4096, 1024, 0,
      Cpart, nullptr, 512, 2097152, 0, 1, 1.f, nullptr, nullptr, 0);
  kredG1<<<8192, 256, 0, stream>>>(Cpart, bcat, tok, tokb);

  for (int l = 0; l < 2; ++l){
    const short* qw  = Wq  + (size_t)l * 1536 * 512;
    const short* ow  = Wo  + (size_t)l * 512 * 512;
    const short* f1w = Wf1 + (size_t)l * 1024 * 512;
    const short* f2w = Wf2 + (size_t)l * 512 * 1024;
    const float* qb  = qkv_b + (size_t)l * 1536;
    const float* obv = out_b + (size_t)l * 512;
    const float* f1b = ff1_b + (size_t)l * 1024;
    const float* f2b_ = ff2_b + (size_t)l * 512;

    // qkv = tok @ qkv_w^T + qkv_b   [4096, 1536] (bf16 out; 768 blocks, 3/CU)
    gemm_bt<64><<<dim3(24, 32, 1), 256, 0, stream>>>(
        4096, 1536, 512, tokb, 512, 0, 0, qw, 512, 0, 0,
        nullptr, qkvb, 1536, 0, 0, 1, 1.f, qb, nullptr, 0);
    // V transpose for flash B-frags
    kvt<<<dim3(32, 16, 4), dim3(32, 8), 0, stream>>>(qkvb, Vt);
    // fused flash attention (split-KV, 1024 blocks) -> obufb[b][q][h*128+d]
    kflash<<<1024, 256, 0, stream>>>(qkvb, Vt, obufb);
    // out-proj split-K-2 (512 blocks), then fused reduce+bias+resid+LN1
    gemm_bt<64><<<dim3(8, 32, 2), 256, 0, stream>>>(
        4096, 512, 256, obufb, 512, 256, 0, ow, 512, 256, 0,
        Cp2, nullptr, 512, 2097152, 0, 1, 1.f, nullptr, nullptr, 0);
    klnR<<<4096, 64, 0, stream>>>(Cp2, obv, tok, ln1_g + l * 512, ln1_b + l * 512, tok2, tok2b);
    // hbuf = gelu(tok2 @ ff1^T + b1) (bf16; 512 blocks)
    gemm_bt<64><<<dim3(16, 32, 1), 256, 0, stream>>>(
        4096, 1024, 512, tok2b, 512, 0, 0, f1w, 512, 0, 0,
        nullptr, hbufb, 1024, 0, 0, 1, 1.f, f1b, nullptr, 1);
    // ff2 split-K-2 (512 blocks), then fused reduce+bias+resid+LN2
    gemm_bt<64><<<dim3(8, 32, 2), 256, 0, stream>>>(
        4096, 512, 512, hbufb, 1024, 512, 0, f2w, 1024, 512, 0,
        Cp2, nullptr, 512, 2097152, 0, 1, 1.f, nullptr, nullptr, 0);
    klnR<<<4096, 64, 0, stream>>>(Cp2, f2b_, tok2, ln2_g + l * 512, ln2_b + l * 512, tok, tokb);
  }

  // fused heads: headS[4096][60] = tok @ [cls_w;det_w]^T + [cls_b;det_b]
  gemm_bt<64><<<dim3(1, 32, 1), 256, 0, stream>>>(
      4096, 60, 512, tokb, 512, 0, 0, Whead, 512, 0, 0,
      headS, nullptr, 60, 0, 0, 1, 1.f, bhead, nullptr, 0);
  kdetsm<<<BDIM * NCOUT, 64, 0, stream>>>(headS, dpS);
  kfinal<<<BDIM * PDIM, 64, 0, stream>>>(headS, dpS, tok, sidx, out);
}